// Round 1
// baseline (911.725 us; speedup 1.0000x reference)
//
#include <hip/hip_runtime.h>
#include <limits.h>

#define THREADS 256

// ---------------- int8 dot4 ----------------
#if __has_builtin(__builtin_amdgcn_sdot4)
__device__ __forceinline__ int dot4(int a, int b, int c) {
  return __builtin_amdgcn_sdot4(a, b, c, false);
}
#else
__device__ __forceinline__ int dot4(int a, int b, int c) {
  c += (int)(signed char)(a & 0xff)         * (int)(signed char)(b & 0xff);
  c += (int)(signed char)((a >> 8) & 0xff)  * (int)(signed char)((b >> 8) & 0xff);
  c += (int)(signed char)((a >> 16) & 0xff) * (int)(signed char)((b >> 16) & 0xff);
  c += (int)(signed char)((a >> 24) & 0xff) * (int)(signed char)((b >> 24) & 0xff);
  return c;
}
#endif

__device__ __forceinline__ float clamp8f(float q) { return fminf(fmaxf(q, -128.0f), 127.0f); }
__device__ __forceinline__ float sc_from_bits(unsigned b) {
  return fmaxf(__uint_as_float(b) / 127.0f, 1e-8f);
}
__device__ __forceinline__ signed char q8(float v, float s) {
  return (signed char)(int)clamp8f(rintf(v / s));
}

// Scalar slots (int/float view of ws base):
// [0] amax_x bits  [1] amax_w1 bits  [2] amax_w2 bits  [3] amax_wid bits
// [4] maxabs_h1(int) [5] maxabs_id(int) [6] maxabs_h2(int)
// [7] max_y2(float) [8] s_h1 [9] s_y2 [10] s_idq [11] amax_sum bits

__global__ __launch_bounds__(THREADS) void k_init(int* IS, int* maxv, int* minv) {
  int t = threadIdx.x;
  if (t < 64) IS[t] = 0;
  maxv[t] = INT_MIN;
  minv[t] = INT_MAX;
}

__global__ __launch_bounds__(THREADS) void k_amax(const float4* __restrict__ p, int n4,
                                                  unsigned* __restrict__ slot) {
  __shared__ float red[THREADS];
  int i = blockIdx.x * THREADS + threadIdx.x;
  float m = 0.0f;
  if (i < n4) {
    float4 v = p[i];
    m = fmaxf(fmaxf(fabsf(v.x), fabsf(v.y)), fmaxf(fabsf(v.z), fabsf(v.w)));
  }
  red[threadIdx.x] = m;
  __syncthreads();
  for (int s = THREADS / 2; s > 0; s >>= 1) {
    if (threadIdx.x < s) red[threadIdx.x] = fmaxf(red[threadIdx.x], red[threadIdx.x + s]);
    __syncthreads();
  }
  if (threadIdx.x == 0) atomicMax(slot, __float_as_uint(red[0]));
}

// Fold BN: ws = gamma*rsqrt(var+eps); quantize ws (8b sym); b = beta - mean*wq
__global__ __launch_bounds__(THREADS) void k_bnfold(const float* __restrict__ gamma,
                                                    const float* __restrict__ beta,
                                                    const float* __restrict__ mean,
                                                    const float* __restrict__ var,
                                                    float* __restrict__ wq, float* __restrict__ bb) {
  __shared__ float red[THREADS];
  int c = threadIdx.x;
  float ws = gamma[c] * (1.0f / sqrtf(var[c] + 1e-5f));
  red[c] = fabsf(ws);
  __syncthreads();
  for (int s = THREADS / 2; s > 0; s >>= 1) {
    if (c < s) red[c] = fmaxf(red[c], red[c + s]);
    __syncthreads();
  }
  float sws = fmaxf(red[0] / 127.0f, 1e-8f);
  float q = clamp8f(rintf(ws / sws)) * sws;
  wq[c] = q;
  bb[c] = beta[c] - mean[c] * q;
}

// Quantize x (NCHW f32) -> X8 (NHWC int8). t -> (n,h,w,ci4): 32*56*56*32 threads.
__global__ __launch_bounds__(THREADS) void k_qx(const float* __restrict__ x, char4* __restrict__ X8,
                                                const unsigned* __restrict__ ISu) {
  int t = blockIdx.x * THREADS + threadIdx.x;  // < 3,211,264
  float s = sc_from_bits(ISu[0]);
  int ci4 = t & 31;
  int p = t >> 5;
  int w = p % 56;
  int q2 = p / 56;
  int h = q2 % 56;
  int n = q2 / 56;
  int base = ((n * 128 + ci4 * 4) * 56 + h) * 56 + w;  // +j*3136 per channel
  char4 r;
  r.x = q8(x[base], s);
  r.y = q8(x[base + 3136], s);
  r.z = q8(x[base + 2 * 3136], s);
  r.w = q8(x[base + 3 * 3136], s);
  X8[t] = r;
}

// Quantize+repack 3x3 weights [co][ci][kh][kw] f32 -> [co][kh][kw][ci] int8
__global__ __launch_bounds__(THREADS) void k_qw(const float* __restrict__ w, char4* __restrict__ wr,
                                                const unsigned* __restrict__ ISu, int slot,
                                                int cin4, int total) {
  int t = blockIdx.x * THREADS + threadIdx.x;
  if (t >= total) return;
  float s = sc_from_bits(ISu[slot]);
  int ci4 = t % cin4;
  int tmp = t / cin4;
  int tap = tmp % 9;
  int co = tmp / 9;
  int kh = tap / 3, kw = tap % 3;
  int cin = cin4 * 4;
  int base = ((co * cin + ci4 * 4) * 3 + kh) * 3 + kw;  // +j*9 per channel
  char4 r;
  r.x = q8(w[base], s);
  r.y = q8(w[base + 9], s);
  r.z = q8(w[base + 18], s);
  r.w = q8(w[base + 27], s);
  wr[t] = r;
}

// Quantize 1x1 identity weights [co][ci] (already channel-contiguous)
__global__ __launch_bounds__(THREADS) void k_qwid(const float* __restrict__ w, char4* __restrict__ wr,
                                                  const unsigned* __restrict__ ISu) {
  int t = blockIdx.x * THREADS + threadIdx.x;  // < 8192
  float s = sc_from_bits(ISu[3]);
  int base = t * 4;
  char4 r;
  r.x = q8(w[base], s);
  r.y = q8(w[base + 1], s);
  r.z = q8(w[base + 2], s);
  r.w = q8(w[base + 3], s);
  wr[t] = r;
}

// conv1 3x3 s2 p1 (Cin=128) fused with identity 1x1 s2. One block per (n, ho).
// LDS holds 3 input rows, 58 cols (zero-padded), 128ch; all compute reads are wave-broadcast.
__global__ __launch_bounds__(THREADS) void k_conv1(const int* __restrict__ X8,
                                                   const int* __restrict__ W1r,
                                                   const int* __restrict__ Widr,
                                                   int* __restrict__ H1, int* __restrict__ IDI,
                                                   int* __restrict__ maxv, int* __restrict__ minv,
                                                   int* __restrict__ maxabs_id) {
  __shared__ int lds[3 * 58 * 32];
  __shared__ int red[THREADS];
  const int tid = threadIdx.x;
  const int n = blockIdx.x / 28, ho = blockIdx.x % 28;

  for (int kh = 0; kh < 3; ++kh) {
    int h = 2 * ho - 1 + kh;
    int* dst = lds + kh * 58 * 32;
    if (h >= 0 && h < 56) {
      const int* src = X8 + (n * 56 + h) * 56 * 32;
      for (int i = tid; i < 56 * 32; i += THREADS) dst[32 + i] = src[i];
      if (tid < 32) dst[tid] = 0;
      else if (tid < 64) dst[57 * 32 + tid - 32] = 0;
    } else {
      for (int i = tid; i < 58 * 32; i += THREADS) dst[i] = 0;
    }
  }
  __syncthreads();

  const int co = tid;
  int acc[28];
#pragma unroll
  for (int i = 0; i < 28; ++i) acc[i] = 0;

  const int* wb = W1r + co * 288;
#pragma unroll
  for (int kh = 0; kh < 3; ++kh) {
#pragma unroll
    for (int kw = 0; kw < 3; ++kw) {
      const int4* wt = (const int4*)(wb + (kh * 3 + kw) * 32);
      const int* lt = lds + (kh * 58 + kw) * 32;  // + wo*64 gives col 2*wo+kw
#pragma unroll 1
      for (int c16 = 0; c16 < 8; ++c16) {
        int4 wv = wt[c16];
#pragma unroll
        for (int wo = 0; wo < 28; ++wo) {
          int4 iv = ((const int4*)(lt + wo * 64))[c16];
          int a = acc[wo];
          a = dot4(wv.x, iv.x, a);
          a = dot4(wv.y, iv.y, a);
          a = dot4(wv.z, iv.z, a);
          a = dot4(wv.w, iv.w, a);
          acc[wo] = a;
        }
      }
    }
  }

  int vmax = INT_MIN, vmin = INT_MAX;
  int* op = H1 + (n * 28 + ho) * 28 * 256 + co;
#pragma unroll
  for (int wo = 0; wo < 28; ++wo) {
    op[wo * 256] = acc[wo];
    vmax = max(vmax, acc[wo]);
    vmin = min(vmin, acc[wo]);
  }
  atomicMax(&maxv[co], vmax);
  atomicMin(&minv[co], vmin);

  // identity branch: input (2ho, 2wo) = lds row 1, col 2*wo+1
#pragma unroll
  for (int i = 0; i < 28; ++i) acc[i] = 0;
  const int4* wib = (const int4*)(Widr + co * 32);
#pragma unroll 1
  for (int c16 = 0; c16 < 8; ++c16) {
    int4 wv = wib[c16];
#pragma unroll
    for (int wo = 0; wo < 28; ++wo) {
      int4 iv = ((const int4*)(lds + (58 + 2 * wo + 1) * 32))[c16];
      int a = acc[wo];
      a = dot4(wv.x, iv.x, a);
      a = dot4(wv.y, iv.y, a);
      a = dot4(wv.z, iv.z, a);
      a = dot4(wv.w, iv.w, a);
      acc[wo] = a;
    }
  }
  int am = 0;
  int* op2 = IDI + (n * 28 + ho) * 28 * 256 + co;
#pragma unroll
  for (int wo = 0; wo < 28; ++wo) {
    op2[wo * 256] = acc[wo];
    int av = acc[wo] < 0 ? -acc[wo] : acc[wo];
    am = max(am, av);
  }
  red[tid] = am;
  __syncthreads();
  for (int s = THREADS / 2; s > 0; s >>= 1) {
    if (tid < s) red[tid] = max(red[tid], red[tid + s]);
    __syncthreads();
  }
  if (tid == 0) atomicMax(maxabs_id, red[0]);
}

// Derive stage-1 scales: maxabs_h1, s_h1, max_y2 (via per-channel extrema; monotone in v),
// s_y2, s_idq. One block, 256 threads (= channels).
__global__ __launch_bounds__(THREADS) void k_s1(int* __restrict__ IS, float* __restrict__ SC,
                                                const int* __restrict__ maxv,
                                                const int* __restrict__ minv,
                                                const float* __restrict__ wq1,
                                                const float* __restrict__ b1) {
  __shared__ int ri[THREADS];
  __shared__ float rf[THREADS];
  int c = threadIdx.x;
  int vmax = maxv[c], vmin = minv[c];
  int a1 = vmax < 0 ? -vmax : vmax;
  int a0 = vmin < 0 ? -vmin : vmin;
  ri[c] = max(a1, a0);
  __syncthreads();
  for (int s = THREADS / 2; s > 0; s >>= 1) {
    if (c < s) ri[c] = max(ri[c], ri[c + s]);
    __syncthreads();
  }
  int mh1 = ri[0];
  const unsigned* ISu = (const unsigned*)IS;
  float sx = sc_from_bits(ISu[0]);
  float sw1 = sc_from_bits(ISu[1]);
  float sxw = sx * sw1;
  float s_h1 = fmaxf(sxw * (float)mh1 / 127.0f, 1e-8f);
  float wq = wq1[c], bbc = b1[c];
  float q1 = clamp8f(rintf((float)vmax * sxw / s_h1));
  float q0 = clamp8f(rintf((float)vmin * sxw / s_h1));
  float hv1 = q1 * s_h1, hv0 = q0 * s_h1;
  float y1 = fmaxf(hv1 * wq + bbc, 0.0f);
  float y0 = fmaxf(hv0 * wq + bbc, 0.0f);
  rf[c] = fmaxf(y1, y0);
  __syncthreads();
  for (int s = THREADS / 2; s > 0; s >>= 1) {
    if (c < s) rf[c] = fmaxf(rf[c], rf[c + s]);
    __syncthreads();
  }
  if (c == 0) {
    IS[4] = mh1;
    SC[7] = rf[0];
    SC[8] = s_h1;
    SC[9] = fmaxf(rf[0] / 127.0f, 1e-8f);
    float swid = sc_from_bits(ISu[3]);
    SC[10] = fmaxf(sx * swid * (float)IS[5] / 127.0f, 1e-8f);
  }
}

// quant(h1) -> bn1 -> relu -> quant => A2 int8 (NHWC)
__device__ __forceinline__ signed char qact(int v, float sxw, float s_h1, float s_y2, float wq,
                                            float bb) {
  float hf = (float)v * sxw;
  float q = clamp8f(rintf(hf / s_h1));
  float hv = q * s_h1;
  float y = fmaxf(hv * wq + bb, 0.0f);
  float a = fminf(fmaxf(rintf(y / s_y2), -128.0f), 127.0f);
  return (signed char)(int)a;
}

__global__ __launch_bounds__(THREADS) void k_qh1(const int4* __restrict__ H1,
                                                 char4* __restrict__ A2,
                                                 const float* __restrict__ SC,
                                                 const float* __restrict__ wq1,
                                                 const float* __restrict__ b1) {
  int t = blockIdx.x * THREADS + threadIdx.x;  // < 1,605,632
  const unsigned* ISu = (const unsigned*)SC;
  float sx = sc_from_bits(ISu[0]);
  float sw1 = sc_from_bits(ISu[1]);
  float sxw = sx * sw1;
  float s_h1 = SC[8];
  float s_y2 = SC[9];
  int4 v = H1[t];
  int c0 = (t * 4) & 255;
  char4 r;
  r.x = qact(v.x, sxw, s_h1, s_y2, wq1[c0], b1[c0]);
  r.y = qact(v.y, sxw, s_h1, s_y2, wq1[c0 + 1], b1[c0 + 1]);
  r.z = qact(v.z, sxw, s_h1, s_y2, wq1[c0 + 2], b1[c0 + 2]);
  r.w = qact(v.w, sxw, s_h1, s_y2, wq1[c0 + 3], b1[c0 + 3]);
  A2[t] = r;
}

// conv2 3x3 s1 p1 (Cin=256). One block per (n, ho).
__global__ __launch_bounds__(THREADS) void k_conv2(const int* __restrict__ A2,
                                                   const int* __restrict__ W2r,
                                                   int* __restrict__ H2,
                                                   int* __restrict__ maxabs_h2) {
  __shared__ int lds[3 * 30 * 64];
  __shared__ int red[THREADS];
  const int tid = threadIdx.x;
  const int n = blockIdx.x / 28, ho = blockIdx.x % 28;

  for (int kh = 0; kh < 3; ++kh) {
    int h = ho - 1 + kh;
    int* dst = lds + kh * 30 * 64;
    if (h >= 0 && h < 28) {
      const int* src = A2 + (n * 28 + h) * 28 * 64;
      for (int i = tid; i < 28 * 64; i += THREADS) dst[64 + i] = src[i];
      if (tid < 64) dst[tid] = 0;
      else if (tid < 128) dst[29 * 64 + tid - 64] = 0;
    } else {
      for (int i = tid; i < 30 * 64; i += THREADS) dst[i] = 0;
    }
  }
  __syncthreads();

  const int co = tid;
  int acc[28];
#pragma unroll
  for (int i = 0; i < 28; ++i) acc[i] = 0;

  const int* wb = W2r + co * 576;
#pragma unroll
  for (int kh = 0; kh < 3; ++kh) {
#pragma unroll
    for (int kw = 0; kw < 3; ++kw) {
      const int4* wt = (const int4*)(wb + (kh * 3 + kw) * 64);
      const int* lt = lds + (kh * 30 + kw) * 64;  // + wo*64 gives col wo+kw
#pragma unroll 1
      for (int c16 = 0; c16 < 16; ++c16) {
        int4 wv = wt[c16];
#pragma unroll
        for (int wo = 0; wo < 28; ++wo) {
          int4 iv = ((const int4*)(lt + wo * 64))[c16];
          int a = acc[wo];
          a = dot4(wv.x, iv.x, a);
          a = dot4(wv.y, iv.y, a);
          a = dot4(wv.z, iv.z, a);
          a = dot4(wv.w, iv.w, a);
          acc[wo] = a;
        }
      }
    }
  }

  int am = 0;
  int* op = H2 + (n * 28 + ho) * 28 * 256 + co;
#pragma unroll
  for (int wo = 0; wo < 28; ++wo) {
    op[wo * 256] = acc[wo];
    int av = acc[wo] < 0 ? -acc[wo] : acc[wo];
    am = max(am, av);
  }
  red[tid] = am;
  __syncthreads();
  for (int s = THREADS / 2; s > 0; s >>= 1) {
    if (tid < s) red[tid] = max(red[tid], red[tid + s]);
    __syncthreads();
  }
  if (tid == 0) atomicMax(maxabs_h2, red[0]);
}

// quant(h2)->bn2  +  quant(id)->bn_id  -> sum (written NCHW to d_out) + global absmax
__global__ __launch_bounds__(THREADS) void k_sum(const int* __restrict__ H2,
                                                 const int* __restrict__ IDI,
                                                 const float* __restrict__ SC,
                                                 const int* __restrict__ IS,
                                                 const float* __restrict__ wq2,
                                                 const float* __restrict__ b2,
                                                 const float* __restrict__ wqid,
                                                 const float* __restrict__ bidp,
                                                 float* __restrict__ out,
                                                 unsigned* __restrict__ slot) {
  __shared__ float red[THREADS];
  int i = blockIdx.x * THREADS + threadIdx.x;  // < 6,422,528
  const unsigned* ISu = (const unsigned*)IS;
  float sx = sc_from_bits(ISu[0]);
  float sw2 = sc_from_bits(ISu[2]);
  float swid = sc_from_bits(ISu[3]);
  float s_y2 = SC[9], s_idq = SC[10];
  float sxw2 = s_y2 * sw2;
  float s_h2 = fmaxf(sxw2 * (float)IS[6] / 127.0f, 1e-8f);
  float sxwid = sx * swid;
  int c = i & 255;
  int p = i >> 8;
  int r = p % 784;
  int n = p / 784;
  int v2 = H2[i];
  float q2 = clamp8f(rintf((float)v2 * sxw2 / s_h2));
  float z = (q2 * s_h2) * wq2[c] + b2[c];
  int vi = IDI[i];
  float qi = clamp8f(rintf((float)vi * sxwid / s_idq));
  float zi = (qi * s_idq) * wqid[c] + bidp[c];
  float sv = z + zi;
  out[n * 200704 + c * 784 + r] = sv;
  red[threadIdx.x] = fabsf(sv);
  __syncthreads();
  for (int s = THREADS / 2; s > 0; s >>= 1) {
    if (threadIdx.x < s) red[threadIdx.x] = fmaxf(red[threadIdx.x], red[threadIdx.x + s]);
    __syncthreads();
  }
  if (threadIdx.x == 0) atomicMax(slot, __float_as_uint(red[0]));
}

// final requant + relu (in place on d_out, NCHW); also emit out_s
__global__ __launch_bounds__(THREADS) void k_final(float* __restrict__ out,
                                                   const float* __restrict__ SC) {
  int i = blockIdx.x * THREADS + threadIdx.x;  // < 6,422,528
  float out_s = fmaxf(__uint_as_float(((const unsigned*)SC)[11]) / 127.0f, 1e-8f);
  float v = out[i];
  float q = clamp8f(rintf(v / out_s));
  out[i] = q > 0.0f ? q * out_s : 0.0f;
  if (i == 0) out[6422528] = out_s;
}

extern "C" void kernel_launch(void* const* d_in, const int* in_sizes, int n_in, void* d_out,
                              int out_size, void* d_ws, size_t ws_size, hipStream_t stream) {
  (void)in_sizes; (void)n_in; (void)out_size; (void)ws_size;
  const float* x = (const float*)d_in[0];
  const float* w1 = (const float*)d_in[1];
  const float* w2 = (const float*)d_in[2];
  const float* wid = (const float*)d_in[3];
  const float* bn1g = (const float*)d_in[4];
  const float* bn1b = (const float*)d_in[5];
  const float* bn1m = (const float*)d_in[6];
  const float* bn1v = (const float*)d_in[7];
  const float* bn2g = (const float*)d_in[8];
  const float* bn2b = (const float*)d_in[9];
  const float* bn2m = (const float*)d_in[10];
  const float* bn2v = (const float*)d_in[11];
  const float* idg = (const float*)d_in[12];
  const float* idb = (const float*)d_in[13];
  const float* idm = (const float*)d_in[14];
  const float* idv = (const float*)d_in[15];

  char* ws = (char*)d_ws;
  float* SC = (float*)ws;
  int* IS = (int*)ws;
  unsigned* ISu = (unsigned*)ws;
  int* maxv = (int*)(ws + 1024);
  int* minv = (int*)(ws + 2048);
  float* wq1 = (float*)(ws + 3072);
  float* b1 = (float*)(ws + 4096);
  float* wq2 = (float*)(ws + 5120);
  float* b2 = (float*)(ws + 6144);
  float* wqid = (float*)(ws + 7168);
  float* bid = (float*)(ws + 8192);
  char* X8 = ws + 16384;                 // 12,845,056 B (NHWC int8); A2 overlays after conv1
  char* A2 = X8;                         // 6,422,528 B
  char* W1r = X8 + 12845056;             // 294,912 B
  char* W2r = W1r + 294912;              // 589,824 B
  char* Widr = W2r + 589824;             // 32,768 B
  int* H1 = (int*)(Widr + 32768);        // 25,690,112 B; H2 overlays after k_qh1
  int* H2 = H1;
  int* IDI = (int*)((char*)H1 + 25690112);  // 25,690,112 B  (total ws ~65.2 MB)
  float* out = (float*)d_out;

  k_init<<<1, THREADS, 0, stream>>>(IS, maxv, minv);
  k_amax<<<12544, THREADS, 0, stream>>>((const float4*)x, 3211264, ISu + 0);
  k_amax<<<288, THREADS, 0, stream>>>((const float4*)w1, 73728, ISu + 1);
  k_amax<<<576, THREADS, 0, stream>>>((const float4*)w2, 147456, ISu + 2);
  k_amax<<<32, THREADS, 0, stream>>>((const float4*)wid, 8192, ISu + 3);
  k_bnfold<<<1, THREADS, 0, stream>>>(bn1g, bn1b, bn1m, bn1v, wq1, b1);
  k_bnfold<<<1, THREADS, 0, stream>>>(bn2g, bn2b, bn2m, bn2v, wq2, b2);
  k_bnfold<<<1, THREADS, 0, stream>>>(idg, idb, idm, idv, wqid, bid);
  k_qx<<<12544, THREADS, 0, stream>>>(x, (char4*)X8, ISu);
  k_qw<<<288, THREADS, 0, stream>>>(w1, (char4*)W1r, ISu, 1, 32, 73728);
  k_qw<<<576, THREADS, 0, stream>>>(w2, (char4*)W2r, ISu, 2, 64, 147456);
  k_qwid<<<32, THREADS, 0, stream>>>(wid, (char4*)Widr, ISu);
  k_conv1<<<896, THREADS, 0, stream>>>((const int*)X8, (const int*)W1r, (const int*)Widr, H1, IDI,
                                       maxv, minv, IS + 5);
  k_s1<<<1, THREADS, 0, stream>>>(IS, SC, maxv, minv, wq1, b1);
  k_qh1<<<6272, THREADS, 0, stream>>>((const int4*)H1, (char4*)A2, SC, wq1, b1);
  k_conv2<<<896, THREADS, 0, stream>>>((const int*)A2, (const int*)W2r, H2, IS + 6);
  k_sum<<<25088, THREADS, 0, stream>>>(H2, IDI, SC, IS, wq2, b2, wqid, bid, out, ISu + 11);
  k_final<<<25088, THREADS, 0, stream>>>(out, SC);
}

// Round 2
// 694.584 us; speedup vs baseline: 1.3126x; 1.3126x over previous
//
#include <hip/hip_runtime.h>
#include <limits.h>

#define THREADS 256

// ---------------- int8 dot4 ----------------
#if __has_builtin(__builtin_amdgcn_sdot4)
__device__ __forceinline__ int dot4(int a, int b, int c) {
  return __builtin_amdgcn_sdot4(a, b, c, false);
}
#else
__device__ __forceinline__ int dot4(int a, int b, int c) {
  c += (int)(signed char)(a & 0xff)         * (int)(signed char)(b & 0xff);
  c += (int)(signed char)((a >> 8) & 0xff)  * (int)(signed char)((b >> 8) & 0xff);
  c += (int)(signed char)((a >> 16) & 0xff) * (int)(signed char)((b >> 16) & 0xff);
  c += (int)(signed char)((a >> 24) & 0xff) * (int)(signed char)((b >> 24) & 0xff);
  return c;
}
#endif

__device__ __forceinline__ float clamp8f(float q) { return fminf(fmaxf(q, -128.0f), 127.0f); }
__device__ __forceinline__ float sc_from_bits(unsigned b) {
  return fmaxf(__uint_as_float(b) / 127.0f, 1e-8f);
}
__device__ __forceinline__ signed char q8(float v, float s) {
  return (signed char)(int)clamp8f(rintf(v / s));
}

// Scalar slots (int/float view of ws base):
// [0] amax_x bits  [1] amax_w1 bits  [2] amax_w2 bits  [3] amax_wid bits
// [4] maxabs_h1(int) [5] maxabs_id(int) [6] maxabs_h2(int)
// [7] max_y2(float) [8] s_h1 [9] s_y2 [10] s_idq [11] amax_sum bits

__global__ __launch_bounds__(THREADS) void k_init(int* IS, int* maxv, int* minv) {
  int t = threadIdx.x;
  if (t < 64) IS[t] = 0;
  maxv[t] = INT_MIN;
  minv[t] = INT_MAX;
}

__global__ __launch_bounds__(THREADS) void k_amax(const float4* __restrict__ p, int n4,
                                                  unsigned* __restrict__ slot) {
  __shared__ float red[THREADS];
  int i = blockIdx.x * THREADS + threadIdx.x;
  float m = 0.0f;
  if (i < n4) {
    float4 v = p[i];
    m = fmaxf(fmaxf(fabsf(v.x), fabsf(v.y)), fmaxf(fabsf(v.z), fabsf(v.w)));
  }
  red[threadIdx.x] = m;
  __syncthreads();
  for (int s = THREADS / 2; s > 0; s >>= 1) {
    if (threadIdx.x < s) red[threadIdx.x] = fmaxf(red[threadIdx.x], red[threadIdx.x + s]);
    __syncthreads();
  }
  if (threadIdx.x == 0) atomicMax(slot, __float_as_uint(red[0]));
}

// Fold BN: ws = gamma*rsqrt(var+eps); quantize ws (8b sym); b = beta - mean*wq
__global__ __launch_bounds__(THREADS) void k_bnfold(const float* __restrict__ gamma,
                                                    const float* __restrict__ beta,
                                                    const float* __restrict__ mean,
                                                    const float* __restrict__ var,
                                                    float* __restrict__ wq, float* __restrict__ bb) {
  __shared__ float red[THREADS];
  int c = threadIdx.x;
  float ws = gamma[c] * (1.0f / sqrtf(var[c] + 1e-5f));
  red[c] = fabsf(ws);
  __syncthreads();
  for (int s = THREADS / 2; s > 0; s >>= 1) {
    if (c < s) red[c] = fmaxf(red[c], red[c + s]);
    __syncthreads();
  }
  float sws = fmaxf(red[0] / 127.0f, 1e-8f);
  float q = clamp8f(rintf(ws / sws)) * sws;
  wq[c] = q;
  bb[c] = beta[c] - mean[c] * q;
}

// Quantize x (NCHW f32) -> X8 (NHWC int8). t -> (n,h,w,ci4): 32*56*56*32 threads.
__global__ __launch_bounds__(THREADS) void k_qx(const float* __restrict__ x, char4* __restrict__ X8,
                                                const unsigned* __restrict__ ISu) {
  int t = blockIdx.x * THREADS + threadIdx.x;  // < 3,211,264
  float s = sc_from_bits(ISu[0]);
  int ci4 = t & 31;
  int p = t >> 5;
  int w = p % 56;
  int q2 = p / 56;
  int h = q2 % 56;
  int n = q2 / 56;
  int base = ((n * 128 + ci4 * 4) * 56 + h) * 56 + w;  // +j*3136 per channel
  char4 r;
  r.x = q8(x[base], s);
  r.y = q8(x[base + 3136], s);
  r.z = q8(x[base + 2 * 3136], s);
  r.w = q8(x[base + 3 * 3136], s);
  X8[t] = r;
}

// Quantize+repack 3x3 weights [co][ci][kh][kw] f32 -> [co][kh][kw][ci] int8
__global__ __launch_bounds__(THREADS) void k_qw(const float* __restrict__ w, char4* __restrict__ wr,
                                                const unsigned* __restrict__ ISu, int slot,
                                                int cin4, int total) {
  int t = blockIdx.x * THREADS + threadIdx.x;
  if (t >= total) return;
  float s = sc_from_bits(ISu[slot]);
  int ci4 = t % cin4;
  int tmp = t / cin4;
  int tap = tmp % 9;
  int co = tmp / 9;
  int kh = tap / 3, kw = tap % 3;
  int cin = cin4 * 4;
  int base = ((co * cin + ci4 * 4) * 3 + kh) * 3 + kw;  // +j*9 per channel
  char4 r;
  r.x = q8(w[base], s);
  r.y = q8(w[base + 9], s);
  r.z = q8(w[base + 18], s);
  r.w = q8(w[base + 27], s);
  wr[t] = r;
}

// Quantize 1x1 identity weights [co][ci] (already channel-contiguous)
__global__ __launch_bounds__(THREADS) void k_qwid(const float* __restrict__ w, char4* __restrict__ wr,
                                                  const unsigned* __restrict__ ISu) {
  int t = blockIdx.x * THREADS + threadIdx.x;  // < 8192
  float s = sc_from_bits(ISu[3]);
  int base = t * 4;
  char4 r;
  r.x = q8(w[base], s);
  r.y = q8(w[base + 1], s);
  r.z = q8(w[base + 2], s);
  r.w = q8(w[base + 3], s);
  wr[t] = r;
}

// conv1 3x3 s2 p1 (Cin=128) fused with identity 1x1 s2. One block per (n, ho).
// LDS holds 3 input rows, 58 cols (zero-padded), 128ch; all compute reads are wave-broadcast.
__global__ __launch_bounds__(THREADS) void k_conv1(const int* __restrict__ X8,
                                                   const int* __restrict__ W1r,
                                                   const int* __restrict__ Widr,
                                                   int* __restrict__ H1, int* __restrict__ IDI,
                                                   int* __restrict__ maxv, int* __restrict__ minv,
                                                   int* __restrict__ maxabs_id) {
  __shared__ int lds[3 * 58 * 32];
  __shared__ int red[THREADS];
  const int tid = threadIdx.x;
  const int n = blockIdx.x / 28, ho = blockIdx.x % 28;

  for (int kh = 0; kh < 3; ++kh) {
    int h = 2 * ho - 1 + kh;
    int* dst = lds + kh * 58 * 32;
    if (h >= 0 && h < 56) {
      const int* src = X8 + (n * 56 + h) * 56 * 32;
      for (int i = tid; i < 56 * 32; i += THREADS) dst[32 + i] = src[i];
      if (tid < 32) dst[tid] = 0;
      else if (tid < 64) dst[57 * 32 + tid - 32] = 0;
    } else {
      for (int i = tid; i < 58 * 32; i += THREADS) dst[i] = 0;
    }
  }
  __syncthreads();

  const int co = tid;
  int acc[28];
#pragma unroll
  for (int i = 0; i < 28; ++i) acc[i] = 0;

  const int* wb = W1r + co * 288;
#pragma unroll
  for (int kh = 0; kh < 3; ++kh) {
#pragma unroll
    for (int kw = 0; kw < 3; ++kw) {
      const int4* wt = (const int4*)(wb + (kh * 3 + kw) * 32);
      const int* lt = lds + (kh * 58 + kw) * 32;  // + wo*64 gives col 2*wo+kw
#pragma unroll 1
      for (int c16 = 0; c16 < 8; ++c16) {
        int4 wv = wt[c16];
#pragma unroll
        for (int wo = 0; wo < 28; ++wo) {
          int4 iv = ((const int4*)(lt + wo * 64))[c16];
          int a = acc[wo];
          a = dot4(wv.x, iv.x, a);
          a = dot4(wv.y, iv.y, a);
          a = dot4(wv.z, iv.z, a);
          a = dot4(wv.w, iv.w, a);
          acc[wo] = a;
        }
      }
    }
  }

  int vmax = INT_MIN, vmin = INT_MAX;
  int* op = H1 + (n * 28 + ho) * 28 * 256 + co;
#pragma unroll
  for (int wo = 0; wo < 28; ++wo) {
    op[wo * 256] = acc[wo];
    vmax = max(vmax, acc[wo]);
    vmin = min(vmin, acc[wo]);
  }
  atomicMax(&maxv[co], vmax);
  atomicMin(&minv[co], vmin);

  // identity branch: input (2ho, 2wo) = lds row 1, col 2*wo+1
#pragma unroll
  for (int i = 0; i < 28; ++i) acc[i] = 0;
  const int4* wib = (const int4*)(Widr + co * 32);
#pragma unroll 1
  for (int c16 = 0; c16 < 8; ++c16) {
    int4 wv = wib[c16];
#pragma unroll
    for (int wo = 0; wo < 28; ++wo) {
      int4 iv = ((const int4*)(lds + (58 + 2 * wo + 1) * 32))[c16];
      int a = acc[wo];
      a = dot4(wv.x, iv.x, a);
      a = dot4(wv.y, iv.y, a);
      a = dot4(wv.z, iv.z, a);
      a = dot4(wv.w, iv.w, a);
      acc[wo] = a;
    }
  }
  int am = 0;
  int* op2 = IDI + (n * 28 + ho) * 28 * 256 + co;
#pragma unroll
  for (int wo = 0; wo < 28; ++wo) {
    op2[wo * 256] = acc[wo];
    int av = acc[wo] < 0 ? -acc[wo] : acc[wo];
    am = max(am, av);
  }
  red[tid] = am;
  __syncthreads();
  for (int s = THREADS / 2; s > 0; s >>= 1) {
    if (tid < s) red[tid] = max(red[tid], red[tid + s]);
    __syncthreads();
  }
  if (tid == 0) atomicMax(maxabs_id, red[0]);
}

// Derive stage-1 scales: maxabs_h1, s_h1, max_y2 (via per-channel extrema; monotone in v),
// s_y2, s_idq. One block, 256 threads (= channels).
__global__ __launch_bounds__(THREADS) void k_s1(int* __restrict__ IS, float* __restrict__ SC,
                                                const int* __restrict__ maxv,
                                                const int* __restrict__ minv,
                                                const float* __restrict__ wq1,
                                                const float* __restrict__ b1) {
  __shared__ int ri[THREADS];
  __shared__ float rf[THREADS];
  int c = threadIdx.x;
  int vmax = maxv[c], vmin = minv[c];
  int a1 = vmax < 0 ? -vmax : vmax;
  int a0 = vmin < 0 ? -vmin : vmin;
  ri[c] = max(a1, a0);
  __syncthreads();
  for (int s = THREADS / 2; s > 0; s >>= 1) {
    if (c < s) ri[c] = max(ri[c], ri[c + s]);
    __syncthreads();
  }
  int mh1 = ri[0];
  const unsigned* ISu = (const unsigned*)IS;
  float sx = sc_from_bits(ISu[0]);
  float sw1 = sc_from_bits(ISu[1]);
  float sxw = sx * sw1;
  float s_h1 = fmaxf(sxw * (float)mh1 / 127.0f, 1e-8f);
  float wq = wq1[c], bbc = b1[c];
  float q1 = clamp8f(rintf((float)vmax * sxw / s_h1));
  float q0 = clamp8f(rintf((float)vmin * sxw / s_h1));
  float hv1 = q1 * s_h1, hv0 = q0 * s_h1;
  float y1 = fmaxf(hv1 * wq + bbc, 0.0f);
  float y0 = fmaxf(hv0 * wq + bbc, 0.0f);
  rf[c] = fmaxf(y1, y0);
  __syncthreads();
  for (int s = THREADS / 2; s > 0; s >>= 1) {
    if (c < s) rf[c] = fmaxf(rf[c], rf[c + s]);
    __syncthreads();
  }
  if (c == 0) {
    IS[4] = mh1;
    SC[7] = rf[0];
    SC[8] = s_h1;
    SC[9] = fmaxf(rf[0] / 127.0f, 1e-8f);
    float swid = sc_from_bits(ISu[3]);
    SC[10] = fmaxf(sx * swid * (float)IS[5] / 127.0f, 1e-8f);
  }
}

// quant(h1) -> bn1 -> relu -> quant => A2 int8 (NHWC)
__device__ __forceinline__ signed char qact(int v, float sxw, float s_h1, float s_y2, float wq,
                                            float bb) {
  float hf = (float)v * sxw;
  float q = clamp8f(rintf(hf / s_h1));
  float hv = q * s_h1;
  float y = fmaxf(hv * wq + bb, 0.0f);
  float a = fminf(fmaxf(rintf(y / s_y2), -128.0f), 127.0f);
  return (signed char)(int)a;
}

__global__ __launch_bounds__(THREADS) void k_qh1(const int4* __restrict__ H1,
                                                 char4* __restrict__ A2,
                                                 const float* __restrict__ SC,
                                                 const float* __restrict__ wq1,
                                                 const float* __restrict__ b1) {
  int t = blockIdx.x * THREADS + threadIdx.x;  // < 1,605,632
  const unsigned* ISu = (const unsigned*)SC;
  float sx = sc_from_bits(ISu[0]);
  float sw1 = sc_from_bits(ISu[1]);
  float sxw = sx * sw1;
  float s_h1 = SC[8];
  float s_y2 = SC[9];
  int4 v = H1[t];
  int c0 = (t * 4) & 255;
  char4 r;
  r.x = qact(v.x, sxw, s_h1, s_y2, wq1[c0], b1[c0]);
  r.y = qact(v.y, sxw, s_h1, s_y2, wq1[c0 + 1], b1[c0 + 1]);
  r.z = qact(v.z, sxw, s_h1, s_y2, wq1[c0 + 2], b1[c0 + 2]);
  r.w = qact(v.w, sxw, s_h1, s_y2, wq1[c0 + 3], b1[c0 + 3]);
  A2[t] = r;
}

// conv2 3x3 s1 p1 (Cin=256). One block per (n, ho).
__global__ __launch_bounds__(THREADS) void k_conv2(const int* __restrict__ A2,
                                                   const int* __restrict__ W2r,
                                                   int* __restrict__ H2,
                                                   int* __restrict__ maxabs_h2) {
  __shared__ int lds[3 * 30 * 64];
  __shared__ int red[THREADS];
  const int tid = threadIdx.x;
  const int n = blockIdx.x / 28, ho = blockIdx.x % 28;

  for (int kh = 0; kh < 3; ++kh) {
    int h = ho - 1 + kh;
    int* dst = lds + kh * 30 * 64;
    if (h >= 0 && h < 28) {
      const int* src = A2 + (n * 28 + h) * 28 * 64;
      for (int i = tid; i < 28 * 64; i += THREADS) dst[64 + i] = src[i];
      if (tid < 64) dst[tid] = 0;
      else if (tid < 128) dst[29 * 64 + tid - 64] = 0;
    } else {
      for (int i = tid; i < 30 * 64; i += THREADS) dst[i] = 0;
    }
  }
  __syncthreads();

  const int co = tid;
  int acc[28];
#pragma unroll
  for (int i = 0; i < 28; ++i) acc[i] = 0;

  const int* wb = W2r + co * 576;
#pragma unroll
  for (int kh = 0; kh < 3; ++kh) {
#pragma unroll
    for (int kw = 0; kw < 3; ++kw) {
      const int4* wt = (const int4*)(wb + (kh * 3 + kw) * 64);
      const int* lt = lds + (kh * 30 + kw) * 64;  // + wo*64 gives col wo+kw
#pragma unroll 1
      for (int c16 = 0; c16 < 16; ++c16) {
        int4 wv = wt[c16];
#pragma unroll
        for (int wo = 0; wo < 28; ++wo) {
          int4 iv = ((const int4*)(lt + wo * 64))[c16];
          int a = acc[wo];
          a = dot4(wv.x, iv.x, a);
          a = dot4(wv.y, iv.y, a);
          a = dot4(wv.z, iv.z, a);
          a = dot4(wv.w, iv.w, a);
          acc[wo] = a;
        }
      }
    }
  }

  int am = 0;
  int* op = H2 + (n * 28 + ho) * 28 * 256 + co;
#pragma unroll
  for (int wo = 0; wo < 28; ++wo) {
    op[wo * 256] = acc[wo];
    int av = acc[wo] < 0 ? -acc[wo] : acc[wo];
    am = max(am, av);
  }
  red[tid] = am;
  __syncthreads();
  for (int s = THREADS / 2; s > 0; s >>= 1) {
    if (tid < s) red[tid] = max(red[tid], red[tid + s]);
    __syncthreads();
  }
  if (tid == 0) atomicMax(maxabs_h2, red[0]);
}

// ---- residual sum math shared by k_absmax2 / k_out ----
struct SumParams {
  float sxw2, s_h2, sxwid, s_idq;
};
__device__ __forceinline__ float sum_val(int v2, int vi, const SumParams& P, float wq2c, float b2c,
                                         float wqidc, float bidc) {
  float q2 = clamp8f(rintf((float)v2 * P.sxw2 / P.s_h2));
  float z = (q2 * P.s_h2) * wq2c + b2c;
  float qi = clamp8f(rintf((float)vi * P.sxwid / P.s_idq));
  float zi = (qi * P.s_idq) * wqidc + bidc;
  return z + zi;
}
__device__ __forceinline__ SumParams make_params(const float* SC, const int* IS) {
  const unsigned* ISu = (const unsigned*)IS;
  SumParams P;
  float sx = sc_from_bits(ISu[0]);
  float sw2 = sc_from_bits(ISu[2]);
  float swid = sc_from_bits(ISu[3]);
  float s_y2 = SC[9];
  P.s_idq = SC[10];
  P.sxw2 = s_y2 * sw2;
  P.s_h2 = fmaxf(P.sxw2 * (float)IS[6] / 127.0f, 1e-8f);
  P.sxwid = sx * swid;
  return P;
}

// Pass 1: global absmax of (quant(h2)·bn2 + quant(id)·bn_id). Fully coalesced, no big writes.
__global__ __launch_bounds__(THREADS) void k_absmax2(const int4* __restrict__ H2,
                                                     const int4* __restrict__ IDI,
                                                     const float* __restrict__ SC,
                                                     const int* __restrict__ IS,
                                                     const float* __restrict__ wq2,
                                                     const float* __restrict__ b2,
                                                     const float* __restrict__ wqid,
                                                     const float* __restrict__ bidp,
                                                     unsigned* __restrict__ slot) {
  __shared__ float red[THREADS];
  __shared__ float pw2[256], pb2[256], pwi[256], pbi[256];
  int tid = threadIdx.x;
  pw2[tid] = wq2[tid];
  pb2[tid] = b2[tid];
  pwi[tid] = wqid[tid];
  pbi[tid] = bidp[tid];
  __syncthreads();
  SumParams P = make_params(SC, IS);
  int i = blockIdx.x * THREADS + tid;  // < 1,605,632
  int4 v2 = H2[i];
  int4 vi = IDI[i];
  int c0 = (i * 4) & 255;
  float m = fabsf(sum_val(v2.x, vi.x, P, pw2[c0], pb2[c0], pwi[c0], pbi[c0]));
  m = fmaxf(m, fabsf(sum_val(v2.y, vi.y, P, pw2[c0 + 1], pb2[c0 + 1], pwi[c0 + 1], pbi[c0 + 1])));
  m = fmaxf(m, fabsf(sum_val(v2.z, vi.z, P, pw2[c0 + 2], pb2[c0 + 2], pwi[c0 + 2], pbi[c0 + 2])));
  m = fmaxf(m, fabsf(sum_val(v2.w, vi.w, P, pw2[c0 + 3], pb2[c0 + 3], pwi[c0 + 3], pbi[c0 + 3])));
  red[tid] = m;
  __syncthreads();
  for (int s = THREADS / 2; s > 0; s >>= 1) {
    if (tid < s) red[tid] = fmaxf(red[tid], red[tid + s]);
    __syncthreads();
  }
  if (tid == 0) atomicMax(slot, __float_as_uint(red[0]));
}

// Pass 2: recompute sum, final requant + relu, write NCHW via padded LDS tile transpose.
// Tile: 64 channels x 56 positions. Grid: 32n * 14rt * 4ct = 1792 blocks.
__global__ __launch_bounds__(THREADS) void k_out(const int* __restrict__ H2,
                                                 const int* __restrict__ IDI,
                                                 const float* __restrict__ SC,
                                                 const int* __restrict__ IS,
                                                 const float* __restrict__ wq2,
                                                 const float* __restrict__ b2,
                                                 const float* __restrict__ wqid,
                                                 const float* __restrict__ bidp,
                                                 float* __restrict__ out) {
  __shared__ float tile[64 * 57];
  __shared__ float pw2[64], pb2[64], pwi[64], pbi[64];
  int tid = threadIdx.x;
  int b = blockIdx.x;
  int ct = b & 3;
  int rt = (b >> 2) % 14;
  int n = b / 56;
  int c0 = ct * 64;
  int r0 = rt * 56;
  if (tid < 64) {
    pw2[tid] = wq2[c0 + tid];
    pb2[tid] = b2[c0 + tid];
    pwi[tid] = wqid[c0 + tid];
    pbi[tid] = bidp[c0 + tid];
  }
  __syncthreads();
  SumParams P = make_params(SC, IS);
  float out_s = fmaxf(__uint_as_float(((const unsigned*)IS)[11]) / 127.0f, 1e-8f);

  const int base = (n * 784 + r0) * 256 + c0;
#pragma unroll
  for (int k = 0; k < 14; ++k) {
    int idx = tid + k * 256;       // < 3584
    int rl = idx >> 6;             // 0..55
    int cl = idx & 63;             // 0..63
    int e = base + rl * 256 + cl;
    float sv = sum_val(H2[e], IDI[e], P, pw2[cl], pb2[cl], pwi[cl], pbi[cl]);
    float q = clamp8f(rintf(sv / out_s));
    tile[cl * 57 + rl] = q > 0.0f ? q * out_s : 0.0f;
  }
  __syncthreads();
  float* ob = out + n * 200704 + c0 * 784 + r0;
#pragma unroll
  for (int k = 0; k < 14; ++k) {
    int idx = tid + k * 256;       // < 3584 = 64*56
    int cl = idx / 56;
    int rl = idx % 56;
    ob[cl * 784 + rl] = tile[cl * 57 + rl];
  }
  if (b == 0 && tid == 0) out[6422528] = out_s;
}

extern "C" void kernel_launch(void* const* d_in, const int* in_sizes, int n_in, void* d_out,
                              int out_size, void* d_ws, size_t ws_size, hipStream_t stream) {
  (void)in_sizes; (void)n_in; (void)out_size; (void)ws_size;
  const float* x = (const float*)d_in[0];
  const float* w1 = (const float*)d_in[1];
  const float* w2 = (const float*)d_in[2];
  const float* wid = (const float*)d_in[3];
  const float* bn1g = (const float*)d_in[4];
  const float* bn1b = (const float*)d_in[5];
  const float* bn1m = (const float*)d_in[6];
  const float* bn1v = (const float*)d_in[7];
  const float* bn2g = (const float*)d_in[8];
  const float* bn2b = (const float*)d_in[9];
  const float* bn2m = (const float*)d_in[10];
  const float* bn2v = (const float*)d_in[11];
  const float* idg = (const float*)d_in[12];
  const float* idb = (const float*)d_in[13];
  const float* idm = (const float*)d_in[14];
  const float* idv = (const float*)d_in[15];

  char* ws = (char*)d_ws;
  float* SC = (float*)ws;
  int* IS = (int*)ws;
  unsigned* ISu = (unsigned*)ws;
  int* maxv = (int*)(ws + 1024);
  int* minv = (int*)(ws + 2048);
  float* wq1 = (float*)(ws + 3072);
  float* b1 = (float*)(ws + 4096);
  float* wq2 = (float*)(ws + 5120);
  float* b2 = (float*)(ws + 6144);
  float* wqid = (float*)(ws + 7168);
  float* bid = (float*)(ws + 8192);
  char* X8 = ws + 16384;                 // 12,845,056 B (NHWC int8); A2 overlays after conv1
  char* A2 = X8;                         // 6,422,528 B
  char* W1r = X8 + 12845056;             // 294,912 B
  char* W2r = W1r + 294912;              // 589,824 B
  char* Widr = W2r + 589824;             // 32,768 B
  int* H1 = (int*)(Widr + 32768);        // 25,690,112 B; H2 overlays after k_qh1
  int* H2 = H1;
  int* IDI = (int*)((char*)H1 + 25690112);  // 25,690,112 B  (total ws ~65.2 MB)
  float* out = (float*)d_out;

  k_init<<<1, THREADS, 0, stream>>>(IS, maxv, minv);
  k_amax<<<12544, THREADS, 0, stream>>>((const float4*)x, 3211264, ISu + 0);
  k_amax<<<288, THREADS, 0, stream>>>((const float4*)w1, 73728, ISu + 1);
  k_amax<<<576, THREADS, 0, stream>>>((const float4*)w2, 147456, ISu + 2);
  k_amax<<<32, THREADS, 0, stream>>>((const float4*)wid, 8192, ISu + 3);
  k_bnfold<<<1, THREADS, 0, stream>>>(bn1g, bn1b, bn1m, bn1v, wq1, b1);
  k_bnfold<<<1, THREADS, 0, stream>>>(bn2g, bn2b, bn2m, bn2v, wq2, b2);
  k_bnfold<<<1, THREADS, 0, stream>>>(idg, idb, idm, idv, wqid, bid);
  k_qx<<<12544, THREADS, 0, stream>>>(x, (char4*)X8, ISu);
  k_qw<<<288, THREADS, 0, stream>>>(w1, (char4*)W1r, ISu, 1, 32, 73728);
  k_qw<<<576, THREADS, 0, stream>>>(w2, (char4*)W2r, ISu, 2, 64, 147456);
  k_qwid<<<32, THREADS, 0, stream>>>(wid, (char4*)Widr, ISu);
  k_conv1<<<896, THREADS, 0, stream>>>((const int*)X8, (const int*)W1r, (const int*)Widr, H1, IDI,
                                       maxv, minv, IS + 5);
  k_s1<<<1, THREADS, 0, stream>>>(IS, SC, maxv, minv, wq1, b1);
  k_qh1<<<6272, THREADS, 0, stream>>>((const int4*)H1, (char4*)A2, SC, wq1, b1);
  k_conv2<<<896, THREADS, 0, stream>>>((const int*)A2, (const int*)W2r, H2, IS + 6);
  k_absmax2<<<6272, THREADS, 0, stream>>>((const int4*)H2, (const int4*)IDI, SC, IS, wq2, b2, wqid,
                                          bid, ISu + 11);
  k_out<<<1792, THREADS, 0, stream>>>(H2, IDI, SC, IS, wq2, b2, wqid, bid, out);
}

// Round 3
// 526.849 us; speedup vs baseline: 1.7305x; 1.3184x over previous
//
#include <hip/hip_runtime.h>
#include <limits.h>

#define THREADS 256

typedef int vi4 __attribute__((ext_vector_type(4)));

__device__ __forceinline__ float clamp8f(float q) { return fminf(fmaxf(q, -128.0f), 127.0f); }
__device__ __forceinline__ float sc_from_bits(unsigned b) {
  return fmaxf(__uint_as_float(b) / 127.0f, 1e-8f);
}
__device__ __forceinline__ signed char q8(float v, float s) {
  return (signed char)(int)clamp8f(rintf(v / s));
}

// Scalar slots (int/float view of ws base):
// [0] amax_x bits  [1] amax_w1 bits  [2] amax_w2 bits  [3] amax_wid bits
// [4] maxabs_h1(int) [5] maxabs_id(int) [6] maxabs_h2(int)
// [7] max_y2(float) [8] s_h1 [9] s_y2 [10] s_idq [11] amax_sum bits

__global__ __launch_bounds__(THREADS) void k_init(int* IS, int* maxv, int* minv) {
  int t = threadIdx.x;
  if (t < 64) IS[t] = 0;
  maxv[t] = INT_MIN;
  minv[t] = INT_MAX;
}

__global__ __launch_bounds__(THREADS) void k_amax(const float4* __restrict__ p, int n4,
                                                  unsigned* __restrict__ slot) {
  __shared__ float red[THREADS];
  int i = blockIdx.x * THREADS + threadIdx.x;
  float m = 0.0f;
  if (i < n4) {
    float4 v = p[i];
    m = fmaxf(fmaxf(fabsf(v.x), fabsf(v.y)), fmaxf(fabsf(v.z), fabsf(v.w)));
  }
  red[threadIdx.x] = m;
  __syncthreads();
  for (int s = THREADS / 2; s > 0; s >>= 1) {
    if (threadIdx.x < s) red[threadIdx.x] = fmaxf(red[threadIdx.x], red[threadIdx.x + s]);
    __syncthreads();
  }
  if (threadIdx.x == 0) atomicMax(slot, __float_as_uint(red[0]));
}

// Fold BN: ws = gamma*rsqrt(var+eps); quantize ws (8b sym); b = beta - mean*wq
__global__ __launch_bounds__(THREADS) void k_bnfold(const float* __restrict__ gamma,
                                                    const float* __restrict__ beta,
                                                    const float* __restrict__ mean,
                                                    const float* __restrict__ var,
                                                    float* __restrict__ wq, float* __restrict__ bb) {
  __shared__ float red[THREADS];
  int c = threadIdx.x;
  float ws = gamma[c] * (1.0f / sqrtf(var[c] + 1e-5f));
  red[c] = fabsf(ws);
  __syncthreads();
  for (int s = THREADS / 2; s > 0; s >>= 1) {
    if (c < s) red[c] = fmaxf(red[c], red[c + s]);
    __syncthreads();
  }
  float sws = fmaxf(red[0] / 127.0f, 1e-8f);
  float q = clamp8f(rintf(ws / sws)) * sws;
  wq[c] = q;
  bb[c] = beta[c] - mean[c] * q;
}

// Quantize x (NCHW f32) -> X8 (NHWC int8) via LDS transpose; coalesced both sides.
// One block per (n,h): 56 w x 128 c.
__global__ __launch_bounds__(THREADS) void k_qx(const float* __restrict__ x, int* __restrict__ X8,
                                                const unsigned* __restrict__ ISu) {
  __shared__ signed char tile[56 * 132];
  float s = sc_from_bits(ISu[0]);
  int b = blockIdx.x;  // 32*56
  int h = b % 56, n = b / 56;
  int t = threadIdx.x;
  const float* xp = x + ((n * 128) * 56 + h) * 56;
#pragma unroll
  for (int k = 0; k < 28; ++k) {
    int i = t + k * 256;  // < 7168
    int w = i % 56, c = i / 56;
    tile[w * 132 + c] = q8(xp[c * 3136 + w], s);
  }
  __syncthreads();
  int* op = X8 + (n * 56 + h) * 56 * 32;
#pragma unroll
  for (int k = 0; k < 7; ++k) {
    int i = t + k * 256;  // < 1792
    int w = i >> 5, c4 = (i & 31) * 4;
    const signed char* tp = tile + w * 132 + c4;
    op[i] = (int)(unsigned char)tp[0] | ((int)(unsigned char)tp[1] << 8) |
            ((int)(unsigned char)tp[2] << 16) | ((int)(unsigned char)tp[3] << 24);
  }
}

// Repack 3x3 weights into MFMA B-fragment order:
// Wm[(ks*16 + cotile)*64 + lane] = 16 bytes: co = cotile*16+(lane&15), ci = kc*64+(lane>>4)*16+j
// ks = tap*KC + kc, tap = kh*3+kw  (KC = cin/64)
__global__ __launch_bounds__(THREADS) void k_qw2m(const float* __restrict__ w, vi4* __restrict__ wm,
                                                  const unsigned* __restrict__ ISu) {
  int t = blockIdx.x * THREADS + threadIdx.x;  // < 36864
  float s = sc_from_bits(ISu[2]);
  int lane = t & 63;
  int cotile = (t >> 6) & 15;
  int ks = t >> 10;  // 0..35
  int tap = ks >> 2, kc = ks & 3;
  int kh = tap / 3, kw = tap % 3;
  int co = cotile * 16 + (lane & 15);
  int ci0 = kc * 64 + (lane >> 4) * 16;
  const float* src = w + (co * 256 + ci0) * 9 + kh * 3 + kw;
  int r[4];
#pragma unroll
  for (int q = 0; q < 4; ++q) {
    unsigned b0 = (unsigned char)q8(src[(q * 4 + 0) * 9], s);
    unsigned b1 = (unsigned char)q8(src[(q * 4 + 1) * 9], s);
    unsigned b2 = (unsigned char)q8(src[(q * 4 + 2) * 9], s);
    unsigned b3 = (unsigned char)q8(src[(q * 4 + 3) * 9], s);
    r[q] = (int)(b0 | (b1 << 8) | (b2 << 16) | (b3 << 24));
  }
  vi4 v = {r[0], r[1], r[2], r[3]};
  wm[t] = v;
}

__global__ __launch_bounds__(THREADS) void k_qw1m(const float* __restrict__ w, vi4* __restrict__ wm,
                                                  const unsigned* __restrict__ ISu) {
  int t = blockIdx.x * THREADS + threadIdx.x;  // < 18432
  float s = sc_from_bits(ISu[1]);
  int lane = t & 63;
  int cotile = (t >> 6) & 15;
  int ks = t >> 10;  // 0..17
  int tap = ks >> 1, kc = ks & 1;
  int kh = tap / 3, kw = tap % 3;
  int co = cotile * 16 + (lane & 15);
  int ci0 = kc * 64 + (lane >> 4) * 16;
  const float* src = w + (co * 128 + ci0) * 9 + kh * 3 + kw;
  int r[4];
#pragma unroll
  for (int q = 0; q < 4; ++q) {
    unsigned b0 = (unsigned char)q8(src[(q * 4 + 0) * 9], s);
    unsigned b1 = (unsigned char)q8(src[(q * 4 + 1) * 9], s);
    unsigned b2 = (unsigned char)q8(src[(q * 4 + 2) * 9], s);
    unsigned b3 = (unsigned char)q8(src[(q * 4 + 3) * 9], s);
    r[q] = (int)(b0 | (b1 << 8) | (b2 << 16) | (b3 << 24));
  }
  vi4 v = {r[0], r[1], r[2], r[3]};
  wm[t] = v;
}

__global__ __launch_bounds__(THREADS) void k_qwidm(const float* __restrict__ w,
                                                   vi4* __restrict__ wm,
                                                   const unsigned* __restrict__ ISu) {
  int t = blockIdx.x * THREADS + threadIdx.x;  // < 2048
  float s = sc_from_bits(ISu[3]);
  int lane = t & 63;
  int cotile = (t >> 6) & 15;
  int ks = t >> 10;  // 0..1
  int co = cotile * 16 + (lane & 15);
  int ci0 = ks * 64 + (lane >> 4) * 16;
  const float* src = w + co * 128 + ci0;
  int r[4];
#pragma unroll
  for (int q = 0; q < 4; ++q) {
    unsigned b0 = (unsigned char)q8(src[q * 4 + 0], s);
    unsigned b1 = (unsigned char)q8(src[q * 4 + 1], s);
    unsigned b2 = (unsigned char)q8(src[q * 4 + 2], s);
    unsigned b3 = (unsigned char)q8(src[q * 4 + 3], s);
    r[q] = (int)(b0 | (b1 << 8) | (b2 << 16) | (b3 << 24));
  }
  vi4 v = {r[0], r[1], r[2], r[3]};
  wm[t] = v;
}

// conv1 3x3 s2 p1 (Cin=128) + identity 1x1 s2, MFMA implicit GEMM.
// Block = (n, ho). LDS: 3 rows x 58 cols x 144B (pad; 16B-aligned stride).
// Wave: M=32 (2 tiles, wo<28 masked), N=64 (4 cotiles of 16).
__global__ __launch_bounds__(THREADS) void k_conv1(const int* __restrict__ X8,
                                                   const vi4* __restrict__ W1m,
                                                   const vi4* __restrict__ Widm,
                                                   int* __restrict__ H1, int* __restrict__ IDI,
                                                   int* __restrict__ maxv, int* __restrict__ minv,
                                                   int* __restrict__ maxabs_id) {
  __shared__ __align__(16) int lds[3 * 58 * 36];
  const int tid = threadIdx.x;
  const int n = blockIdx.x / 28, ho = blockIdx.x % 28;

  for (int kh = 0; kh < 3; ++kh) {
    int h = 2 * ho - 1 + kh;
    int* dst = lds + kh * 58 * 36;
    if (h >= 0 && h < 56) {
      const int* src = X8 + (n * 56 + h) * 56 * 32;
      for (int i = tid; i < 56 * 32; i += THREADS) {
        int col = i >> 5, c = i & 31;
        dst[(col + 1) * 36 + c] = src[i];
      }
      if (tid < 32) dst[tid] = 0;
      else if (tid >= 128 && tid < 160) dst[57 * 36 + (tid - 128)] = 0;
    } else {
      for (int i = tid; i < 58 * 36; i += THREADS) dst[i] = 0;
    }
  }
  __syncthreads();

  const int lane = tid & 63, wv = tid >> 6;
  const int lm = lane & 15, quad = lane >> 4;
  const int woc0 = lm;
  const int woc1 = (16 + lm) > 27 ? 27 : (16 + lm);
  const int choff = ((lane >> 4) << 2);  // quad*4 ints

  vi4 zero = {0, 0, 0, 0};
  vi4 acc[2][4], accid[2][4];
#pragma unroll
  for (int mt = 0; mt < 2; ++mt)
#pragma unroll
    for (int ct = 0; ct < 4; ++ct) {
      acc[mt][ct] = zero;
      accid[mt][ct] = zero;
    }

  const vi4* wbase = W1m + (wv * 4) * 64 + lane;
#pragma unroll 1
  for (int kh = 0; kh < 3; ++kh) {
    const int* lrow = lds + kh * 58 * 36;
#pragma unroll
    for (int kwkc = 0; kwkc < 6; ++kwkc) {
      int kw = kwkc >> 1, kc = kwkc & 1;
      int ks = (kh * 3 + kw) * 2 + kc;
      vi4 b0 = wbase[ks * 1024 + 0];
      vi4 b1 = wbase[ks * 1024 + 64];
      vi4 b2 = wbase[ks * 1024 + 128];
      vi4 b3 = wbase[ks * 1024 + 192];
      vi4 a0 = *(const vi4*)(lrow + (2 * woc0 + kw) * 36 + kc * 16 + choff);
      vi4 a1 = *(const vi4*)(lrow + (2 * woc1 + kw) * 36 + kc * 16 + choff);
      acc[0][0] = __builtin_amdgcn_mfma_i32_16x16x64_i8(a0, b0, acc[0][0], 0, 0, 0);
      acc[0][1] = __builtin_amdgcn_mfma_i32_16x16x64_i8(a0, b1, acc[0][1], 0, 0, 0);
      acc[0][2] = __builtin_amdgcn_mfma_i32_16x16x64_i8(a0, b2, acc[0][2], 0, 0, 0);
      acc[0][3] = __builtin_amdgcn_mfma_i32_16x16x64_i8(a0, b3, acc[0][3], 0, 0, 0);
      acc[1][0] = __builtin_amdgcn_mfma_i32_16x16x64_i8(a1, b0, acc[1][0], 0, 0, 0);
      acc[1][1] = __builtin_amdgcn_mfma_i32_16x16x64_i8(a1, b1, acc[1][1], 0, 0, 0);
      acc[1][2] = __builtin_amdgcn_mfma_i32_16x16x64_i8(a1, b2, acc[1][2], 0, 0, 0);
      acc[1][3] = __builtin_amdgcn_mfma_i32_16x16x64_i8(a1, b3, acc[1][3], 0, 0, 0);
    }
  }

  // identity: input row kh=1 (h=2ho), col 2*wo+1
  const vi4* wibase = Widm + (wv * 4) * 64 + lane;
#pragma unroll
  for (int kc = 0; kc < 2; ++kc) {
    vi4 b0 = wibase[kc * 1024 + 0];
    vi4 b1 = wibase[kc * 1024 + 64];
    vi4 b2 = wibase[kc * 1024 + 128];
    vi4 b3 = wibase[kc * 1024 + 192];
    const int* lrow = lds + 58 * 36;
    vi4 a0 = *(const vi4*)(lrow + (2 * woc0 + 1) * 36 + kc * 16 + choff);
    vi4 a1 = *(const vi4*)(lrow + (2 * woc1 + 1) * 36 + kc * 16 + choff);
    accid[0][0] = __builtin_amdgcn_mfma_i32_16x16x64_i8(a0, b0, accid[0][0], 0, 0, 0);
    accid[0][1] = __builtin_amdgcn_mfma_i32_16x16x64_i8(a0, b1, accid[0][1], 0, 0, 0);
    accid[0][2] = __builtin_amdgcn_mfma_i32_16x16x64_i8(a0, b2, accid[0][2], 0, 0, 0);
    accid[0][3] = __builtin_amdgcn_mfma_i32_16x16x64_i8(a0, b3, accid[0][3], 0, 0, 0);
    accid[1][0] = __builtin_amdgcn_mfma_i32_16x16x64_i8(a1, b0, accid[1][0], 0, 0, 0);
    accid[1][1] = __builtin_amdgcn_mfma_i32_16x16x64_i8(a1, b1, accid[1][1], 0, 0, 0);
    accid[1][2] = __builtin_amdgcn_mfma_i32_16x16x64_i8(a1, b2, accid[1][2], 0, 0, 0);
    accid[1][3] = __builtin_amdgcn_mfma_i32_16x16x64_i8(a1, b3, accid[1][3], 0, 0, 0);
  }

  const int obase = (n * 28 + ho) * 28 * 256;
  int am = 0;
#pragma unroll
  for (int ct = 0; ct < 4; ++ct) {
    const int co = wv * 64 + ct * 16 + lm;
    int vmax = INT_MIN, vmin = INT_MAX;
#pragma unroll
    for (int mt = 0; mt < 2; ++mt) {
#pragma unroll
      for (int r = 0; r < 4; ++r) {
        int wo = mt * 16 + quad * 4 + r;
        if (wo < 28) {
          int v = acc[mt][ct][r];
          H1[obase + wo * 256 + co] = v;
          vmax = max(vmax, v);
          vmin = min(vmin, v);
          int vi_ = accid[mt][ct][r];
          IDI[obase + wo * 256 + co] = vi_;
          am = max(am, vi_ < 0 ? -vi_ : vi_);
        }
      }
    }
    vmax = max(vmax, __shfl_xor(vmax, 16));
    vmax = max(vmax, __shfl_xor(vmax, 32));
    vmin = min(vmin, __shfl_xor(vmin, 16));
    vmin = min(vmin, __shfl_xor(vmin, 32));
    if (lane < 16) {
      atomicMax(&maxv[wv * 64 + ct * 16 + lane], vmax);
      atomicMin(&minv[wv * 64 + ct * 16 + lane], vmin);
    }
  }
#pragma unroll
  for (int k = 32; k >= 1; k >>= 1) am = max(am, __shfl_xor(am, k));
  if (lane == 0) atomicMax(maxabs_id, am);
}

// Derive stage-1 scales.
__global__ __launch_bounds__(THREADS) void k_s1(int* __restrict__ IS, float* __restrict__ SC,
                                                const int* __restrict__ maxv,
                                                const int* __restrict__ minv,
                                                const float* __restrict__ wq1,
                                                const float* __restrict__ b1) {
  __shared__ int ri[THREADS];
  __shared__ float rf[THREADS];
  int c = threadIdx.x;
  int vmax = maxv[c], vmin = minv[c];
  int a1 = vmax < 0 ? -vmax : vmax;
  int a0 = vmin < 0 ? -vmin : vmin;
  ri[c] = max(a1, a0);
  __syncthreads();
  for (int s = THREADS / 2; s > 0; s >>= 1) {
    if (c < s) ri[c] = max(ri[c], ri[c + s]);
    __syncthreads();
  }
  int mh1 = ri[0];
  const unsigned* ISu = (const unsigned*)IS;
  float sx = sc_from_bits(ISu[0]);
  float sw1 = sc_from_bits(ISu[1]);
  float sxw = sx * sw1;
  float s_h1 = fmaxf(sxw * (float)mh1 / 127.0f, 1e-8f);
  float wq = wq1[c], bbc = b1[c];
  float q1 = clamp8f(rintf((float)vmax * sxw / s_h1));
  float q0 = clamp8f(rintf((float)vmin * sxw / s_h1));
  float hv1 = q1 * s_h1, hv0 = q0 * s_h1;
  float y1 = fmaxf(hv1 * wq + bbc, 0.0f);
  float y0 = fmaxf(hv0 * wq + bbc, 0.0f);
  rf[c] = fmaxf(y1, y0);
  __syncthreads();
  for (int s = THREADS / 2; s > 0; s >>= 1) {
    if (c < s) rf[c] = fmaxf(rf[c], rf[c + s]);
    __syncthreads();
  }
  if (c == 0) {
    IS[4] = mh1;
    SC[7] = rf[0];
    SC[8] = s_h1;
    SC[9] = fmaxf(rf[0] / 127.0f, 1e-8f);
    float swid = sc_from_bits(ISu[3]);
    SC[10] = fmaxf(sx * swid * (float)IS[5] / 127.0f, 1e-8f);
  }
}

// quant(h1) -> bn1 -> relu -> quant => A2 int8 (NHWC)
__device__ __forceinline__ signed char qact(int v, float sxw, float s_h1, float s_y2, float wq,
                                            float bb) {
  float hf = (float)v * sxw;
  float q = clamp8f(rintf(hf / s_h1));
  float hv = q * s_h1;
  float y = fmaxf(hv * wq + bb, 0.0f);
  float a = fminf(fmaxf(rintf(y / s_y2), -128.0f), 127.0f);
  return (signed char)(int)a;
}

__global__ __launch_bounds__(THREADS) void k_qh1(const int4* __restrict__ H1,
                                                 char4* __restrict__ A2,
                                                 const float* __restrict__ SC,
                                                 const float* __restrict__ wq1,
                                                 const float* __restrict__ b1) {
  int t = blockIdx.x * THREADS + threadIdx.x;  // < 1,605,632
  const unsigned* ISu = (const unsigned*)SC;
  float sx = sc_from_bits(ISu[0]);
  float sw1 = sc_from_bits(ISu[1]);
  float sxw = sx * sw1;
  float s_h1 = SC[8];
  float s_y2 = SC[9];
  int4 v = H1[t];
  int c0 = (t * 4) & 255;
  char4 r;
  r.x = qact(v.x, sxw, s_h1, s_y2, wq1[c0], b1[c0]);
  r.y = qact(v.y, sxw, s_h1, s_y2, wq1[c0 + 1], b1[c0 + 1]);
  r.z = qact(v.z, sxw, s_h1, s_y2, wq1[c0 + 2], b1[c0 + 2]);
  r.w = qact(v.w, sxw, s_h1, s_y2, wq1[c0 + 3], b1[c0 + 3]);
  A2[t] = r;
}

// conv2 3x3 s1 p1 (Cin=256), MFMA implicit GEMM. Block = (n, ho).
// LDS: 3 rows x 30 cols x 272B (pad; 16B-aligned stride).
__global__ __launch_bounds__(THREADS) void k_conv2(const int* __restrict__ A2,
                                                   const vi4* __restrict__ W2m,
                                                   int* __restrict__ H2,
                                                   int* __restrict__ maxabs_h2) {
  __shared__ __align__(16) int lds[3 * 30 * 68];
  const int tid = threadIdx.x;
  const int n = blockIdx.x / 28, ho = blockIdx.x % 28;

  for (int kh = 0; kh < 3; ++kh) {
    int h = ho - 1 + kh;
    int* dst = lds + kh * 30 * 68;
    if (h >= 0 && h < 28) {
      const int* src = A2 + (n * 28 + h) * 28 * 64;
      for (int i = tid; i < 28 * 64; i += THREADS) {
        int col = i >> 6, c = i & 63;
        dst[(col + 1) * 68 + c] = src[i];
      }
      if (tid < 64) dst[tid] = 0;
      else if (tid >= 128 && tid < 192) dst[29 * 68 + (tid - 128)] = 0;
    } else {
      for (int i = tid; i < 30 * 68; i += THREADS) dst[i] = 0;
    }
  }
  __syncthreads();

  const int lane = tid & 63, wv = tid >> 6;
  const int lm = lane & 15, quad = lane >> 4;
  const int woc0 = lm;
  const int woc1 = (16 + lm) > 27 ? 27 : (16 + lm);
  const int choff = ((lane >> 4) << 2);

  vi4 zero = {0, 0, 0, 0};
  vi4 acc[2][4];
#pragma unroll
  for (int mt = 0; mt < 2; ++mt)
#pragma unroll
    for (int ct = 0; ct < 4; ++ct) acc[mt][ct] = zero;

  const vi4* wbase = W2m + (wv * 4) * 64 + lane;
#pragma unroll 1
  for (int kh = 0; kh < 3; ++kh) {
    const int* lrow = lds + kh * 30 * 68;
#pragma unroll
    for (int kwkc = 0; kwkc < 12; ++kwkc) {
      int kw = kwkc >> 2, kc = kwkc & 3;
      int ks = (kh * 3 + kw) * 4 + kc;
      vi4 b0 = wbase[ks * 1024 + 0];
      vi4 b1 = wbase[ks * 1024 + 64];
      vi4 b2 = wbase[ks * 1024 + 128];
      vi4 b3 = wbase[ks * 1024 + 192];
      vi4 a0 = *(const vi4*)(lrow + (woc0 + kw) * 68 + kc * 16 + choff);
      vi4 a1 = *(const vi4*)(lrow + (woc1 + kw) * 68 + kc * 16 + choff);
      acc[0][0] = __builtin_amdgcn_mfma_i32_16x16x64_i8(a0, b0, acc[0][0], 0, 0, 0);
      acc[0][1] = __builtin_amdgcn_mfma_i32_16x16x64_i8(a0, b1, acc[0][1], 0, 0, 0);
      acc[0][2] = __builtin_amdgcn_mfma_i32_16x16x64_i8(a0, b2, acc[0][2], 0, 0, 0);
      acc[0][3] = __builtin_amdgcn_mfma_i32_16x16x64_i8(a0, b3, acc[0][3], 0, 0, 0);
      acc[1][0] = __builtin_amdgcn_mfma_i32_16x16x64_i8(a1, b0, acc[1][0], 0, 0, 0);
      acc[1][1] = __builtin_amdgcn_mfma_i32_16x16x64_i8(a1, b1, acc[1][1], 0, 0, 0);
      acc[1][2] = __builtin_amdgcn_mfma_i32_16x16x64_i8(a1, b2, acc[1][2], 0, 0, 0);
      acc[1][3] = __builtin_amdgcn_mfma_i32_16x16x64_i8(a1, b3, acc[1][3], 0, 0, 0);
    }
  }

  const int obase = (n * 28 + ho) * 28 * 256;
  int am = 0;
#pragma unroll
  for (int ct = 0; ct < 4; ++ct) {
    const int co = wv * 64 + ct * 16 + lm;
#pragma unroll
    for (int mt = 0; mt < 2; ++mt) {
#pragma unroll
      for (int r = 0; r < 4; ++r) {
        int wo = mt * 16 + quad * 4 + r;
        if (wo < 28) {
          int v = acc[mt][ct][r];
          H2[obase + wo * 256 + co] = v;
          am = max(am, v < 0 ? -v : v);
        }
      }
    }
  }
#pragma unroll
  for (int k = 32; k >= 1; k >>= 1) am = max(am, __shfl_xor(am, k));
  if (lane == 0) atomicMax(maxabs_h2, am);
}

// ---- residual sum math shared by k_absmax2 / k_out ----
struct SumParams {
  float sxw2, s_h2, sxwid, s_idq;
};
__device__ __forceinline__ float sum_val(int v2, int vi, const SumParams& P, float wq2c, float b2c,
                                         float wqidc, float bidc) {
  float q2 = clamp8f(rintf((float)v2 * P.sxw2 / P.s_h2));
  float z = (q2 * P.s_h2) * wq2c + b2c;
  float qi = clamp8f(rintf((float)vi * P.sxwid / P.s_idq));
  float zi = (qi * P.s_idq) * wqidc + bidc;
  return z + zi;
}
__device__ __forceinline__ SumParams make_params(const float* SC, const int* IS) {
  const unsigned* ISu = (const unsigned*)IS;
  SumParams P;
  float sx = sc_from_bits(ISu[0]);
  float sw2 = sc_from_bits(ISu[2]);
  float swid = sc_from_bits(ISu[3]);
  float s_y2 = SC[9];
  P.s_idq = SC[10];
  P.sxw2 = s_y2 * sw2;
  P.s_h2 = fmaxf(P.sxw2 * (float)IS[6] / 127.0f, 1e-8f);
  P.sxwid = sx * swid;
  return P;
}

// Pass 1: global absmax of (quant(h2)·bn2 + quant(id)·bn_id). Fully coalesced.
__global__ __launch_bounds__(THREADS) void k_absmax2(const int4* __restrict__ H2,
                                                     const int4* __restrict__ IDI,
                                                     const float* __restrict__ SC,
                                                     const int* __restrict__ IS,
                                                     const float* __restrict__ wq2,
                                                     const float* __restrict__ b2,
                                                     const float* __restrict__ wqid,
                                                     const float* __restrict__ bidp,
                                                     unsigned* __restrict__ slot) {
  __shared__ float red[THREADS];
  __shared__ float pw2[256], pb2[256], pwi[256], pbi[256];
  int tid = threadIdx.x;
  pw2[tid] = wq2[tid];
  pb2[tid] = b2[tid];
  pwi[tid] = wqid[tid];
  pbi[tid] = bidp[tid];
  __syncthreads();
  SumParams P = make_params(SC, IS);
  int i = blockIdx.x * THREADS + tid;  // < 1,605,632
  int4 v2 = H2[i];
  int4 vi = IDI[i];
  int c0 = (i * 4) & 255;
  float m = fabsf(sum_val(v2.x, vi.x, P, pw2[c0], pb2[c0], pwi[c0], pbi[c0]));
  m = fmaxf(m, fabsf(sum_val(v2.y, vi.y, P, pw2[c0 + 1], pb2[c0 + 1], pwi[c0 + 1], pbi[c0 + 1])));
  m = fmaxf(m, fabsf(sum_val(v2.z, vi.z, P, pw2[c0 + 2], pb2[c0 + 2], pwi[c0 + 2], pbi[c0 + 2])));
  m = fmaxf(m, fabsf(sum_val(v2.w, vi.w, P, pw2[c0 + 3], pb2[c0 + 3], pwi[c0 + 3], pbi[c0 + 3])));
  red[tid] = m;
  __syncthreads();
  for (int s = THREADS / 2; s > 0; s >>= 1) {
    if (tid < s) red[tid] = fmaxf(red[tid], red[tid + s]);
    __syncthreads();
  }
  if (tid == 0) atomicMax(slot, __float_as_uint(red[0]));
}

// Pass 2: recompute sum, final requant + relu, write NCHW via padded LDS tile transpose.
__global__ __launch_bounds__(THREADS) void k_out(const int* __restrict__ H2,
                                                 const int* __restrict__ IDI,
                                                 const float* __restrict__ SC,
                                                 const int* __restrict__ IS,
                                                 const float* __restrict__ wq2,
                                                 const float* __restrict__ b2,
                                                 const float* __restrict__ wqid,
                                                 const float* __restrict__ bidp,
                                                 float* __restrict__ out) {
  __shared__ float tile[64 * 57];
  __shared__ float pw2[64], pb2[64], pwi[64], pbi[64];
  int tid = threadIdx.x;
  int b = blockIdx.x;
  int ct = b & 3;
  int rt = (b >> 2) % 14;
  int n = b / 56;
  int c0 = ct * 64;
  int r0 = rt * 56;
  if (tid < 64) {
    pw2[tid] = wq2[c0 + tid];
    pb2[tid] = b2[c0 + tid];
    pwi[tid] = wqid[c0 + tid];
    pbi[tid] = bidp[c0 + tid];
  }
  __syncthreads();
  SumParams P = make_params(SC, IS);
  float out_s = fmaxf(__uint_as_float(((const unsigned*)IS)[11]) / 127.0f, 1e-8f);

  const int base = (n * 784 + r0) * 256 + c0;
#pragma unroll
  for (int k = 0; k < 14; ++k) {
    int idx = tid + k * 256;  // < 3584
    int rl = idx >> 6;
    int cl = idx & 63;
    int e = base + rl * 256 + cl;
    float sv = sum_val(H2[e], IDI[e], P, pw2[cl], pb2[cl], pwi[cl], pbi[cl]);
    float q = clamp8f(rintf(sv / out_s));
    tile[cl * 57 + rl] = q > 0.0f ? q * out_s : 0.0f;
  }
  __syncthreads();
  float* ob = out + n * 200704 + c0 * 784 + r0;
#pragma unroll
  for (int k = 0; k < 14; ++k) {
    int idx = tid + k * 256;
    int cl = idx / 56;
    int rl = idx % 56;
    ob[cl * 784 + rl] = tile[cl * 57 + rl];
  }
  if (b == 0 && tid == 0) out[6422528] = out_s;
}

extern "C" void kernel_launch(void* const* d_in, const int* in_sizes, int n_in, void* d_out,
                              int out_size, void* d_ws, size_t ws_size, hipStream_t stream) {
  (void)in_sizes; (void)n_in; (void)out_size; (void)ws_size;
  const float* x = (const float*)d_in[0];
  const float* w1 = (const float*)d_in[1];
  const float* w2 = (const float*)d_in[2];
  const float* wid = (const float*)d_in[3];
  const float* bn1g = (const float*)d_in[4];
  const float* bn1b = (const float*)d_in[5];
  const float* bn1m = (const float*)d_in[6];
  const float* bn1v = (const float*)d_in[7];
  const float* bn2g = (const float*)d_in[8];
  const float* bn2b = (const float*)d_in[9];
  const float* bn2m = (const float*)d_in[10];
  const float* bn2v = (const float*)d_in[11];
  const float* idg = (const float*)d_in[12];
  const float* idb = (const float*)d_in[13];
  const float* idm = (const float*)d_in[14];
  const float* idv = (const float*)d_in[15];

  char* ws = (char*)d_ws;
  float* SC = (float*)ws;
  int* IS = (int*)ws;
  unsigned* ISu = (unsigned*)ws;
  int* maxv = (int*)(ws + 1024);
  int* minv = (int*)(ws + 2048);
  float* wq1 = (float*)(ws + 3072);
  float* b1 = (float*)(ws + 4096);
  float* wq2 = (float*)(ws + 5120);
  float* b2 = (float*)(ws + 6144);
  float* wqid = (float*)(ws + 7168);
  float* bid = (float*)(ws + 8192);
  char* X8 = ws + 16384;                 // 12,845,056 B (NHWC int8); A2 overlays after conv1
  char* A2 = X8;                         // 6,422,528 B
  char* W1m = X8 + 12845056;             // 294,912 B (MFMA B-fragment order)
  char* W2m = W1m + 294912;              // 589,824 B
  char* Widm = W2m + 589824;             // 32,768 B
  int* H1 = (int*)(Widm + 32768);        // 25,690,112 B; H2 overlays after k_qh1
  int* H2 = H1;
  int* IDI = (int*)((char*)H1 + 25690112);  // 25,690,112 B
  float* out = (float*)d_out;

  k_init<<<1, THREADS, 0, stream>>>(IS, maxv, minv);
  k_amax<<<12544, THREADS, 0, stream>>>((const float4*)x, 3211264, ISu + 0);
  k_amax<<<288, THREADS, 0, stream>>>((const float4*)w1, 73728, ISu + 1);
  k_amax<<<576, THREADS, 0, stream>>>((const float4*)w2, 147456, ISu + 2);
  k_amax<<<32, THREADS, 0, stream>>>((const float4*)wid, 8192, ISu + 3);
  k_bnfold<<<1, THREADS, 0, stream>>>(bn1g, bn1b, bn1m, bn1v, wq1, b1);
  k_bnfold<<<1, THREADS, 0, stream>>>(bn2g, bn2b, bn2m, bn2v, wq2, b2);
  k_bnfold<<<1, THREADS, 0, stream>>>(idg, idb, idm, idv, wqid, bid);
  k_qx<<<1792, THREADS, 0, stream>>>(x, (int*)X8, ISu);
  k_qw1m<<<72, THREADS, 0, stream>>>(w1, (vi4*)W1m, ISu);
  k_qw2m<<<144, THREADS, 0, stream>>>(w2, (vi4*)W2m, ISu);
  k_qwidm<<<8, THREADS, 0, stream>>>(wid, (vi4*)Widm, ISu);
  k_conv1<<<896, THREADS, 0, stream>>>((const int*)X8, (const vi4*)W1m, (const vi4*)Widm, H1, IDI,
                                       maxv, minv, IS + 5);
  k_s1<<<1, THREADS, 0, stream>>>(IS, SC, maxv, minv, wq1, b1);
  k_qh1<<<6272, THREADS, 0, stream>>>((const int4*)H1, (char4*)A2, SC, wq1, b1);
  k_conv2<<<896, THREADS, 0, stream>>>((const int*)A2, (const vi4*)W2m, H2, IS + 6);
  k_absmax2<<<6272, THREADS, 0, stream>>>((const int4*)H2, (const int4*)IDI, SC, IS, wq2, b2, wqid,
                                          bid, ISu + 11);
  k_out<<<1792, THREADS, 0, stream>>>(H2, IDI, SC, IS, wq2, b2, wqid, bid, out);
}

// Round 4
// 327.730 us; speedup vs baseline: 2.7819x; 1.6076x over previous
//
#include <hip/hip_runtime.h>
#include <limits.h>

#define THREADS 256

typedef int vi4 __attribute__((ext_vector_type(4)));

__device__ __forceinline__ float clamp8f(float q) { return fminf(fmaxf(q, -128.0f), 127.0f); }
__device__ __forceinline__ float sc_from_bits(unsigned b) {
  return fmaxf(__uint_as_float(b) / 127.0f, 1e-8f);
}
__device__ __forceinline__ signed char q8(float v, float s) {
  return (signed char)(int)clamp8f(rintf(v / s));
}

// Scalar slots (int/float view of ws base):
// [0] amax_x bits  [1] amax_w1 bits  [2] amax_w2 bits  [3] amax_wid bits
// [4] maxabs_h1(int) [5] maxabs_id(int) [6] maxabs_h2(int)
// [7] max_y2(float) [8] s_h1 [9] s_y2 [10] s_idq [11] amax_sum bits

__global__ __launch_bounds__(THREADS) void k_init(int* IS, int* maxv, int* minv) {
  int t = threadIdx.x;
  if (t < 64) IS[t] = 0;
  maxv[t] = INT_MIN;
  minv[t] = INT_MAX;
}

// Grid-stride absmax: 4-way unrolled float4 loads, shfl reduce, 1 atomic/block.
__global__ __launch_bounds__(THREADS) void k_amax(const float4* __restrict__ p, int n4,
                                                  unsigned* __restrict__ slot) {
  const int tid = threadIdx.x;
  const int stride = gridDim.x * THREADS;
  float m = 0.0f;
  int i = blockIdx.x * THREADS + tid;
  for (; i + 3 * stride < n4; i += 4 * stride) {
    float4 v0 = p[i];
    float4 v1 = p[i + stride];
    float4 v2 = p[i + 2 * stride];
    float4 v3 = p[i + 3 * stride];
    float m0 = fmaxf(fmaxf(fabsf(v0.x), fabsf(v0.y)), fmaxf(fabsf(v0.z), fabsf(v0.w)));
    float m1 = fmaxf(fmaxf(fabsf(v1.x), fabsf(v1.y)), fmaxf(fabsf(v1.z), fabsf(v1.w)));
    float m2 = fmaxf(fmaxf(fabsf(v2.x), fabsf(v2.y)), fmaxf(fabsf(v2.z), fabsf(v2.w)));
    float m3 = fmaxf(fmaxf(fabsf(v3.x), fabsf(v3.y)), fmaxf(fabsf(v3.z), fabsf(v3.w)));
    m = fmaxf(m, fmaxf(fmaxf(m0, m1), fmaxf(m2, m3)));
  }
  for (; i < n4; i += stride) {
    float4 v = p[i];
    m = fmaxf(m, fmaxf(fmaxf(fabsf(v.x), fabsf(v.y)), fmaxf(fabsf(v.z), fabsf(v.w))));
  }
#pragma unroll
  for (int k = 32; k >= 1; k >>= 1) m = fmaxf(m, __shfl_xor(m, k));
  __shared__ float wred[4];
  if ((tid & 63) == 0) wred[tid >> 6] = m;
  __syncthreads();
  if (tid == 0) {
    m = fmaxf(fmaxf(wred[0], wred[1]), fmaxf(wred[2], wred[3]));
    atomicMax(slot, __float_as_uint(m));
  }
}

// Fold BN: ws = gamma*rsqrt(var+eps); quantize ws (8b sym); b = beta - mean*wq
__global__ __launch_bounds__(THREADS) void k_bnfold(const float* __restrict__ gamma,
                                                    const float* __restrict__ beta,
                                                    const float* __restrict__ mean,
                                                    const float* __restrict__ var,
                                                    float* __restrict__ wq, float* __restrict__ bb) {
  __shared__ float red[THREADS];
  int c = threadIdx.x;
  float ws = gamma[c] * (1.0f / sqrtf(var[c] + 1e-5f));
  red[c] = fabsf(ws);
  __syncthreads();
  for (int s = THREADS / 2; s > 0; s >>= 1) {
    if (c < s) red[c] = fmaxf(red[c], red[c + s]);
    __syncthreads();
  }
  float sws = fmaxf(red[0] / 127.0f, 1e-8f);
  float q = clamp8f(rintf(ws / sws)) * sws;
  wq[c] = q;
  bb[c] = beta[c] - mean[c] * q;
}

// Quantize x (NCHW f32) -> X8 (NHWC int8) via LDS transpose; coalesced both sides.
// One block per (n,h): 56 w x 128 c.
__global__ __launch_bounds__(THREADS) void k_qx(const float* __restrict__ x, int* __restrict__ X8,
                                                const unsigned* __restrict__ ISu) {
  __shared__ signed char tile[56 * 132];
  float s = sc_from_bits(ISu[0]);
  int b = blockIdx.x;  // 32*56
  int h = b % 56, n = b / 56;
  int t = threadIdx.x;
  const float* xp = x + ((n * 128) * 56 + h) * 56;
#pragma unroll
  for (int k = 0; k < 28; ++k) {
    int i = t + k * 256;  // < 7168
    int w = i % 56, c = i / 56;
    tile[w * 132 + c] = q8(xp[c * 3136 + w], s);
  }
  __syncthreads();
  int* op = X8 + (n * 56 + h) * 56 * 32;
#pragma unroll
  for (int k = 0; k < 7; ++k) {
    int i = t + k * 256;  // < 1792
    int w = i >> 5, c4 = (i & 31) * 4;
    const signed char* tp = tile + w * 132 + c4;
    op[i] = (int)(unsigned char)tp[0] | ((int)(unsigned char)tp[1] << 8) |
            ((int)(unsigned char)tp[2] << 16) | ((int)(unsigned char)tp[3] << 24);
  }
}

// Repack 3x3 weights into MFMA B-fragment order:
// Wm[(ks*16 + cotile)*64 + lane] = 16 bytes: co = cotile*16+(lane&15), ci = kc*64+(lane>>4)*16+j
// ks = tap*KC + kc, tap = kh*3+kw  (KC = cin/64)
__global__ __launch_bounds__(THREADS) void k_qw2m(const float* __restrict__ w, vi4* __restrict__ wm,
                                                  const unsigned* __restrict__ ISu) {
  int t = blockIdx.x * THREADS + threadIdx.x;  // < 36864
  float s = sc_from_bits(ISu[2]);
  int lane = t & 63;
  int cotile = (t >> 6) & 15;
  int ks = t >> 10;  // 0..35
  int tap = ks >> 2, kc = ks & 3;
  int kh = tap / 3, kw = tap % 3;
  int co = cotile * 16 + (lane & 15);
  int ci0 = kc * 64 + (lane >> 4) * 16;
  const float* src = w + (co * 256 + ci0) * 9 + kh * 3 + kw;
  int r[4];
#pragma unroll
  for (int q = 0; q < 4; ++q) {
    unsigned b0 = (unsigned char)q8(src[(q * 4 + 0) * 9], s);
    unsigned b1 = (unsigned char)q8(src[(q * 4 + 1) * 9], s);
    unsigned b2 = (unsigned char)q8(src[(q * 4 + 2) * 9], s);
    unsigned b3 = (unsigned char)q8(src[(q * 4 + 3) * 9], s);
    r[q] = (int)(b0 | (b1 << 8) | (b2 << 16) | (b3 << 24));
  }
  vi4 v = {r[0], r[1], r[2], r[3]};
  wm[t] = v;
}

__global__ __launch_bounds__(THREADS) void k_qw1m(const float* __restrict__ w, vi4* __restrict__ wm,
                                                  const unsigned* __restrict__ ISu) {
  int t = blockIdx.x * THREADS + threadIdx.x;  // < 18432
  float s = sc_from_bits(ISu[1]);
  int lane = t & 63;
  int cotile = (t >> 6) & 15;
  int ks = t >> 10;  // 0..17
  int tap = ks >> 1, kc = ks & 1;
  int kh = tap / 3, kw = tap % 3;
  int co = cotile * 16 + (lane & 15);
  int ci0 = kc * 64 + (lane >> 4) * 16;
  const float* src = w + (co * 128 + ci0) * 9 + kh * 3 + kw;
  int r[4];
#pragma unroll
  for (int q = 0; q < 4; ++q) {
    unsigned b0 = (unsigned char)q8(src[(q * 4 + 0) * 9], s);
    unsigned b1 = (unsigned char)q8(src[(q * 4 + 1) * 9], s);
    unsigned b2 = (unsigned char)q8(src[(q * 4 + 2) * 9], s);
    unsigned b3 = (unsigned char)q8(src[(q * 4 + 3) * 9], s);
    r[q] = (int)(b0 | (b1 << 8) | (b2 << 16) | (b3 << 24));
  }
  vi4 v = {r[0], r[1], r[2], r[3]};
  wm[t] = v;
}

__global__ __launch_bounds__(THREADS) void k_qwidm(const float* __restrict__ w,
                                                   vi4* __restrict__ wm,
                                                   const unsigned* __restrict__ ISu) {
  int t = blockIdx.x * THREADS + threadIdx.x;  // < 2048
  float s = sc_from_bits(ISu[3]);
  int lane = t & 63;
  int cotile = (t >> 6) & 15;
  int ks = t >> 10;  // 0..1
  int co = cotile * 16 + (lane & 15);
  int ci0 = ks * 64 + (lane >> 4) * 16;
  const float* src = w + co * 128 + ci0;
  int r[4];
#pragma unroll
  for (int q = 0; q < 4; ++q) {
    unsigned b0 = (unsigned char)q8(src[q * 4 + 0], s);
    unsigned b1 = (unsigned char)q8(src[q * 4 + 1], s);
    unsigned b2 = (unsigned char)q8(src[q * 4 + 2], s);
    unsigned b3 = (unsigned char)q8(src[q * 4 + 3], s);
    r[q] = (int)(b0 | (b1 << 8) | (b2 << 16) | (b3 << 24));
  }
  vi4 v = {r[0], r[1], r[2], r[3]};
  wm[t] = v;
}

// conv1 3x3 s2 p1 (Cin=128) + identity 1x1 s2, MFMA implicit GEMM.
// Block = (n, ho). LDS: 3 rows x 58 cols x 144B (pad; 16B-aligned stride).
// Wave: M=32 (2 tiles, wo<28 masked), N=64 (4 cotiles of 16).
__global__ __launch_bounds__(THREADS) void k_conv1(const int* __restrict__ X8,
                                                   const vi4* __restrict__ W1m,
                                                   const vi4* __restrict__ Widm,
                                                   int* __restrict__ H1, int* __restrict__ IDI,
                                                   int* __restrict__ maxv, int* __restrict__ minv,
                                                   int* __restrict__ maxabs_id) {
  __shared__ __align__(16) int lds[3 * 58 * 36];
  const int tid = threadIdx.x;
  const int n = blockIdx.x / 28, ho = blockIdx.x % 28;

  for (int kh = 0; kh < 3; ++kh) {
    int h = 2 * ho - 1 + kh;
    int* dst = lds + kh * 58 * 36;
    if (h >= 0 && h < 56) {
      const int* src = X8 + (n * 56 + h) * 56 * 32;
      for (int i = tid; i < 56 * 32; i += THREADS) {
        int col = i >> 5, c = i & 31;
        dst[(col + 1) * 36 + c] = src[i];
      }
      if (tid < 32) dst[tid] = 0;
      else if (tid >= 128 && tid < 160) dst[57 * 36 + (tid - 128)] = 0;
    } else {
      for (int i = tid; i < 58 * 36; i += THREADS) dst[i] = 0;
    }
  }
  __syncthreads();

  const int lane = tid & 63, wv = tid >> 6;
  const int lm = lane & 15, quad = lane >> 4;
  const int woc0 = lm;
  const int woc1 = (16 + lm) > 27 ? 27 : (16 + lm);
  const int choff = ((lane >> 4) << 2);  // quad*4 ints

  vi4 zero = {0, 0, 0, 0};
  vi4 acc[2][4], accid[2][4];
#pragma unroll
  for (int mt = 0; mt < 2; ++mt)
#pragma unroll
    for (int ct = 0; ct < 4; ++ct) {
      acc[mt][ct] = zero;
      accid[mt][ct] = zero;
    }

  const vi4* wbase = W1m + (wv * 4) * 64 + lane;
#pragma unroll 1
  for (int kh = 0; kh < 3; ++kh) {
    const int* lrow = lds + kh * 58 * 36;
#pragma unroll
    for (int kwkc = 0; kwkc < 6; ++kwkc) {
      int kw = kwkc >> 1, kc = kwkc & 1;
      int ks = (kh * 3 + kw) * 2 + kc;
      vi4 b0 = wbase[ks * 1024 + 0];
      vi4 b1 = wbase[ks * 1024 + 64];
      vi4 b2 = wbase[ks * 1024 + 128];
      vi4 b3 = wbase[ks * 1024 + 192];
      vi4 a0 = *(const vi4*)(lrow + (2 * woc0 + kw) * 36 + kc * 16 + choff);
      vi4 a1 = *(const vi4*)(lrow + (2 * woc1 + kw) * 36 + kc * 16 + choff);
      acc[0][0] = __builtin_amdgcn_mfma_i32_16x16x64_i8(a0, b0, acc[0][0], 0, 0, 0);
      acc[0][1] = __builtin_amdgcn_mfma_i32_16x16x64_i8(a0, b1, acc[0][1], 0, 0, 0);
      acc[0][2] = __builtin_amdgcn_mfma_i32_16x16x64_i8(a0, b2, acc[0][2], 0, 0, 0);
      acc[0][3] = __builtin_amdgcn_mfma_i32_16x16x64_i8(a0, b3, acc[0][3], 0, 0, 0);
      acc[1][0] = __builtin_amdgcn_mfma_i32_16x16x64_i8(a1, b0, acc[1][0], 0, 0, 0);
      acc[1][1] = __builtin_amdgcn_mfma_i32_16x16x64_i8(a1, b1, acc[1][1], 0, 0, 0);
      acc[1][2] = __builtin_amdgcn_mfma_i32_16x16x64_i8(a1, b2, acc[1][2], 0, 0, 0);
      acc[1][3] = __builtin_amdgcn_mfma_i32_16x16x64_i8(a1, b3, acc[1][3], 0, 0, 0);
    }
  }

  // identity: input row kh=1 (h=2ho), col 2*wo+1
  const vi4* wibase = Widm + (wv * 4) * 64 + lane;
#pragma unroll
  for (int kc = 0; kc < 2; ++kc) {
    vi4 b0 = wibase[kc * 1024 + 0];
    vi4 b1 = wibase[kc * 1024 + 64];
    vi4 b2 = wibase[kc * 1024 + 128];
    vi4 b3 = wibase[kc * 1024 + 192];
    const int* lrow = lds + 58 * 36;
    vi4 a0 = *(const vi4*)(lrow + (2 * woc0 + 1) * 36 + kc * 16 + choff);
    vi4 a1 = *(const vi4*)(lrow + (2 * woc1 + 1) * 36 + kc * 16 + choff);
    accid[0][0] = __builtin_amdgcn_mfma_i32_16x16x64_i8(a0, b0, accid[0][0], 0, 0, 0);
    accid[0][1] = __builtin_amdgcn_mfma_i32_16x16x64_i8(a0, b1, accid[0][1], 0, 0, 0);
    accid[0][2] = __builtin_amdgcn_mfma_i32_16x16x64_i8(a0, b2, accid[0][2], 0, 0, 0);
    accid[0][3] = __builtin_amdgcn_mfma_i32_16x16x64_i8(a0, b3, accid[0][3], 0, 0, 0);
    accid[1][0] = __builtin_amdgcn_mfma_i32_16x16x64_i8(a1, b0, accid[1][0], 0, 0, 0);
    accid[1][1] = __builtin_amdgcn_mfma_i32_16x16x64_i8(a1, b1, accid[1][1], 0, 0, 0);
    accid[1][2] = __builtin_amdgcn_mfma_i32_16x16x64_i8(a1, b2, accid[1][2], 0, 0, 0);
    accid[1][3] = __builtin_amdgcn_mfma_i32_16x16x64_i8(a1, b3, accid[1][3], 0, 0, 0);
  }

  const int obase = (n * 28 + ho) * 28 * 256;
  int am = 0;
#pragma unroll
  for (int ct = 0; ct < 4; ++ct) {
    const int co = wv * 64 + ct * 16 + lm;
    int vmax = INT_MIN, vmin = INT_MAX;
#pragma unroll
    for (int mt = 0; mt < 2; ++mt) {
#pragma unroll
      for (int r = 0; r < 4; ++r) {
        int wo = mt * 16 + quad * 4 + r;
        if (wo < 28) {
          int v = acc[mt][ct][r];
          H1[obase + wo * 256 + co] = v;
          vmax = max(vmax, v);
          vmin = min(vmin, v);
          int vi_ = accid[mt][ct][r];
          IDI[obase + wo * 256 + co] = vi_;
          am = max(am, vi_ < 0 ? -vi_ : vi_);
        }
      }
    }
    vmax = max(vmax, __shfl_xor(vmax, 16));
    vmax = max(vmax, __shfl_xor(vmax, 32));
    vmin = min(vmin, __shfl_xor(vmin, 16));
    vmin = min(vmin, __shfl_xor(vmin, 32));
    if (lane < 16) {
      atomicMax(&maxv[wv * 64 + ct * 16 + lane], vmax);
      atomicMin(&minv[wv * 64 + ct * 16 + lane], vmin);
    }
  }
#pragma unroll
  for (int k = 32; k >= 1; k >>= 1) am = max(am, __shfl_xor(am, k));
  if (lane == 0) atomicMax(maxabs_id, am);
}

// Derive stage-1 scales.
__global__ __launch_bounds__(THREADS) void k_s1(int* __restrict__ IS, float* __restrict__ SC,
                                                const int* __restrict__ maxv,
                                                const int* __restrict__ minv,
                                                const float* __restrict__ wq1,
                                                const float* __restrict__ b1) {
  __shared__ int ri[THREADS];
  __shared__ float rf[THREADS];
  int c = threadIdx.x;
  int vmax = maxv[c], vmin = minv[c];
  int a1 = vmax < 0 ? -vmax : vmax;
  int a0 = vmin < 0 ? -vmin : vmin;
  ri[c] = max(a1, a0);
  __syncthreads();
  for (int s = THREADS / 2; s > 0; s >>= 1) {
    if (c < s) ri[c] = max(ri[c], ri[c + s]);
    __syncthreads();
  }
  int mh1 = ri[0];
  const unsigned* ISu = (const unsigned*)IS;
  float sx = sc_from_bits(ISu[0]);
  float sw1 = sc_from_bits(ISu[1]);
  float sxw = sx * sw1;
  float s_h1 = fmaxf(sxw * (float)mh1 / 127.0f, 1e-8f);
  float wq = wq1[c], bbc = b1[c];
  float q1 = clamp8f(rintf((float)vmax * sxw / s_h1));
  float q0 = clamp8f(rintf((float)vmin * sxw / s_h1));
  float hv1 = q1 * s_h1, hv0 = q0 * s_h1;
  float y1 = fmaxf(hv1 * wq + bbc, 0.0f);
  float y0 = fmaxf(hv0 * wq + bbc, 0.0f);
  rf[c] = fmaxf(y1, y0);
  __syncthreads();
  for (int s = THREADS / 2; s > 0; s >>= 1) {
    if (c < s) rf[c] = fmaxf(rf[c], rf[c + s]);
    __syncthreads();
  }
  if (c == 0) {
    IS[4] = mh1;
    SC[7] = rf[0];
    SC[8] = s_h1;
    SC[9] = fmaxf(rf[0] / 127.0f, 1e-8f);
    float swid = sc_from_bits(ISu[3]);
    SC[10] = fmaxf(sx * swid * (float)IS[5] / 127.0f, 1e-8f);
  }
}

// quant(h1) -> bn1 -> relu -> quant => A2 int8 (NHWC)
__device__ __forceinline__ signed char qact(int v, float sxw, float s_h1, float s_y2, float wq,
                                            float bb) {
  float hf = (float)v * sxw;
  float q = clamp8f(rintf(hf / s_h1));
  float hv = q * s_h1;
  float y = fmaxf(hv * wq + bb, 0.0f);
  float a = fminf(fmaxf(rintf(y / s_y2), -128.0f), 127.0f);
  return (signed char)(int)a;
}

__global__ __launch_bounds__(THREADS) void k_qh1(const int4* __restrict__ H1,
                                                 char4* __restrict__ A2,
                                                 const float* __restrict__ SC,
                                                 const float* __restrict__ wq1,
                                                 const float* __restrict__ b1) {
  int t = blockIdx.x * THREADS + threadIdx.x;  // < 1,605,632
  const unsigned* ISu = (const unsigned*)SC;
  float sx = sc_from_bits(ISu[0]);
  float sw1 = sc_from_bits(ISu[1]);
  float sxw = sx * sw1;
  float s_h1 = SC[8];
  float s_y2 = SC[9];
  int4 v = H1[t];
  int c0 = (t * 4) & 255;
  char4 r;
  r.x = qact(v.x, sxw, s_h1, s_y2, wq1[c0], b1[c0]);
  r.y = qact(v.y, sxw, s_h1, s_y2, wq1[c0 + 1], b1[c0 + 1]);
  r.z = qact(v.z, sxw, s_h1, s_y2, wq1[c0 + 2], b1[c0 + 2]);
  r.w = qact(v.w, sxw, s_h1, s_y2, wq1[c0 + 3], b1[c0 + 3]);
  A2[t] = r;
}

// conv2 3x3 s1 p1 (Cin=256), MFMA implicit GEMM. Block = (n, ho).
// LDS: 3 rows x 30 cols x 272B (pad; 16B-aligned stride).
__global__ __launch_bounds__(THREADS) void k_conv2(const int* __restrict__ A2,
                                                   const vi4* __restrict__ W2m,
                                                   int* __restrict__ H2,
                                                   int* __restrict__ maxabs_h2) {
  __shared__ __align__(16) int lds[3 * 30 * 68];
  const int tid = threadIdx.x;
  const int n = blockIdx.x / 28, ho = blockIdx.x % 28;

  for (int kh = 0; kh < 3; ++kh) {
    int h = ho - 1 + kh;
    int* dst = lds + kh * 30 * 68;
    if (h >= 0 && h < 28) {
      const int* src = A2 + (n * 28 + h) * 28 * 64;
      for (int i = tid; i < 28 * 64; i += THREADS) {
        int col = i >> 6, c = i & 63;
        dst[(col + 1) * 68 + c] = src[i];
      }
      if (tid < 64) dst[tid] = 0;
      else if (tid >= 128 && tid < 192) dst[29 * 68 + (tid - 128)] = 0;
    } else {
      for (int i = tid; i < 30 * 68; i += THREADS) dst[i] = 0;
    }
  }
  __syncthreads();

  const int lane = tid & 63, wv = tid >> 6;
  const int lm = lane & 15, quad = lane >> 4;
  const int woc0 = lm;
  const int woc1 = (16 + lm) > 27 ? 27 : (16 + lm);
  const int choff = ((lane >> 4) << 2);

  vi4 zero = {0, 0, 0, 0};
  vi4 acc[2][4];
#pragma unroll
  for (int mt = 0; mt < 2; ++mt)
#pragma unroll
    for (int ct = 0; ct < 4; ++ct) acc[mt][ct] = zero;

  const vi4* wbase = W2m + (wv * 4) * 64 + lane;
#pragma unroll 1
  for (int kh = 0; kh < 3; ++kh) {
    const int* lrow = lds + kh * 30 * 68;
#pragma unroll
    for (int kwkc = 0; kwkc < 12; ++kwkc) {
      int kw = kwkc >> 2, kc = kwkc & 3;
      int ks = (kh * 3 + kw) * 4 + kc;
      vi4 b0 = wbase[ks * 1024 + 0];
      vi4 b1 = wbase[ks * 1024 + 64];
      vi4 b2 = wbase[ks * 1024 + 128];
      vi4 b3 = wbase[ks * 1024 + 192];
      vi4 a0 = *(const vi4*)(lrow + (woc0 + kw) * 68 + kc * 16 + choff);
      vi4 a1 = *(const vi4*)(lrow + (woc1 + kw) * 68 + kc * 16 + choff);
      acc[0][0] = __builtin_amdgcn_mfma_i32_16x16x64_i8(a0, b0, acc[0][0], 0, 0, 0);
      acc[0][1] = __builtin_amdgcn_mfma_i32_16x16x64_i8(a0, b1, acc[0][1], 0, 0, 0);
      acc[0][2] = __builtin_amdgcn_mfma_i32_16x16x64_i8(a0, b2, acc[0][2], 0, 0, 0);
      acc[0][3] = __builtin_amdgcn_mfma_i32_16x16x64_i8(a0, b3, acc[0][3], 0, 0, 0);
      acc[1][0] = __builtin_amdgcn_mfma_i32_16x16x64_i8(a1, b0, acc[1][0], 0, 0, 0);
      acc[1][1] = __builtin_amdgcn_mfma_i32_16x16x64_i8(a1, b1, acc[1][1], 0, 0, 0);
      acc[1][2] = __builtin_amdgcn_mfma_i32_16x16x64_i8(a1, b2, acc[1][2], 0, 0, 0);
      acc[1][3] = __builtin_amdgcn_mfma_i32_16x16x64_i8(a1, b3, acc[1][3], 0, 0, 0);
    }
  }

  const int obase = (n * 28 + ho) * 28 * 256;
  int am = 0;
#pragma unroll
  for (int ct = 0; ct < 4; ++ct) {
    const int co = wv * 64 + ct * 16 + lm;
#pragma unroll
    for (int mt = 0; mt < 2; ++mt) {
#pragma unroll
      for (int r = 0; r < 4; ++r) {
        int wo = mt * 16 + quad * 4 + r;
        if (wo < 28) {
          int v = acc[mt][ct][r];
          H2[obase + wo * 256 + co] = v;
          am = max(am, v < 0 ? -v : v);
        }
      }
    }
  }
#pragma unroll
  for (int k = 32; k >= 1; k >>= 1) am = max(am, __shfl_xor(am, k));
  if (lane == 0) atomicMax(maxabs_h2, am);
}

// ---- residual sum math shared by k_absmax2 / k_out ----
struct SumParams {
  float sxw2, s_h2, sxwid, s_idq;
};
__device__ __forceinline__ float sum_val(int v2, int vi, const SumParams& P, float wq2c, float b2c,
                                         float wqidc, float bidc) {
  float q2 = clamp8f(rintf((float)v2 * P.sxw2 / P.s_h2));
  float z = (q2 * P.s_h2) * wq2c + b2c;
  float qi = clamp8f(rintf((float)vi * P.sxwid / P.s_idq));
  float zi = (qi * P.s_idq) * wqidc + bidc;
  return z + zi;
}
__device__ __forceinline__ SumParams make_params(const float* SC, const int* IS) {
  const unsigned* ISu = (const unsigned*)IS;
  SumParams P;
  float sx = sc_from_bits(ISu[0]);
  float sw2 = sc_from_bits(ISu[2]);
  float swid = sc_from_bits(ISu[3]);
  float s_y2 = SC[9];
  P.s_idq = SC[10];
  P.sxw2 = s_y2 * sw2;
  P.s_h2 = fmaxf(P.sxw2 * (float)IS[6] / 127.0f, 1e-8f);
  P.sxwid = sx * swid;
  return P;
}

// Pass 1: global absmax of (quant(h2)·bn2 + quant(id)·bn_id). Grid-stride, 1 atomic/block.
__global__ __launch_bounds__(THREADS) void k_absmax2(const int4* __restrict__ H2,
                                                     const int4* __restrict__ IDI,
                                                     const float* __restrict__ SC,
                                                     const int* __restrict__ IS,
                                                     const float* __restrict__ wq2,
                                                     const float* __restrict__ b2,
                                                     const float* __restrict__ wqid,
                                                     const float* __restrict__ bidp,
                                                     unsigned* __restrict__ slot) {
  __shared__ float pw2[256], pb2[256], pwi[256], pbi[256];
  int tid = threadIdx.x;
  pw2[tid] = wq2[tid];
  pb2[tid] = b2[tid];
  pwi[tid] = wqid[tid];
  pbi[tid] = bidp[tid];
  __syncthreads();
  SumParams P = make_params(SC, IS);
  const int n4 = 1605632;
  const int stride = gridDim.x * THREADS;
  float m = 0.0f;
  for (int i = blockIdx.x * THREADS + tid; i < n4; i += stride) {
    int4 v2 = H2[i];
    int4 vi = IDI[i];
    int c0 = (i * 4) & 255;
    m = fmaxf(m, fabsf(sum_val(v2.x, vi.x, P, pw2[c0], pb2[c0], pwi[c0], pbi[c0])));
    m = fmaxf(m, fabsf(sum_val(v2.y, vi.y, P, pw2[c0 + 1], pb2[c0 + 1], pwi[c0 + 1], pbi[c0 + 1])));
    m = fmaxf(m, fabsf(sum_val(v2.z, vi.z, P, pw2[c0 + 2], pb2[c0 + 2], pwi[c0 + 2], pbi[c0 + 2])));
    m = fmaxf(m, fabsf(sum_val(v2.w, vi.w, P, pw2[c0 + 3], pb2[c0 + 3], pwi[c0 + 3], pbi[c0 + 3])));
  }
#pragma unroll
  for (int k = 32; k >= 1; k >>= 1) m = fmaxf(m, __shfl_xor(m, k));
  __shared__ float wred[4];
  if ((tid & 63) == 0) wred[tid >> 6] = m;
  __syncthreads();
  if (tid == 0) {
    m = fmaxf(fmaxf(wred[0], wred[1]), fmaxf(wred[2], wred[3]));
    atomicMax(slot, __float_as_uint(m));
  }
}

// Pass 2: recompute sum, final requant + relu, write NCHW via padded LDS tile transpose.
__global__ __launch_bounds__(THREADS) void k_out(const int* __restrict__ H2,
                                                 const int* __restrict__ IDI,
                                                 const float* __restrict__ SC,
                                                 const int* __restrict__ IS,
                                                 const float* __restrict__ wq2,
                                                 const float* __restrict__ b2,
                                                 const float* __restrict__ wqid,
                                                 const float* __restrict__ bidp,
                                                 float* __restrict__ out) {
  __shared__ float tile[64 * 57];
  __shared__ float pw2[64], pb2[64], pwi[64], pbi[64];
  int tid = threadIdx.x;
  int b = blockIdx.x;
  int ct = b & 3;
  int rt = (b >> 2) % 14;
  int n = b / 56;
  int c0 = ct * 64;
  int r0 = rt * 56;
  if (tid < 64) {
    pw2[tid] = wq2[c0 + tid];
    pb2[tid] = b2[c0 + tid];
    pwi[tid] = wqid[c0 + tid];
    pbi[tid] = bidp[c0 + tid];
  }
  __syncthreads();
  SumParams P = make_params(SC, IS);
  float out_s = fmaxf(__uint_as_float(((const unsigned*)IS)[11]) / 127.0f, 1e-8f);

  const int base = (n * 784 + r0) * 256 + c0;
#pragma unroll
  for (int k = 0; k < 14; ++k) {
    int idx = tid + k * 256;  // < 3584
    int rl = idx >> 6;
    int cl = idx & 63;
    int e = base + rl * 256 + cl;
    float sv = sum_val(H2[e], IDI[e], P, pw2[cl], pb2[cl], pwi[cl], pbi[cl]);
    float q = clamp8f(rintf(sv / out_s));
    tile[cl * 57 + rl] = q > 0.0f ? q * out_s : 0.0f;
  }
  __syncthreads();
  float* ob = out + n * 200704 + c0 * 784 + r0;
#pragma unroll
  for (int k = 0; k < 14; ++k) {
    int idx = tid + k * 256;
    int cl = idx / 56;
    int rl = idx % 56;
    ob[cl * 784 + rl] = tile[cl * 57 + rl];
  }
  if (b == 0 && tid == 0) out[6422528] = out_s;
}

extern "C" void kernel_launch(void* const* d_in, const int* in_sizes, int n_in, void* d_out,
                              int out_size, void* d_ws, size_t ws_size, hipStream_t stream) {
  (void)in_sizes; (void)n_in; (void)out_size; (void)ws_size;
  const float* x = (const float*)d_in[0];
  const float* w1 = (const float*)d_in[1];
  const float* w2 = (const float*)d_in[2];
  const float* wid = (const float*)d_in[3];
  const float* bn1g = (const float*)d_in[4];
  const float* bn1b = (const float*)d_in[5];
  const float* bn1m = (const float*)d_in[6];
  const float* bn1v = (const float*)d_in[7];
  const float* bn2g = (const float*)d_in[8];
  const float* bn2b = (const float*)d_in[9];
  const float* bn2m = (const float*)d_in[10];
  const float* bn2v = (const float*)d_in[11];
  const float* idg = (const float*)d_in[12];
  const float* idb = (const float*)d_in[13];
  const float* idm = (const float*)d_in[14];
  const float* idv = (const float*)d_in[15];

  char* ws = (char*)d_ws;
  float* SC = (float*)ws;
  int* IS = (int*)ws;
  unsigned* ISu = (unsigned*)ws;
  int* maxv = (int*)(ws + 1024);
  int* minv = (int*)(ws + 2048);
  float* wq1 = (float*)(ws + 3072);
  float* b1 = (float*)(ws + 4096);
  float* wq2 = (float*)(ws + 5120);
  float* b2 = (float*)(ws + 6144);
  float* wqid = (float*)(ws + 7168);
  float* bid = (float*)(ws + 8192);
  char* X8 = ws + 16384;                 // 12,845,056 B (NHWC int8); A2 overlays after conv1
  char* A2 = X8;                         // 6,422,528 B
  char* W1m = X8 + 12845056;             // 294,912 B (MFMA B-fragment order)
  char* W2m = W1m + 294912;              // 589,824 B
  char* Widm = W2m + 589824;             // 32,768 B
  int* H1 = (int*)(Widm + 32768);        // 25,690,112 B; H2 overlays after k_qh1
  int* H2 = H1;
  int* IDI = (int*)((char*)H1 + 25690112);  // 25,690,112 B
  float* out = (float*)d_out;

  k_init<<<1, THREADS, 0, stream>>>(IS, maxv, minv);
  k_amax<<<512, THREADS, 0, stream>>>((const float4*)x, 3211264, ISu + 0);
  k_amax<<<64, THREADS, 0, stream>>>((const float4*)w1, 73728, ISu + 1);
  k_amax<<<128, THREADS, 0, stream>>>((const float4*)w2, 147456, ISu + 2);
  k_amax<<<16, THREADS, 0, stream>>>((const float4*)wid, 8192, ISu + 3);
  k_bnfold<<<1, THREADS, 0, stream>>>(bn1g, bn1b, bn1m, bn1v, wq1, b1);
  k_bnfold<<<1, THREADS, 0, stream>>>(bn2g, bn2b, bn2m, bn2v, wq2, b2);
  k_bnfold<<<1, THREADS, 0, stream>>>(idg, idb, idm, idv, wqid, bid);
  k_qx<<<1792, THREADS, 0, stream>>>(x, (int*)X8, ISu);
  k_qw1m<<<72, THREADS, 0, stream>>>(w1, (vi4*)W1m, ISu);
  k_qw2m<<<144, THREADS, 0, stream>>>(w2, (vi4*)W2m, ISu);
  k_qwidm<<<8, THREADS, 0, stream>>>(wid, (vi4*)Widm, ISu);
  k_conv1<<<896, THREADS, 0, stream>>>((const int*)X8, (const vi4*)W1m, (const vi4*)Widm, H1, IDI,
                                       maxv, minv, IS + 5);
  k_s1<<<1, THREADS, 0, stream>>>(IS, SC, maxv, minv, wq1, b1);
  k_qh1<<<6272, THREADS, 0, stream>>>((const int4*)H1, (char4*)A2, SC, wq1, b1);
  k_conv2<<<896, THREADS, 0, stream>>>((const int*)A2, (const vi4*)W2m, H2, IS + 6);
  k_absmax2<<<1024, THREADS, 0, stream>>>((const int4*)H2, (const int4*)IDI, SC, IS, wq2, b2, wqid,
                                          bid, ISu + 11);
  k_out<<<1792, THREADS, 0, stream>>>(H2, IDI, SC, IS, wq2, b2, wqid, bid, out);
}

// Round 5
// 305.702 us; speedup vs baseline: 2.9824x; 1.0721x over previous
//
#include <hip/hip_runtime.h>
#include <limits.h>

#define THREADS 256

typedef int vi4 __attribute__((ext_vector_type(4)));

__device__ __forceinline__ float clamp8f(float q) { return fminf(fmaxf(q, -128.0f), 127.0f); }
__device__ __forceinline__ float sc_from_bits(unsigned b) {
  return fmaxf(__uint_as_float(b) / 127.0f, 1e-8f);
}
__device__ __forceinline__ signed char q8(float v, float s) {
  return (signed char)(int)clamp8f(rintf(v / s));
}

// Scalar slots: [0] amax_x [1] amax_w1 [2] amax_w2 [3] amax_wid
// [4] maxabs_h1 [5] maxabs_id [6] maxabs_h2 [7] max_y2 [8] s_h1 [9] s_y2 [10] s_idq [11] amax_sum

__global__ __launch_bounds__(THREADS) void k_init(int* IS, int* maxv, int* minv) {
  int t = threadIdx.x;
  if (t < 64) IS[t] = 0;
  maxv[t] = INT_MIN;
  minv[t] = INT_MAX;
}

// Grid-stride absmax: 4-way unrolled float4 loads, shfl reduce, 1 atomic/block.
__global__ __launch_bounds__(THREADS) void k_amax(const float4* __restrict__ p, int n4,
                                                  unsigned* __restrict__ slot) {
  const int tid = threadIdx.x;
  const int stride = gridDim.x * THREADS;
  float m = 0.0f;
  int i = blockIdx.x * THREADS + tid;
  for (; i + 3 * stride < n4; i += 4 * stride) {
    float4 v0 = p[i];
    float4 v1 = p[i + stride];
    float4 v2 = p[i + 2 * stride];
    float4 v3 = p[i + 3 * stride];
    float m0 = fmaxf(fmaxf(fabsf(v0.x), fabsf(v0.y)), fmaxf(fabsf(v0.z), fabsf(v0.w)));
    float m1 = fmaxf(fmaxf(fabsf(v1.x), fabsf(v1.y)), fmaxf(fabsf(v1.z), fabsf(v1.w)));
    float m2 = fmaxf(fmaxf(fabsf(v2.x), fabsf(v2.y)), fmaxf(fabsf(v2.z), fabsf(v2.w)));
    float m3 = fmaxf(fmaxf(fabsf(v3.x), fabsf(v3.y)), fmaxf(fabsf(v3.z), fabsf(v3.w)));
    m = fmaxf(m, fmaxf(fmaxf(m0, m1), fmaxf(m2, m3)));
  }
  for (; i < n4; i += stride) {
    float4 v = p[i];
    m = fmaxf(m, fmaxf(fmaxf(fabsf(v.x), fabsf(v.y)), fmaxf(fabsf(v.z), fabsf(v.w))));
  }
#pragma unroll
  for (int k = 32; k >= 1; k >>= 1) m = fmaxf(m, __shfl_xor(m, k));
  __shared__ float wred[4];
  if ((tid & 63) == 0) wred[tid >> 6] = m;
  __syncthreads();
  if (tid == 0) {
    m = fmaxf(fmaxf(wred[0], wred[1]), fmaxf(wred[2], wred[3]));
    atomicMax(slot, __float_as_uint(m));
  }
}

__global__ __launch_bounds__(THREADS) void k_bnfold(const float* __restrict__ gamma,
                                                    const float* __restrict__ beta,
                                                    const float* __restrict__ mean,
                                                    const float* __restrict__ var,
                                                    float* __restrict__ wq, float* __restrict__ bb) {
  __shared__ float red[THREADS];
  int c = threadIdx.x;
  float ws = gamma[c] * (1.0f / sqrtf(var[c] + 1e-5f));
  red[c] = fabsf(ws);
  __syncthreads();
  for (int s = THREADS / 2; s > 0; s >>= 1) {
    if (c < s) red[c] = fmaxf(red[c], red[c + s]);
    __syncthreads();
  }
  float sws = fmaxf(red[0] / 127.0f, 1e-8f);
  float q = clamp8f(rintf(ws / sws)) * sws;
  wq[c] = q;
  bb[c] = beta[c] - mean[c] * q;
}

// Quantize x (NCHW f32) -> X8 (NHWC int8) via LDS transpose.
__global__ __launch_bounds__(THREADS) void k_qx(const float* __restrict__ x, int* __restrict__ X8,
                                                const unsigned* __restrict__ ISu) {
  __shared__ signed char tile[56 * 132];
  float s = sc_from_bits(ISu[0]);
  int b = blockIdx.x;  // 32*56
  int h = b % 56, n = b / 56;
  int t = threadIdx.x;
  const float* xp = x + ((n * 128) * 56 + h) * 56;
#pragma unroll
  for (int k = 0; k < 28; ++k) {
    int i = t + k * 256;  // < 7168
    int w = i % 56, c = i / 56;
    tile[w * 132 + c] = q8(xp[c * 3136 + w], s);
  }
  __syncthreads();
  int* op = X8 + (n * 56 + h) * 56 * 32;
#pragma unroll
  for (int k = 0; k < 7; ++k) {
    int i = t + k * 256;  // < 1792
    int w = i >> 5, c4 = (i & 31) * 4;
    const signed char* tp = tile + w * 132 + c4;
    op[i] = (int)(unsigned char)tp[0] | ((int)(unsigned char)tp[1] << 8) |
            ((int)(unsigned char)tp[2] << 16) | ((int)(unsigned char)tp[3] << 24);
  }
}

// Repack 3x3 weights into MFMA B-fragment order:
// Wm[(ks*16 + cotile)*64 + lane]: co = cotile*16+(lane&15), ci = kc*64+(lane>>4)*16+j
__global__ __launch_bounds__(THREADS) void k_qw2m(const float* __restrict__ w, vi4* __restrict__ wm,
                                                  const unsigned* __restrict__ ISu) {
  int t = blockIdx.x * THREADS + threadIdx.x;  // < 36864
  float s = sc_from_bits(ISu[2]);
  int lane = t & 63;
  int cotile = (t >> 6) & 15;
  int ks = t >> 10;  // 0..35
  int tap = ks >> 2, kc = ks & 3;
  int kh = tap / 3, kw = tap % 3;
  int co = cotile * 16 + (lane & 15);
  int ci0 = kc * 64 + (lane >> 4) * 16;
  const float* src = w + (co * 256 + ci0) * 9 + kh * 3 + kw;
  int r[4];
#pragma unroll
  for (int q = 0; q < 4; ++q) {
    unsigned b0 = (unsigned char)q8(src[(q * 4 + 0) * 9], s);
    unsigned b1 = (unsigned char)q8(src[(q * 4 + 1) * 9], s);
    unsigned b2 = (unsigned char)q8(src[(q * 4 + 2) * 9], s);
    unsigned b3 = (unsigned char)q8(src[(q * 4 + 3) * 9], s);
    r[q] = (int)(b0 | (b1 << 8) | (b2 << 16) | (b3 << 24));
  }
  vi4 v = {r[0], r[1], r[2], r[3]};
  wm[t] = v;
}

__global__ __launch_bounds__(THREADS) void k_qw1m(const float* __restrict__ w, vi4* __restrict__ wm,
                                                  const unsigned* __restrict__ ISu) {
  int t = blockIdx.x * THREADS + threadIdx.x;  // < 18432
  float s = sc_from_bits(ISu[1]);
  int lane = t & 63;
  int cotile = (t >> 6) & 15;
  int ks = t >> 10;  // 0..17
  int tap = ks >> 1, kc = ks & 1;
  int kh = tap / 3, kw = tap % 3;
  int co = cotile * 16 + (lane & 15);
  int ci0 = kc * 64 + (lane >> 4) * 16;
  const float* src = w + (co * 128 + ci0) * 9 + kh * 3 + kw;
  int r[4];
#pragma unroll
  for (int q = 0; q < 4; ++q) {
    unsigned b0 = (unsigned char)q8(src[(q * 4 + 0) * 9], s);
    unsigned b1 = (unsigned char)q8(src[(q * 4 + 1) * 9], s);
    unsigned b2 = (unsigned char)q8(src[(q * 4 + 2) * 9], s);
    unsigned b3 = (unsigned char)q8(src[(q * 4 + 3) * 9], s);
    r[q] = (int)(b0 | (b1 << 8) | (b2 << 16) | (b3 << 24));
  }
  vi4 v = {r[0], r[1], r[2], r[3]};
  wm[t] = v;
}

__global__ __launch_bounds__(THREADS) void k_qwidm(const float* __restrict__ w,
                                                   vi4* __restrict__ wm,
                                                   const unsigned* __restrict__ ISu) {
  int t = blockIdx.x * THREADS + threadIdx.x;  // < 2048
  float s = sc_from_bits(ISu[3]);
  int lane = t & 63;
  int cotile = (t >> 6) & 15;
  int ks = t >> 10;  // 0..1
  int co = cotile * 16 + (lane & 15);
  int ci0 = ks * 64 + (lane >> 4) * 16;
  const float* src = w + co * 128 + ci0;
  int r[4];
#pragma unroll
  for (int q = 0; q < 4; ++q) {
    unsigned b0 = (unsigned char)q8(src[q * 4 + 0], s);
    unsigned b1 = (unsigned char)q8(src[q * 4 + 1], s);
    unsigned b2 = (unsigned char)q8(src[q * 4 + 2], s);
    unsigned b3 = (unsigned char)q8(src[q * 4 + 3], s);
    r[q] = (int)(b0 | (b1 << 8) | (b2 << 16) | (b3 << 24));
  }
  vi4 v = {r[0], r[1], r[2], r[3]};
  wm[t] = v;
}

#define MFMA_I8(a, b, c) __builtin_amdgcn_mfma_i32_16x16x64_i8(a, b, c, 0, 0, 0)

// conv1 3x3 s2 p1 (Cin=128) + identity 1x1 s2, MFMA implicit GEMM.
// Block = (n, ho-pair). LDS: 5 input rows x 58 cols x 144B.
// Wave (mw,nw): mw = output row (ho0+mw), nw = cotile half (8 cotiles, N=128).
__global__ __launch_bounds__(THREADS, 2) void k_conv1(const int* __restrict__ X8,
                                                      const vi4* __restrict__ W1m,
                                                      const vi4* __restrict__ Widm,
                                                      int* __restrict__ H1, int* __restrict__ IDI,
                                                      int* __restrict__ maxv,
                                                      int* __restrict__ minv,
                                                      int* __restrict__ maxabs_id) {
  __shared__ __align__(16) int lds[5 * 58 * 36];
  const int tid = threadIdx.x;
  const int n = blockIdx.x / 14, hp = blockIdx.x % 14;
  const int ho0 = hp * 2;

  for (int r = 0; r < 5; ++r) {
    int h = 2 * ho0 - 1 + r;
    int* dst = lds + r * 58 * 36;
    if (h >= 0 && h < 56) {
      const int* src = X8 + (n * 56 + h) * 56 * 32;
      for (int i = tid; i < 56 * 32; i += THREADS) {
        int col = i >> 5, c = i & 31;
        dst[(col + 1) * 36 + c] = src[i];
      }
      if (tid < 32) dst[tid] = 0;
      else if (tid >= 128 && tid < 160) dst[57 * 36 + (tid - 128)] = 0;
    } else {
      for (int i = tid; i < 58 * 36; i += THREADS) dst[i] = 0;
    }
  }
  __syncthreads();

  const int lane = tid & 63, wv = tid >> 6;
  const int mw = wv & 1, nw = wv >> 1;
  const int lm = lane & 15, quad = lane >> 4;
  const int woc0 = lm, woc1 = (16 + lm) > 27 ? 27 : (16 + lm);
  const int choff = quad * 4;
  const int ho = ho0 + mw;
  const int obase = ((n * 28 + ho) * 28) * 256;

  vi4 zero = {0, 0, 0, 0};
  vi4 acc[2][8];
  vi4 bcur[8], bnext[8];
  vi4 a0c, a1c, a0n, a1n;

  // ---- identity branch first (2 K-steps), reusing acc ----
#pragma unroll
  for (int mt = 0; mt < 2; ++mt)
#pragma unroll
    for (int ct = 0; ct < 8; ++ct) acc[mt][ct] = zero;
  const vi4* wibase = Widm + (nw * 8) * 64 + lane;
  {
    const int ro = (2 * mw + 1) * 58;
#pragma unroll
    for (int kc = 0; kc < 2; ++kc) {
      vi4 a0 = *(const vi4*)(lds + (ro + 2 * woc0 + 1) * 36 + kc * 16 + choff);
      vi4 a1 = *(const vi4*)(lds + (ro + 2 * woc1 + 1) * 36 + kc * 16 + choff);
#pragma unroll
      for (int ct = 0; ct < 8; ++ct) {
        vi4 b = wibase[kc * 1024 + ct * 64];
        acc[0][ct] = MFMA_I8(a0, b, acc[0][ct]);
        acc[1][ct] = MFMA_I8(a1, b, acc[1][ct]);
      }
    }
  }
  int am = 0;
#pragma unroll
  for (int ct = 0; ct < 8; ++ct) {
    const int co = (nw * 8 + ct) * 16 + lm;
#pragma unroll
    for (int mt = 0; mt < 2; ++mt)
#pragma unroll
      for (int r = 0; r < 4; ++r) {
        int wo = mt * 16 + quad * 4 + r;
        if (wo < 28) {
          int v = acc[mt][ct][r];
          IDI[obase + wo * 256 + co] = v;
          am = max(am, v < 0 ? -v : v);
        }
      }
  }
#pragma unroll
  for (int k = 32; k >= 1; k >>= 1) am = max(am, __shfl_xor(am, k));
  if (lane == 0) atomicMax(maxabs_id, am);

  // ---- main 3x3 conv, 18 K-steps, software-pipelined ----
#pragma unroll
  for (int mt = 0; mt < 2; ++mt)
#pragma unroll
    for (int ct = 0; ct < 8; ++ct) acc[mt][ct] = zero;
  const vi4* wbase = W1m + (nw * 8) * 64 + lane;
#pragma unroll
  for (int ct = 0; ct < 8; ++ct) bcur[ct] = wbase[ct * 64];
  {
    const int ro = (2 * mw) * 58;  // kh=0
    a0c = *(const vi4*)(lds + (ro + 2 * woc0) * 36 + choff);
    a1c = *(const vi4*)(lds + (ro + 2 * woc1) * 36 + choff);
  }
#pragma unroll 1
  for (int ks = 0; ks < 18; ++ks) {
    int ksn = ks + 1;
    if (ksn < 18) {
      int khn = (ksn >= 6) + (ksn >= 12);
      int t2 = ksn - khn * 6;
      int kwn = t2 >> 1, kcn = t2 & 1;
#pragma unroll
      for (int ct = 0; ct < 8; ++ct) bnext[ct] = wbase[ksn * 1024 + ct * 64];
      int ro = (2 * mw + khn) * 58;
      a0n = *(const vi4*)(lds + (ro + 2 * woc0 + kwn) * 36 + kcn * 16 + choff);
      a1n = *(const vi4*)(lds + (ro + 2 * woc1 + kwn) * 36 + kcn * 16 + choff);
    }
#pragma unroll
    for (int ct = 0; ct < 8; ++ct) {
      acc[0][ct] = MFMA_I8(a0c, bcur[ct], acc[0][ct]);
      acc[1][ct] = MFMA_I8(a1c, bcur[ct], acc[1][ct]);
    }
    a0c = a0n;
    a1c = a1n;
#pragma unroll
    for (int ct = 0; ct < 8; ++ct) bcur[ct] = bnext[ct];
  }

#pragma unroll
  for (int ct = 0; ct < 8; ++ct) {
    const int co = (nw * 8 + ct) * 16 + lm;
    int vmax = INT_MIN, vmin = INT_MAX;
#pragma unroll
    for (int mt = 0; mt < 2; ++mt)
#pragma unroll
      for (int r = 0; r < 4; ++r) {
        int wo = mt * 16 + quad * 4 + r;
        if (wo < 28) {
          int v = acc[mt][ct][r];
          H1[obase + wo * 256 + co] = v;
          vmax = max(vmax, v);
          vmin = min(vmin, v);
        }
      }
    vmax = max(vmax, __shfl_xor(vmax, 16));
    vmax = max(vmax, __shfl_xor(vmax, 32));
    vmin = min(vmin, __shfl_xor(vmin, 16));
    vmin = min(vmin, __shfl_xor(vmin, 32));
    if (lane < 16) {
      atomicMax(&maxv[(nw * 8 + ct) * 16 + lane], vmax);
      atomicMin(&minv[(nw * 8 + ct) * 16 + lane], vmin);
    }
  }
}

// Derive stage-1 scales.
__global__ __launch_bounds__(THREADS) void k_s1(int* __restrict__ IS, float* __restrict__ SC,
                                                const int* __restrict__ maxv,
                                                const int* __restrict__ minv,
                                                const float* __restrict__ wq1,
                                                const float* __restrict__ b1) {
  __shared__ int ri[THREADS];
  __shared__ float rf[THREADS];
  int c = threadIdx.x;
  int vmax = maxv[c], vmin = minv[c];
  int a1 = vmax < 0 ? -vmax : vmax;
  int a0 = vmin < 0 ? -vmin : vmin;
  ri[c] = max(a1, a0);
  __syncthreads();
  for (int s = THREADS / 2; s > 0; s >>= 1) {
    if (c < s) ri[c] = max(ri[c], ri[c + s]);
    __syncthreads();
  }
  int mh1 = ri[0];
  const unsigned* ISu = (const unsigned*)IS;
  float sx = sc_from_bits(ISu[0]);
  float sw1 = sc_from_bits(ISu[1]);
  float sxw = sx * sw1;
  float s_h1 = fmaxf(sxw * (float)mh1 / 127.0f, 1e-8f);
  float wq = wq1[c], bbc = b1[c];
  float q1 = clamp8f(rintf((float)vmax * sxw / s_h1));
  float q0 = clamp8f(rintf((float)vmin * sxw / s_h1));
  float hv1 = q1 * s_h1, hv0 = q0 * s_h1;
  float y1 = fmaxf(hv1 * wq + bbc, 0.0f);
  float y0 = fmaxf(hv0 * wq + bbc, 0.0f);
  rf[c] = fmaxf(y1, y0);
  __syncthreads();
  for (int s = THREADS / 2; s > 0; s >>= 1) {
    if (c < s) rf[c] = fmaxf(rf[c], rf[c + s]);
    __syncthreads();
  }
  if (c == 0) {
    IS[4] = mh1;
    SC[7] = rf[0];
    SC[8] = s_h1;
    SC[9] = fmaxf(rf[0] / 127.0f, 1e-8f);
    float swid = sc_from_bits(ISu[3]);
    SC[10] = fmaxf(sx * swid * (float)IS[5] / 127.0f, 1e-8f);
  }
}

// quant(h1) -> bn1 -> relu -> quant => A2 int8 (NHWC)
__device__ __forceinline__ signed char qact(int v, float sxw, float s_h1, float s_y2, float wq,
                                            float bb) {
  float hf = (float)v * sxw;
  float q = clamp8f(rintf(hf / s_h1));
  float hv = q * s_h1;
  float y = fmaxf(hv * wq + bb, 0.0f);
  float a = fminf(fmaxf(rintf(y / s_y2), -128.0f), 127.0f);
  return (signed char)(int)a;
}

__global__ __launch_bounds__(THREADS) void k_qh1(const int4* __restrict__ H1,
                                                 char4* __restrict__ A2,
                                                 const float* __restrict__ SC,
                                                 const float* __restrict__ wq1,
                                                 const float* __restrict__ b1) {
  int t = blockIdx.x * THREADS + threadIdx.x;  // < 1,605,632
  const unsigned* ISu = (const unsigned*)SC;
  float sx = sc_from_bits(ISu[0]);
  float sw1 = sc_from_bits(ISu[1]);
  float sxw = sx * sw1;
  float s_h1 = SC[8];
  float s_y2 = SC[9];
  int4 v = H1[t];
  int c0 = (t * 4) & 255;
  char4 r;
  r.x = qact(v.x, sxw, s_h1, s_y2, wq1[c0], b1[c0]);
  r.y = qact(v.y, sxw, s_h1, s_y2, wq1[c0 + 1], b1[c0 + 1]);
  r.z = qact(v.z, sxw, s_h1, s_y2, wq1[c0 + 2], b1[c0 + 2]);
  r.w = qact(v.w, sxw, s_h1, s_y2, wq1[c0 + 3], b1[c0 + 3]);
  A2[t] = r;
}

// conv2 3x3 s1 p1 (Cin=256), MFMA implicit GEMM, ho-pair blocks, pipelined.
// LDS: 4 input rows x 30 cols x 272B. Wave (mw,nw): row ho0+mw, cotiles nw*8..+7.
__global__ __launch_bounds__(THREADS, 2) void k_conv2(const int* __restrict__ A2,
                                                      const vi4* __restrict__ W2m,
                                                      int* __restrict__ H2,
                                                      int* __restrict__ maxabs_h2) {
  __shared__ __align__(16) int lds[4 * 30 * 68];
  const int tid = threadIdx.x;
  const int n = blockIdx.x / 14, hp = blockIdx.x % 14;
  const int ho0 = hp * 2;

  for (int r = 0; r < 4; ++r) {
    int h = ho0 - 1 + r;
    int* dst = lds + r * 30 * 68;
    if (h >= 0 && h < 28) {
      const int* src = A2 + (n * 28 + h) * 28 * 64;
      for (int i = tid; i < 28 * 64; i += THREADS) {
        int col = i >> 6, c = i & 63;
        dst[(col + 1) * 68 + c] = src[i];
      }
      if (tid < 64) dst[tid] = 0;
      else if (tid >= 128 && tid < 192) dst[29 * 68 + (tid - 128)] = 0;
    } else {
      for (int i = tid; i < 30 * 68; i += THREADS) dst[i] = 0;
    }
  }
  __syncthreads();

  const int lane = tid & 63, wv = tid >> 6;
  const int mw = wv & 1, nw = wv >> 1;
  const int lm = lane & 15, quad = lane >> 4;
  const int woc0 = lm, woc1 = (16 + lm) > 27 ? 27 : (16 + lm);
  const int choff = quad * 4;
  const int ho = ho0 + mw;

  vi4 zero = {0, 0, 0, 0};
  vi4 acc[2][8];
#pragma unroll
  for (int mt = 0; mt < 2; ++mt)
#pragma unroll
    for (int ct = 0; ct < 8; ++ct) acc[mt][ct] = zero;

  const vi4* wbase = W2m + (nw * 8) * 64 + lane;
  vi4 bcur[8], bnext[8];
  vi4 a0c, a1c, a0n, a1n;
#pragma unroll
  for (int ct = 0; ct < 8; ++ct) bcur[ct] = wbase[ct * 64];
  {
    const int ro = mw * 30;  // kh=0
    a0c = *(const vi4*)(lds + (ro + woc0) * 68 + choff);
    a1c = *(const vi4*)(lds + (ro + woc1) * 68 + choff);
  }
#pragma unroll 1
  for (int ks = 0; ks < 36; ++ks) {
    int ksn = ks + 1;
    if (ksn < 36) {
      int khn = (ksn >= 12) + (ksn >= 24);
      int t2 = ksn - khn * 12;
      int kwn = t2 >> 2, kcn = t2 & 3;
#pragma unroll
      for (int ct = 0; ct < 8; ++ct) bnext[ct] = wbase[ksn * 1024 + ct * 64];
      int ro = (mw + khn) * 30;
      a0n = *(const vi4*)(lds + (ro + woc0 + kwn) * 68 + kcn * 16 + choff);
      a1n = *(const vi4*)(lds + (ro + woc1 + kwn) * 68 + kcn * 16 + choff);
    }
#pragma unroll
    for (int ct = 0; ct < 8; ++ct) {
      acc[0][ct] = MFMA_I8(a0c, bcur[ct], acc[0][ct]);
      acc[1][ct] = MFMA_I8(a1c, bcur[ct], acc[1][ct]);
    }
    a0c = a0n;
    a1c = a1n;
#pragma unroll
    for (int ct = 0; ct < 8; ++ct) bcur[ct] = bnext[ct];
  }

  const int obase = ((n * 28 + ho) * 28) * 256;
  int am = 0;
#pragma unroll
  for (int ct = 0; ct < 8; ++ct) {
    const int co = (nw * 8 + ct) * 16 + lm;
#pragma unroll
    for (int mt = 0; mt < 2; ++mt)
#pragma unroll
      for (int r = 0; r < 4; ++r) {
        int wo = mt * 16 + quad * 4 + r;
        if (wo < 28) {
          int v = acc[mt][ct][r];
          H2[obase + wo * 256 + co] = v;
          am = max(am, v < 0 ? -v : v);
        }
      }
  }
#pragma unroll
  for (int k = 32; k >= 1; k >>= 1) am = max(am, __shfl_xor(am, k));
  if (lane == 0) atomicMax(maxabs_h2, am);
}

// ---- residual sum math shared by k_absmax2 / k_out ----
struct SumParams {
  float sxw2, s_h2, sxwid, s_idq;
};
__device__ __forceinline__ float sum_val(int v2, int vi, const SumParams& P, float wq2c, float b2c,
                                         float wqidc, float bidc) {
  float q2 = clamp8f(rintf((float)v2 * P.sxw2 / P.s_h2));
  float z = (q2 * P.s_h2) * wq2c + b2c;
  float qi = clamp8f(rintf((float)vi * P.sxwid / P.s_idq));
  float zi = (qi * P.s_idq) * wqidc + bidc;
  return z + zi;
}
__device__ __forceinline__ SumParams make_params(const float* SC, const int* IS) {
  const unsigned* ISu = (const unsigned*)IS;
  SumParams P;
  float sx = sc_from_bits(ISu[0]);
  float sw2 = sc_from_bits(ISu[2]);
  float swid = sc_from_bits(ISu[3]);
  float s_y2 = SC[9];
  P.s_idq = SC[10];
  P.sxw2 = s_y2 * sw2;
  P.s_h2 = fmaxf(P.sxw2 * (float)IS[6] / 127.0f, 1e-8f);
  P.sxwid = sx * swid;
  return P;
}

// Pass 1: global absmax of residual sum. Grid-stride, 1 atomic/block.
__global__ __launch_bounds__(THREADS) void k_absmax2(const int4* __restrict__ H2,
                                                     const int4* __restrict__ IDI,
                                                     const float* __restrict__ SC,
                                                     const int* __restrict__ IS,
                                                     const float* __restrict__ wq2,
                                                     const float* __restrict__ b2,
                                                     const float* __restrict__ wqid,
                                                     const float* __restrict__ bidp,
                                                     unsigned* __restrict__ slot) {
  __shared__ float pw2[256], pb2[256], pwi[256], pbi[256];
  int tid = threadIdx.x;
  pw2[tid] = wq2[tid];
  pb2[tid] = b2[tid];
  pwi[tid] = wqid[tid];
  pbi[tid] = bidp[tid];
  __syncthreads();
  SumParams P = make_params(SC, IS);
  const int n4 = 1605632;
  const int stride = gridDim.x * THREADS;
  float m = 0.0f;
  for (int i = blockIdx.x * THREADS + tid; i < n4; i += stride) {
    int4 v2 = H2[i];
    int4 vi = IDI[i];
    int c0 = (i * 4) & 255;
    m = fmaxf(m, fabsf(sum_val(v2.x, vi.x, P, pw2[c0], pb2[c0], pwi[c0], pbi[c0])));
    m = fmaxf(m, fabsf(sum_val(v2.y, vi.y, P, pw2[c0 + 1], pb2[c0 + 1], pwi[c0 + 1], pbi[c0 + 1])));
    m = fmaxf(m, fabsf(sum_val(v2.z, vi.z, P, pw2[c0 + 2], pb2[c0 + 2], pwi[c0 + 2], pbi[c0 + 2])));
    m = fmaxf(m, fabsf(sum_val(v2.w, vi.w, P, pw2[c0 + 3], pb2[c0 + 3], pwi[c0 + 3], pbi[c0 + 3])));
  }
#pragma unroll
  for (int k = 32; k >= 1; k >>= 1) m = fmaxf(m, __shfl_xor(m, k));
  __shared__ float wred[4];
  if ((tid & 63) == 0) wred[tid >> 6] = m;
  __syncthreads();
  if (tid == 0) {
    m = fmaxf(fmaxf(wred[0], wred[1]), fmaxf(wred[2], wred[3]));
    atomicMax(slot, __float_as_uint(m));
  }
}

// Pass 2: recompute sum, final requant + relu, write NCHW via padded LDS tile transpose.
__global__ __launch_bounds__(THREADS) void k_out(const int* __restrict__ H2,
                                                 const int* __restrict__ IDI,
                                                 const float* __restrict__ SC,
                                                 const int* __restrict__ IS,
                                                 const float* __restrict__ wq2,
                                                 const float* __restrict__ b2,
                                                 const float* __restrict__ wqid,
                                                 const float* __restrict__ bidp,
                                                 float* __restrict__ out) {
  __shared__ float tile[64 * 57];
  __shared__ float pw2[64], pb2[64], pwi[64], pbi[64];
  int tid = threadIdx.x;
  int b = blockIdx.x;
  int ct = b & 3;
  int rt = (b >> 2) % 14;
  int n = b / 56;
  int c0 = ct * 64;
  int r0 = rt * 56;
  if (tid < 64) {
    pw2[tid] = wq2[c0 + tid];
    pb2[tid] = b2[c0 + tid];
    pwi[tid] = wqid[c0 + tid];
    pbi[tid] = bidp[c0 + tid];
  }
  __syncthreads();
  SumParams P = make_params(SC, IS);
  float out_s = fmaxf(__uint_as_float(((const unsigned*)IS)[11]) / 127.0f, 1e-8f);

  const int base = (n * 784 + r0) * 256 + c0;
#pragma unroll
  for (int k = 0; k < 14; ++k) {
    int idx = tid + k * 256;  // < 3584
    int rl = idx >> 6;
    int cl = idx & 63;
    int e = base + rl * 256 + cl;
    float sv = sum_val(H2[e], IDI[e], P, pw2[cl], pb2[cl], pwi[cl], pbi[cl]);
    float q = clamp8f(rintf(sv / out_s));
    tile[cl * 57 + rl] = q > 0.0f ? q * out_s : 0.0f;
  }
  __syncthreads();
  float* ob = out + n * 200704 + c0 * 784 + r0;
#pragma unroll
  for (int k = 0; k < 14; ++k) {
    int idx = tid + k * 256;
    int cl = idx / 56;
    int rl = idx % 56;
    ob[cl * 784 + rl] = tile[cl * 57 + rl];
  }
  if (b == 0 && tid == 0) out[6422528] = out_s;
}

extern "C" void kernel_launch(void* const* d_in, const int* in_sizes, int n_in, void* d_out,
                              int out_size, void* d_ws, size_t ws_size, hipStream_t stream) {
  (void)in_sizes; (void)n_in; (void)out_size; (void)ws_size;
  const float* x = (const float*)d_in[0];
  const float* w1 = (const float*)d_in[1];
  const float* w2 = (const float*)d_in[2];
  const float* wid = (const float*)d_in[3];
  const float* bn1g = (const float*)d_in[4];
  const float* bn1b = (const float*)d_in[5];
  const float* bn1m = (const float*)d_in[6];
  const float* bn1v = (const float*)d_in[7];
  const float* bn2g = (const float*)d_in[8];
  const float* bn2b = (const float*)d_in[9];
  const float* bn2m = (const float*)d_in[10];
  const float* bn2v = (const float*)d_in[11];
  const float* idg = (const float*)d_in[12];
  const float* idb = (const float*)d_in[13];
  const float* idm = (const float*)d_in[14];
  const float* idv = (const float*)d_in[15];

  char* ws = (char*)d_ws;
  float* SC = (float*)ws;
  int* IS = (int*)ws;
  unsigned* ISu = (unsigned*)ws;
  int* maxv = (int*)(ws + 1024);
  int* minv = (int*)(ws + 2048);
  float* wq1 = (float*)(ws + 3072);
  float* b1 = (float*)(ws + 4096);
  float* wq2 = (float*)(ws + 5120);
  float* b2 = (float*)(ws + 6144);
  float* wqid = (float*)(ws + 7168);
  float* bid = (float*)(ws + 8192);
  char* X8 = ws + 16384;                 // NHWC int8; A2 overlays after conv1
  char* A2 = X8;
  char* W1m = X8 + 12845056;
  char* W2m = W1m + 294912;
  char* Widm = W2m + 589824;
  int* H1 = (int*)(Widm + 32768);
  int* H2 = H1;
  int* IDI = (int*)((char*)H1 + 25690112);
  float* out = (float*)d_out;

  k_init<<<1, THREADS, 0, stream>>>(IS, maxv, minv);
  k_amax<<<512, THREADS, 0, stream>>>((const float4*)x, 3211264, ISu + 0);
  k_amax<<<64, THREADS, 0, stream>>>((const float4*)w1, 73728, ISu + 1);
  k_amax<<<128, THREADS, 0, stream>>>((const float4*)w2, 147456, ISu + 2);
  k_amax<<<16, THREADS, 0, stream>>>((const float4*)wid, 8192, ISu + 3);
  k_bnfold<<<1, THREADS, 0, stream>>>(bn1g, bn1b, bn1m, bn1v, wq1, b1);
  k_bnfold<<<1, THREADS, 0, stream>>>(bn2g, bn2b, bn2m, bn2v, wq2, b2);
  k_bnfold<<<1, THREADS, 0, stream>>>(idg, idb, idm, idv, wqid, bid);
  k_qx<<<1792, THREADS, 0, stream>>>(x, (int*)X8, ISu);
  k_qw1m<<<72, THREADS, 0, stream>>>(w1, (vi4*)W1m, ISu);
  k_qw2m<<<144, THREADS, 0, stream>>>(w2, (vi4*)W2m, ISu);
  k_qwidm<<<8, THREADS, 0, stream>>>(wid, (vi4*)Widm, ISu);
  k_conv1<<<448, THREADS, 0, stream>>>((const int*)X8, (const vi4*)W1m, (const vi4*)Widm, H1, IDI,
                                       maxv, minv, IS + 5);
  k_s1<<<1, THREADS, 0, stream>>>(IS, SC, maxv, minv, wq1, b1);
  k_qh1<<<6272, THREADS, 0, stream>>>((const int4*)H1, (char4*)A2, SC, wq1, b1);
  k_conv2<<<448, THREADS, 0, stream>>>((const int*)A2, (const vi4*)W2m, H2, IS + 6);
  k_absmax2<<<1024, THREADS, 0, stream>>>((const int4*)H2, (const int4*)IDI, SC, IS, wq2, b2, wqid,
                                          bid, ISu + 11);
  k_out<<<1792, THREADS, 0, stream>>>(H2, IDI, SC, IS, wq2, b2, wqid, bid, out);
}

// Round 6
// 292.885 us; speedup vs baseline: 3.1129x; 1.0438x over previous
//
#include <hip/hip_runtime.h>
#include <limits.h>

#define THREADS 256

typedef int vi4 __attribute__((ext_vector_type(4)));

__device__ __forceinline__ float clamp8f(float q) { return fminf(fmaxf(q, -128.0f), 127.0f); }
__device__ __forceinline__ float sc_from_bits(unsigned b) {
  return fmaxf(__uint_as_float(b) / 127.0f, 1e-8f);
}
__device__ __forceinline__ signed char q8(float v, float s) {
  return (signed char)(int)clamp8f(rintf(v / s));
}

// Scalar slots: [0] amax_x [1] amax_w1 [2] amax_w2 [3] amax_wid
// [4] maxabs_h1 [5] maxabs_id [6] maxabs_h2 [7] max_y2 [8] s_h1 [9] s_y2 [10] s_idq [11] amax_sum

__global__ __launch_bounds__(THREADS) void k_init(int* IS, int* maxv, int* minv) {
  int t = threadIdx.x;
  if (t < 64) IS[t] = 0;
  maxv[t] = INT_MIN;
  minv[t] = INT_MAX;
}

// Grid-stride absmax: 4-way unrolled float4 loads, shfl reduce, 1 atomic/block.
__global__ __launch_bounds__(THREADS) void k_amax(const float4* __restrict__ p, int n4,
                                                  unsigned* __restrict__ slot) {
  const int tid = threadIdx.x;
  const int stride = gridDim.x * THREADS;
  float m = 0.0f;
  int i = blockIdx.x * THREADS + tid;
  for (; i + 3 * stride < n4; i += 4 * stride) {
    float4 v0 = p[i];
    float4 v1 = p[i + stride];
    float4 v2 = p[i + 2 * stride];
    float4 v3 = p[i + 3 * stride];
    float m0 = fmaxf(fmaxf(fabsf(v0.x), fabsf(v0.y)), fmaxf(fabsf(v0.z), fabsf(v0.w)));
    float m1 = fmaxf(fmaxf(fabsf(v1.x), fabsf(v1.y)), fmaxf(fabsf(v1.z), fabsf(v1.w)));
    float m2 = fmaxf(fmaxf(fabsf(v2.x), fabsf(v2.y)), fmaxf(fabsf(v2.z), fabsf(v2.w)));
    float m3 = fmaxf(fmaxf(fabsf(v3.x), fabsf(v3.y)), fmaxf(fabsf(v3.z), fabsf(v3.w)));
    m = fmaxf(m, fmaxf(fmaxf(m0, m1), fmaxf(m2, m3)));
  }
  for (; i < n4; i += stride) {
    float4 v = p[i];
    m = fmaxf(m, fmaxf(fmaxf(fabsf(v.x), fabsf(v.y)), fmaxf(fabsf(v.z), fabsf(v.w))));
  }
#pragma unroll
  for (int k = 32; k >= 1; k >>= 1) m = fmaxf(m, __shfl_xor(m, k));
  __shared__ float wred[4];
  if ((tid & 63) == 0) wred[tid >> 6] = m;
  __syncthreads();
  if (tid == 0) {
    m = fmaxf(fmaxf(wred[0], wred[1]), fmaxf(wred[2], wred[3]));
    atomicMax(slot, __float_as_uint(m));
  }
}

__global__ __launch_bounds__(THREADS) void k_bnfold(const float* __restrict__ gamma,
                                                    const float* __restrict__ beta,
                                                    const float* __restrict__ mean,
                                                    const float* __restrict__ var,
                                                    float* __restrict__ wq, float* __restrict__ bb) {
  __shared__ float red[THREADS];
  int c = threadIdx.x;
  float ws = gamma[c] * (1.0f / sqrtf(var[c] + 1e-5f));
  red[c] = fabsf(ws);
  __syncthreads();
  for (int s = THREADS / 2; s > 0; s >>= 1) {
    if (c < s) red[c] = fmaxf(red[c], red[c + s]);
    __syncthreads();
  }
  float sws = fmaxf(red[0] / 127.0f, 1e-8f);
  float q = clamp8f(rintf(ws / sws)) * sws;
  wq[c] = q;
  bb[c] = beta[c] - mean[c] * q;
}

// Quantize x (NCHW f32) -> X8 (NHWC int8) via LDS transpose.
__global__ __launch_bounds__(THREADS) void k_qx(const float* __restrict__ x, int* __restrict__ X8,
                                                const unsigned* __restrict__ ISu) {
  __shared__ signed char tile[56 * 132];
  float s = sc_from_bits(ISu[0]);
  int b = blockIdx.x;  // 32*56
  int h = b % 56, n = b / 56;
  int t = threadIdx.x;
  const float* xp = x + ((n * 128) * 56 + h) * 56;
#pragma unroll
  for (int k = 0; k < 28; ++k) {
    int i = t + k * 256;  // < 7168
    int w = i % 56, c = i / 56;
    tile[w * 132 + c] = q8(xp[c * 3136 + w], s);
  }
  __syncthreads();
  int* op = X8 + (n * 56 + h) * 56 * 32;
#pragma unroll
  for (int k = 0; k < 7; ++k) {
    int i = t + k * 256;  // < 1792
    int w = i >> 5, c4 = (i & 31) * 4;
    const signed char* tp = tile + w * 132 + c4;
    op[i] = (int)(unsigned char)tp[0] | ((int)(unsigned char)tp[1] << 8) |
            ((int)(unsigned char)tp[2] << 16) | ((int)(unsigned char)tp[3] << 24);
  }
}

// Repack 3x3 weights into MFMA B-fragment order:
// Wm[(ks*16 + cotile)*64 + lane]: co = cotile*16+(lane&15), ci = kc*64+(lane>>4)*16+j
__global__ __launch_bounds__(THREADS) void k_qw2m(const float* __restrict__ w, vi4* __restrict__ wm,
                                                  const unsigned* __restrict__ ISu) {
  int t = blockIdx.x * THREADS + threadIdx.x;  // < 36864
  float s = sc_from_bits(ISu[2]);
  int lane = t & 63;
  int cotile = (t >> 6) & 15;
  int ks = t >> 10;  // 0..35
  int tap = ks >> 2, kc = ks & 3;
  int kh = tap / 3, kw = tap % 3;
  int co = cotile * 16 + (lane & 15);
  int ci0 = kc * 64 + (lane >> 4) * 16;
  const float* src = w + (co * 256 + ci0) * 9 + kh * 3 + kw;
  int r[4];
#pragma unroll
  for (int q = 0; q < 4; ++q) {
    unsigned b0 = (unsigned char)q8(src[(q * 4 + 0) * 9], s);
    unsigned b1 = (unsigned char)q8(src[(q * 4 + 1) * 9], s);
    unsigned b2 = (unsigned char)q8(src[(q * 4 + 2) * 9], s);
    unsigned b3 = (unsigned char)q8(src[(q * 4 + 3) * 9], s);
    r[q] = (int)(b0 | (b1 << 8) | (b2 << 16) | (b3 << 24));
  }
  vi4 v = {r[0], r[1], r[2], r[3]};
  wm[t] = v;
}

__global__ __launch_bounds__(THREADS) void k_qw1m(const float* __restrict__ w, vi4* __restrict__ wm,
                                                  const unsigned* __restrict__ ISu) {
  int t = blockIdx.x * THREADS + threadIdx.x;  // < 18432
  float s = sc_from_bits(ISu[1]);
  int lane = t & 63;
  int cotile = (t >> 6) & 15;
  int ks = t >> 10;  // 0..17
  int tap = ks >> 1, kc = ks & 1;
  int kh = tap / 3, kw = tap % 3;
  int co = cotile * 16 + (lane & 15);
  int ci0 = kc * 64 + (lane >> 4) * 16;
  const float* src = w + (co * 128 + ci0) * 9 + kh * 3 + kw;
  int r[4];
#pragma unroll
  for (int q = 0; q < 4; ++q) {
    unsigned b0 = (unsigned char)q8(src[(q * 4 + 0) * 9], s);
    unsigned b1 = (unsigned char)q8(src[(q * 4 + 1) * 9], s);
    unsigned b2 = (unsigned char)q8(src[(q * 4 + 2) * 9], s);
    unsigned b3 = (unsigned char)q8(src[(q * 4 + 3) * 9], s);
    r[q] = (int)(b0 | (b1 << 8) | (b2 << 16) | (b3 << 24));
  }
  vi4 v = {r[0], r[1], r[2], r[3]};
  wm[t] = v;
}

__global__ __launch_bounds__(THREADS) void k_qwidm(const float* __restrict__ w,
                                                   vi4* __restrict__ wm,
                                                   const unsigned* __restrict__ ISu) {
  int t = blockIdx.x * THREADS + threadIdx.x;  // < 2048
  float s = sc_from_bits(ISu[3]);
  int lane = t & 63;
  int cotile = (t >> 6) & 15;
  int ks = t >> 10;  // 0..1
  int co = cotile * 16 + (lane & 15);
  int ci0 = ks * 64 + (lane >> 4) * 16;
  const float* src = w + co * 128 + ci0;
  int r[4];
#pragma unroll
  for (int q = 0; q < 4; ++q) {
    unsigned b0 = (unsigned char)q8(src[q * 4 + 0], s);
    unsigned b1 = (unsigned char)q8(src[q * 4 + 1], s);
    unsigned b2 = (unsigned char)q8(src[q * 4 + 2], s);
    unsigned b3 = (unsigned char)q8(src[q * 4 + 3], s);
    r[q] = (int)(b0 | (b1 << 8) | (b2 << 16) | (b3 << 24));
  }
  vi4 v = {r[0], r[1], r[2], r[3]};
  wm[t] = v;
}

#define MFMA_I8(a, b, c) __builtin_amdgcn_mfma_i32_16x16x64_i8(a, b, c, 0, 0, 0)

// conv1 3x3 s2 p1 (Cin=128) + identity 1x1 s2, MFMA implicit GEMM.
// Block = (n, ho-pair, N-half): 896 blocks, M=56, N=128.
// Waves (mw,nw): output row ho0+mw, 4 cotiles at nh*8+nw*4.
// NO per-channel atomics: extrema -> LDS -> per-block scratch rows (reduced by k_red).
__global__ __launch_bounds__(THREADS, 2) void k_conv1(const int* __restrict__ X8,
                                                      const vi4* __restrict__ W1m,
                                                      const vi4* __restrict__ Widm,
                                                      int* __restrict__ H1, int* __restrict__ IDI,
                                                      int* __restrict__ maxS,
                                                      int* __restrict__ minS,
                                                      int* __restrict__ maxabs_id) {
  __shared__ __align__(16) int lds[5 * 58 * 36];
  __shared__ int sMax[2][128], sMin[2][128], redA[4];
  const int tid = threadIdx.x;
  const int bx = blockIdx.x;
  const int n = bx / 28, rr = bx % 28;
  const int hp = rr >> 1, nh = rr & 1;
  const int ho0 = hp * 2;

  for (int r = 0; r < 5; ++r) {
    int h = 2 * ho0 - 1 + r;
    int* dst = lds + r * 58 * 36;
    if (h >= 0 && h < 56) {
      const int* src = X8 + (n * 56 + h) * 56 * 32;
      for (int i = tid; i < 56 * 32; i += THREADS) {
        int col = i >> 5, c = i & 31;
        dst[(col + 1) * 36 + c] = src[i];
      }
      if (tid < 32) dst[tid] = 0;
      else if (tid >= 128 && tid < 160) dst[57 * 36 + (tid - 128)] = 0;
    } else {
      for (int i = tid; i < 58 * 36; i += THREADS) dst[i] = 0;
    }
  }
  __syncthreads();

  const int lane = tid & 63, wv = tid >> 6;
  const int mw = wv & 1, nw = wv >> 1;
  const int lm = lane & 15, quad = lane >> 4;
  const int woc0 = lm, woc1 = (16 + lm) > 27 ? 27 : (16 + lm);
  const int choff = quad * 4;
  const int ho = ho0 + mw;
  const int obase = ((n * 28 + ho) * 28) * 256;
  const int ctbase = nh * 8 + nw * 4;

  vi4 zero = {0, 0, 0, 0};
  vi4 acc[2][4];
  vi4 bcur[4], bnext[4];
  vi4 a0c, a1c, a0n, a1n;

  // ---- identity branch first (2 K-steps), reusing acc ----
#pragma unroll
  for (int mt = 0; mt < 2; ++mt)
#pragma unroll
    for (int ct = 0; ct < 4; ++ct) acc[mt][ct] = zero;
  const vi4* wibase = Widm + ctbase * 64 + lane;
  {
    const int ro = (2 * mw + 1) * 58;
#pragma unroll
    for (int kc = 0; kc < 2; ++kc) {
      vi4 a0 = *(const vi4*)(lds + (ro + 2 * woc0 + 1) * 36 + kc * 16 + choff);
      vi4 a1 = *(const vi4*)(lds + (ro + 2 * woc1 + 1) * 36 + kc * 16 + choff);
#pragma unroll
      for (int ct = 0; ct < 4; ++ct) {
        vi4 b = wibase[kc * 1024 + ct * 64];
        acc[0][ct] = MFMA_I8(a0, b, acc[0][ct]);
        acc[1][ct] = MFMA_I8(a1, b, acc[1][ct]);
      }
    }
  }
  int am = 0;
#pragma unroll
  for (int ct = 0; ct < 4; ++ct) {
    const int co = (ctbase + ct) * 16 + lm;
#pragma unroll
    for (int mt = 0; mt < 2; ++mt)
#pragma unroll
      for (int r = 0; r < 4; ++r) {
        int wo = mt * 16 + quad * 4 + r;
        if (wo < 28) {
          int v = acc[mt][ct][r];
          IDI[obase + wo * 256 + co] = v;
          am = max(am, v < 0 ? -v : v);
        }
      }
  }
#pragma unroll
  for (int k = 32; k >= 1; k >>= 1) am = max(am, __shfl_xor(am, k));
  if (lane == 0) redA[wv] = am;

  // ---- main 3x3 conv, 18 K-steps, software-pipelined ----
#pragma unroll
  for (int mt = 0; mt < 2; ++mt)
#pragma unroll
    for (int ct = 0; ct < 4; ++ct) acc[mt][ct] = zero;
  const vi4* wbase = W1m + ctbase * 64 + lane;
#pragma unroll
  for (int ct = 0; ct < 4; ++ct) bcur[ct] = wbase[ct * 64];
  {
    const int ro = (2 * mw) * 58;  // kh=0
    a0c = *(const vi4*)(lds + (ro + 2 * woc0) * 36 + choff);
    a1c = *(const vi4*)(lds + (ro + 2 * woc1) * 36 + choff);
  }
#pragma unroll 1
  for (int ks = 0; ks < 18; ++ks) {
    int ksn = ks + 1;
    if (ksn < 18) {
      int khn = (ksn >= 6) + (ksn >= 12);
      int t2 = ksn - khn * 6;
      int kwn = t2 >> 1, kcn = t2 & 1;
#pragma unroll
      for (int ct = 0; ct < 4; ++ct) bnext[ct] = wbase[ksn * 1024 + ct * 64];
      int ro = (2 * mw + khn) * 58;
      a0n = *(const vi4*)(lds + (ro + 2 * woc0 + kwn) * 36 + kcn * 16 + choff);
      a1n = *(const vi4*)(lds + (ro + 2 * woc1 + kwn) * 36 + kcn * 16 + choff);
    }
#pragma unroll
    for (int ct = 0; ct < 4; ++ct) {
      acc[0][ct] = MFMA_I8(a0c, bcur[ct], acc[0][ct]);
      acc[1][ct] = MFMA_I8(a1c, bcur[ct], acc[1][ct]);
    }
    a0c = a0n;
    a1c = a1n;
#pragma unroll
    for (int ct = 0; ct < 4; ++ct) bcur[ct] = bnext[ct];
  }

#pragma unroll
  for (int ct = 0; ct < 4; ++ct) {
    const int co = (ctbase + ct) * 16 + lm;
    int vmax = INT_MIN, vmin = INT_MAX;
#pragma unroll
    for (int mt = 0; mt < 2; ++mt)
#pragma unroll
      for (int r = 0; r < 4; ++r) {
        int wo = mt * 16 + quad * 4 + r;
        if (wo < 28) {
          int v = acc[mt][ct][r];
          H1[obase + wo * 256 + co] = v;
          vmax = max(vmax, v);
          vmin = min(vmin, v);
        }
      }
    vmax = max(vmax, __shfl_xor(vmax, 16));
    vmax = max(vmax, __shfl_xor(vmax, 32));
    vmin = min(vmin, __shfl_xor(vmin, 16));
    vmin = min(vmin, __shfl_xor(vmin, 32));
    if (lane < 16) {
      sMax[mw][nw * 64 + ct * 16 + lane] = vmax;
      sMin[mw][nw * 64 + ct * 16 + lane] = vmin;
    }
  }
  __syncthreads();
  if (tid < 128) {
    int row = n * 14 + hp;
    maxS[row * 256 + nh * 128 + tid] = max(sMax[0][tid], sMax[1][tid]);
    minS[row * 256 + nh * 128 + tid] = min(sMin[0][tid], sMin[1][tid]);
  }
  if (tid == 0) {
    int a = max(max(redA[0], redA[1]), max(redA[2], redA[3]));
    atomicMax(maxabs_id, a);
  }
}

// Reduce per-block extrema scratch (448 rows x 256 ch) into maxv/minv. 32 blocks.
__global__ __launch_bounds__(THREADS) void k_red(const int* __restrict__ maxS,
                                                 const int* __restrict__ minS,
                                                 int* __restrict__ maxv, int* __restrict__ minv) {
  int c = threadIdx.x, b = blockIdx.x;
  int vx = INT_MIN, vn = INT_MAX;
#pragma unroll
  for (int r = 0; r < 14; ++r) {
    int row = b * 14 + r;
    vx = max(vx, maxS[row * 256 + c]);
    vn = min(vn, minS[row * 256 + c]);
  }
  atomicMax(&maxv[c], vx);
  atomicMin(&minv[c], vn);
}

// Derive stage-1 scales.
__global__ __launch_bounds__(THREADS) void k_s1(int* __restrict__ IS, float* __restrict__ SC,
                                                const int* __restrict__ maxv,
                                                const int* __restrict__ minv,
                                                const float* __restrict__ wq1,
                                                const float* __restrict__ b1) {
  __shared__ int ri[THREADS];
  __shared__ float rf[THREADS];
  int c = threadIdx.x;
  int vmax = maxv[c], vmin = minv[c];
  int a1 = vmax < 0 ? -vmax : vmax;
  int a0 = vmin < 0 ? -vmin : vmin;
  ri[c] = max(a1, a0);
  __syncthreads();
  for (int s = THREADS / 2; s > 0; s >>= 1) {
    if (c < s) ri[c] = max(ri[c], ri[c + s]);
    __syncthreads();
  }
  int mh1 = ri[0];
  const unsigned* ISu = (const unsigned*)IS;
  float sx = sc_from_bits(ISu[0]);
  float sw1 = sc_from_bits(ISu[1]);
  float sxw = sx * sw1;
  float s_h1 = fmaxf(sxw * (float)mh1 / 127.0f, 1e-8f);
  float wq = wq1[c], bbc = b1[c];
  float q1 = clamp8f(rintf((float)vmax * sxw / s_h1));
  float q0 = clamp8f(rintf((float)vmin * sxw / s_h1));
  float hv1 = q1 * s_h1, hv0 = q0 * s_h1;
  float y1 = fmaxf(hv1 * wq + bbc, 0.0f);
  float y0 = fmaxf(hv0 * wq + bbc, 0.0f);
  rf[c] = fmaxf(y1, y0);
  __syncthreads();
  for (int s = THREADS / 2; s > 0; s >>= 1) {
    if (c < s) rf[c] = fmaxf(rf[c], rf[c + s]);
    __syncthreads();
  }
  if (c == 0) {
    IS[4] = mh1;
    SC[7] = rf[0];
    SC[8] = s_h1;
    SC[9] = fmaxf(rf[0] / 127.0f, 1e-8f);
    float swid = sc_from_bits(ISu[3]);
    SC[10] = fmaxf(sx * swid * (float)IS[5] / 127.0f, 1e-8f);
  }
}

// quant(h1) -> bn1 -> relu -> quant => A2 int8 (NHWC)
__device__ __forceinline__ signed char qact(int v, float sxw, float s_h1, float s_y2, float wq,
                                            float bb) {
  float hf = (float)v * sxw;
  float q = clamp8f(rintf(hf / s_h1));
  float hv = q * s_h1;
  float y = fmaxf(hv * wq + bb, 0.0f);
  float a = fminf(fmaxf(rintf(y / s_y2), -128.0f), 127.0f);
  return (signed char)(int)a;
}

__global__ __launch_bounds__(THREADS) void k_qh1(const int4* __restrict__ H1,
                                                 char4* __restrict__ A2,
                                                 const float* __restrict__ SC,
                                                 const float* __restrict__ wq1,
                                                 const float* __restrict__ b1) {
  int t = blockIdx.x * THREADS + threadIdx.x;  // < 1,605,632
  const unsigned* ISu = (const unsigned*)SC;
  float sx = sc_from_bits(ISu[0]);
  float sw1 = sc_from_bits(ISu[1]);
  float sxw = sx * sw1;
  float s_h1 = SC[8];
  float s_y2 = SC[9];
  int4 v = H1[t];
  int c0 = (t * 4) & 255;
  char4 r;
  r.x = qact(v.x, sxw, s_h1, s_y2, wq1[c0], b1[c0]);
  r.y = qact(v.y, sxw, s_h1, s_y2, wq1[c0 + 1], b1[c0 + 1]);
  r.z = qact(v.z, sxw, s_h1, s_y2, wq1[c0 + 2], b1[c0 + 2]);
  r.w = qact(v.w, sxw, s_h1, s_y2, wq1[c0 + 3], b1[c0 + 3]);
  A2[t] = r;
}

// conv2 3x3 s1 p1 (Cin=256), MFMA implicit GEMM. 896 blocks (n, ho-pair, N-half).
__global__ __launch_bounds__(THREADS, 2) void k_conv2(const int* __restrict__ A2,
                                                      const vi4* __restrict__ W2m,
                                                      int* __restrict__ H2,
                                                      int* __restrict__ maxabs_h2) {
  __shared__ __align__(16) int lds[4 * 30 * 68];
  __shared__ int redA[4];
  const int tid = threadIdx.x;
  const int bx = blockIdx.x;
  const int n = bx / 28, rr = bx % 28;
  const int hp = rr >> 1, nh = rr & 1;
  const int ho0 = hp * 2;

  for (int r = 0; r < 4; ++r) {
    int h = ho0 - 1 + r;
    int* dst = lds + r * 30 * 68;
    if (h >= 0 && h < 28) {
      const int* src = A2 + (n * 28 + h) * 28 * 64;
      for (int i = tid; i < 28 * 64; i += THREADS) {
        int col = i >> 6, c = i & 63;
        dst[(col + 1) * 68 + c] = src[i];
      }
      if (tid < 64) dst[tid] = 0;
      else if (tid >= 128 && tid < 192) dst[29 * 68 + (tid - 128)] = 0;
    } else {
      for (int i = tid; i < 30 * 68; i += THREADS) dst[i] = 0;
    }
  }
  __syncthreads();

  const int lane = tid & 63, wv = tid >> 6;
  const int mw = wv & 1, nw = wv >> 1;
  const int lm = lane & 15, quad = lane >> 4;
  const int woc0 = lm, woc1 = (16 + lm) > 27 ? 27 : (16 + lm);
  const int choff = quad * 4;
  const int ho = ho0 + mw;
  const int ctbase = nh * 8 + nw * 4;

  vi4 zero = {0, 0, 0, 0};
  vi4 acc[2][4];
#pragma unroll
  for (int mt = 0; mt < 2; ++mt)
#pragma unroll
    for (int ct = 0; ct < 4; ++ct) acc[mt][ct] = zero;

  const vi4* wbase = W2m + ctbase * 64 + lane;
  vi4 bcur[4], bnext[4];
  vi4 a0c, a1c, a0n, a1n;
#pragma unroll
  for (int ct = 0; ct < 4; ++ct) bcur[ct] = wbase[ct * 64];
  {
    const int ro = mw * 30;  // kh=0
    a0c = *(const vi4*)(lds + (ro + woc0) * 68 + choff);
    a1c = *(const vi4*)(lds + (ro + woc1) * 68 + choff);
  }
#pragma unroll 1
  for (int ks = 0; ks < 36; ++ks) {
    int ksn = ks + 1;
    if (ksn < 36) {
      int khn = (ksn >= 12) + (ksn >= 24);
      int t2 = ksn - khn * 12;
      int kwn = t2 >> 2, kcn = t2 & 3;
#pragma unroll
      for (int ct = 0; ct < 4; ++ct) bnext[ct] = wbase[ksn * 1024 + ct * 64];
      int ro = (mw + khn) * 30;
      a0n = *(const vi4*)(lds + (ro + woc0 + kwn) * 68 + kcn * 16 + choff);
      a1n = *(const vi4*)(lds + (ro + woc1 + kwn) * 68 + kcn * 16 + choff);
    }
#pragma unroll
    for (int ct = 0; ct < 4; ++ct) {
      acc[0][ct] = MFMA_I8(a0c, bcur[ct], acc[0][ct]);
      acc[1][ct] = MFMA_I8(a1c, bcur[ct], acc[1][ct]);
    }
    a0c = a0n;
    a1c = a1n;
#pragma unroll
    for (int ct = 0; ct < 4; ++ct) bcur[ct] = bnext[ct];
  }

  const int obase = ((n * 28 + ho) * 28) * 256;
  int am = 0;
#pragma unroll
  for (int ct = 0; ct < 4; ++ct) {
    const int co = (ctbase + ct) * 16 + lm;
#pragma unroll
    for (int mt = 0; mt < 2; ++mt)
#pragma unroll
      for (int r = 0; r < 4; ++r) {
        int wo = mt * 16 + quad * 4 + r;
        if (wo < 28) {
          int v = acc[mt][ct][r];
          H2[obase + wo * 256 + co] = v;
          am = max(am, v < 0 ? -v : v);
        }
      }
  }
#pragma unroll
  for (int k = 32; k >= 1; k >>= 1) am = max(am, __shfl_xor(am, k));
  if (lane == 0) redA[wv] = am;
  __syncthreads();
  if (tid == 0) {
    int a = max(max(redA[0], redA[1]), max(redA[2], redA[3]));
    atomicMax(maxabs_h2, a);
  }
}

// ---- residual sum math shared by k_absmax2 / k_out ----
struct SumParams {
  float sxw2, s_h2, sxwid, s_idq;
};
__device__ __forceinline__ float sum_val(int v2, int vi, const SumParams& P, float wq2c, float b2c,
                                         float wqidc, float bidc) {
  float q2 = clamp8f(rintf((float)v2 * P.sxw2 / P.s_h2));
  float z = (q2 * P.s_h2) * wq2c + b2c;
  float qi = clamp8f(rintf((float)vi * P.sxwid / P.s_idq));
  float zi = (qi * P.s_idq) * wqidc + bidc;
  return z + zi;
}
__device__ __forceinline__ SumParams make_params(const float* SC, const int* IS) {
  const unsigned* ISu = (const unsigned*)IS;
  SumParams P;
  float sx = sc_from_bits(ISu[0]);
  float sw2 = sc_from_bits(ISu[2]);
  float swid = sc_from_bits(ISu[3]);
  float s_y2 = SC[9];
  P.s_idq = SC[10];
  P.sxw2 = s_y2 * sw2;
  P.s_h2 = fmaxf(P.sxw2 * (float)IS[6] / 127.0f, 1e-8f);
  P.sxwid = sx * swid;
  return P;
}

// Pass 1: global absmax of residual sum. Grid-stride, 1 atomic/block.
__global__ __launch_bounds__(THREADS) void k_absmax2(const int4* __restrict__ H2,
                                                     const int4* __restrict__ IDI,
                                                     const float* __restrict__ SC,
                                                     const int* __restrict__ IS,
                                                     const float* __restrict__ wq2,
                                                     const float* __restrict__ b2,
                                                     const float* __restrict__ wqid,
                                                     const float* __restrict__ bidp,
                                                     unsigned* __restrict__ slot) {
  __shared__ float pw2[256], pb2[256], pwi[256], pbi[256];
  int tid = threadIdx.x;
  pw2[tid] = wq2[tid];
  pb2[tid] = b2[tid];
  pwi[tid] = wqid[tid];
  pbi[tid] = bidp[tid];
  __syncthreads();
  SumParams P = make_params(SC, IS);
  const int n4 = 1605632;
  const int stride = gridDim.x * THREADS;
  float m = 0.0f;
  for (int i = blockIdx.x * THREADS + tid; i < n4; i += stride) {
    int4 v2 = H2[i];
    int4 vi = IDI[i];
    int c0 = (i * 4) & 255;
    m = fmaxf(m, fabsf(sum_val(v2.x, vi.x, P, pw2[c0], pb2[c0], pwi[c0], pbi[c0])));
    m = fmaxf(m, fabsf(sum_val(v2.y, vi.y, P, pw2[c0 + 1], pb2[c0 + 1], pwi[c0 + 1], pbi[c0 + 1])));
    m = fmaxf(m, fabsf(sum_val(v2.z, vi.z, P, pw2[c0 + 2], pb2[c0 + 2], pwi[c0 + 2], pbi[c0 + 2])));
    m = fmaxf(m, fabsf(sum_val(v2.w, vi.w, P, pw2[c0 + 3], pb2[c0 + 3], pwi[c0 + 3], pbi[c0 + 3])));
  }
#pragma unroll
  for (int k = 32; k >= 1; k >>= 1) m = fmaxf(m, __shfl_xor(m, k));
  __shared__ float wred[4];
  if ((tid & 63) == 0) wred[tid >> 6] = m;
  __syncthreads();
  if (tid == 0) {
    m = fmaxf(fmaxf(wred[0], wred[1]), fmaxf(wred[2], wred[3]));
    atomicMax(slot, __float_as_uint(m));
  }
}

// Pass 2: recompute sum, final requant + relu, write NCHW via padded LDS tile transpose.
__global__ __launch_bounds__(THREADS) void k_out(const int* __restrict__ H2,
                                                 const int* __restrict__ IDI,
                                                 const float* __restrict__ SC,
                                                 const int* __restrict__ IS,
                                                 const float* __restrict__ wq2,
                                                 const float* __restrict__ b2,
                                                 const float* __restrict__ wqid,
                                                 const float* __restrict__ bidp,
                                                 float* __restrict__ out) {
  __shared__ float tile[64 * 57];
  __shared__ float pw2[64], pb2[64], pwi[64], pbi[64];
  int tid = threadIdx.x;
  int b = blockIdx.x;
  int ct = b & 3;
  int rt = (b >> 2) % 14;
  int n = b / 56;
  int c0 = ct * 64;
  int r0 = rt * 56;
  if (tid < 64) {
    pw2[tid] = wq2[c0 + tid];
    pb2[tid] = b2[c0 + tid];
    pwi[tid] = wqid[c0 + tid];
    pbi[tid] = bidp[c0 + tid];
  }
  __syncthreads();
  SumParams P = make_params(SC, IS);
  float out_s = fmaxf(__uint_as_float(((const unsigned*)IS)[11]) / 127.0f, 1e-8f);

  const int base = (n * 784 + r0) * 256 + c0;
#pragma unroll
  for (int k = 0; k < 14; ++k) {
    int idx = tid + k * 256;  // < 3584
    int rl = idx >> 6;
    int cl = idx & 63;
    int e = base + rl * 256 + cl;
    float sv = sum_val(H2[e], IDI[e], P, pw2[cl], pb2[cl], pwi[cl], pbi[cl]);
    float q = clamp8f(rintf(sv / out_s));
    tile[cl * 57 + rl] = q > 0.0f ? q * out_s : 0.0f;
  }
  __syncthreads();
  float* ob = out + n * 200704 + c0 * 784 + r0;
#pragma unroll
  for (int k = 0; k < 14; ++k) {
    int idx = tid + k * 256;
    int cl = idx / 56;
    int rl = idx % 56;
    ob[cl * 784 + rl] = tile[cl * 57 + rl];
  }
  if (b == 0 && tid == 0) out[6422528] = out_s;
}

extern "C" void kernel_launch(void* const* d_in, const int* in_sizes, int n_in, void* d_out,
                              int out_size, void* d_ws, size_t ws_size, hipStream_t stream) {
  (void)in_sizes; (void)n_in; (void)out_size; (void)ws_size;
  const float* x = (const float*)d_in[0];
  const float* w1 = (const float*)d_in[1];
  const float* w2 = (const float*)d_in[2];
  const float* wid = (const float*)d_in[3];
  const float* bn1g = (const float*)d_in[4];
  const float* bn1b = (const float*)d_in[5];
  const float* bn1m = (const float*)d_in[6];
  const float* bn1v = (const float*)d_in[7];
  const float* bn2g = (const float*)d_in[8];
  const float* bn2b = (const float*)d_in[9];
  const float* bn2m = (const float*)d_in[10];
  const float* bn2v = (const float*)d_in[11];
  const float* idg = (const float*)d_in[12];
  const float* idb = (const float*)d_in[13];
  const float* idm = (const float*)d_in[14];
  const float* idv = (const float*)d_in[15];

  char* ws = (char*)d_ws;
  float* SC = (float*)ws;
  int* IS = (int*)ws;
  unsigned* ISu = (unsigned*)ws;
  int* maxv = (int*)(ws + 1024);
  int* minv = (int*)(ws + 2048);
  float* wq1 = (float*)(ws + 3072);
  float* b1 = (float*)(ws + 4096);
  float* wq2 = (float*)(ws + 5120);
  float* b2 = (float*)(ws + 6144);
  float* wqid = (float*)(ws + 7168);
  float* bid = (float*)(ws + 8192);
  char* X8 = ws + 16384;                 // NHWC int8; A2 overlays after conv1
  char* A2 = X8;
  char* W1m = X8 + 12845056;
  char* W2m = W1m + 294912;
  char* Widm = W2m + 589824;
  int* H1 = (int*)(Widm + 32768);
  int* H2 = H1;
  int* IDI = (int*)((char*)H1 + 25690112);
  float* out = (float*)d_out;
  // Per-block extrema scratch lives in d_out (dead until k_out overwrites it):
  // 448 rows x 256 ch, max then min. 917504 B << 25.7 MB.
  int* maxS = (int*)d_out;
  int* minS = maxS + 448 * 256;

  k_init<<<1, THREADS, 0, stream>>>(IS, maxv, minv);
  k_amax<<<512, THREADS, 0, stream>>>((const float4*)x, 3211264, ISu + 0);
  k_amax<<<64, THREADS, 0, stream>>>((const float4*)w1, 73728, ISu + 1);
  k_amax<<<128, THREADS, 0, stream>>>((const float4*)w2, 147456, ISu + 2);
  k_amax<<<16, THREADS, 0, stream>>>((const float4*)wid, 8192, ISu + 3);
  k_bnfold<<<1, THREADS, 0, stream>>>(bn1g, bn1b, bn1m, bn1v, wq1, b1);
  k_bnfold<<<1, THREADS, 0, stream>>>(bn2g, bn2b, bn2m, bn2v, wq2, b2);
  k_bnfold<<<1, THREADS, 0, stream>>>(idg, idb, idm, idv, wqid, bid);
  k_qx<<<1792, THREADS, 0, stream>>>(x, (int*)X8, ISu);
  k_qw1m<<<72, THREADS, 0, stream>>>(w1, (vi4*)W1m, ISu);
  k_qw2m<<<144, THREADS, 0, stream>>>(w2, (vi4*)W2m, ISu);
  k_qwidm<<<8, THREADS, 0, stream>>>(wid, (vi4*)Widm, ISu);
  k_conv1<<<896, THREADS, 0, stream>>>((const int*)X8, (const vi4*)W1m, (const vi4*)Widm, H1, IDI,
                                       maxS, minS, IS + 5);
  k_red<<<32, THREADS, 0, stream>>>(maxS, minS, maxv, minv);
  k_s1<<<1, THREADS, 0, stream>>>(IS, SC, maxv, minv, wq1, b1);
  k_qh1<<<6272, THREADS, 0, stream>>>((const int4*)H1, (char4*)A2, SC, wq1, b1);
  k_conv2<<<896, THREADS, 0, stream>>>((const int*)A2, (const vi4*)W2m, H2, IS + 6);
  k_absmax2<<<1024, THREADS, 0, stream>>>((const int4*)H2, (const int4*)IDI, SC, IS, wq2, b2, wqid,
                                          bid, ISu + 11);
  k_out<<<1792, THREADS, 0, stream>>>(H2, IDI, SC, IS, wq2, b2, wqid, bid, out);
}

// Round 7
// 286.537 us; speedup vs baseline: 3.1819x; 1.0222x over previous
//
#include <hip/hip_runtime.h>
#include <limits.h>

#define THREADS 256

typedef int vi4 __attribute__((ext_vector_type(4)));

__device__ __forceinline__ float clamp8f(float q) { return fminf(fmaxf(q, -128.0f), 127.0f); }
__device__ __forceinline__ float sc_from_bits(unsigned b) {
  return fmaxf(__uint_as_float(b) / 127.0f, 1e-8f);
}
__device__ __forceinline__ signed char q8(float v, float s) {
  return (signed char)(int)clamp8f(rintf(v / s));
}

// Scalar slots: [0] amax_x [1] amax_w1 [2] amax_w2 [3] amax_wid
// [4] maxabs_h1 [5] maxabs_id [6] maxabs_h2 [7] max_y2 [8] s_h1 [9] s_y2 [10] s_idq [11] amax_sum

// Merged init + 3x bnfold. Block 0: init; blocks 1..3: bnfold for (bn1, bn2, id).
__global__ __launch_bounds__(THREADS) void k_boot(int* IS, int* maxv, int* minv,
                                                  const float* g1, const float* be1,
                                                  const float* m1, const float* v1,
                                                  float* wq1, float* b1, const float* g2,
                                                  const float* be2, const float* m2,
                                                  const float* v2, float* wq2, float* b2,
                                                  const float* gi, const float* bei,
                                                  const float* mi, const float* vi,
                                                  float* wqi, float* bi) {
  int c = threadIdx.x;
  if (blockIdx.x == 0) {
    if (c < 64) IS[c] = 0;
    maxv[c] = INT_MIN;
    minv[c] = INT_MAX;
    return;
  }
  const float *gamma, *beta, *mean, *var;
  float *wq, *bb;
  if (blockIdx.x == 1) { gamma = g1; beta = be1; mean = m1; var = v1; wq = wq1; bb = b1; }
  else if (blockIdx.x == 2) { gamma = g2; beta = be2; mean = m2; var = v2; wq = wq2; bb = b2; }
  else { gamma = gi; beta = bei; mean = mi; var = vi; wq = wqi; bb = bi; }
  __shared__ float red[THREADS];
  float ws = gamma[c] * (1.0f / sqrtf(var[c] + 1e-5f));
  red[c] = fabsf(ws);
  __syncthreads();
  for (int s = THREADS / 2; s > 0; s >>= 1) {
    if (c < s) red[c] = fmaxf(red[c], red[c + s]);
    __syncthreads();
  }
  float sws = fmaxf(red[0] / 127.0f, 1e-8f);
  float q = clamp8f(rintf(ws / sws)) * sws;
  wq[c] = q;
  bb[c] = beta[c] - mean[c] * q;
}

__device__ __forceinline__ void amax_body(const float4* __restrict__ p, int n4, int bid,
                                          int nblocks, unsigned* __restrict__ slot) {
  const int tid = threadIdx.x;
  const int stride = nblocks * THREADS;
  float m = 0.0f;
  int i = bid * THREADS + tid;
  for (; i + 3 * stride < n4; i += 4 * stride) {
    float4 v0 = p[i];
    float4 v1 = p[i + stride];
    float4 v2 = p[i + 2 * stride];
    float4 v3 = p[i + 3 * stride];
    float m0 = fmaxf(fmaxf(fabsf(v0.x), fabsf(v0.y)), fmaxf(fabsf(v0.z), fabsf(v0.w)));
    float m1 = fmaxf(fmaxf(fabsf(v1.x), fabsf(v1.y)), fmaxf(fabsf(v1.z), fabsf(v1.w)));
    float m2 = fmaxf(fmaxf(fabsf(v2.x), fabsf(v2.y)), fmaxf(fabsf(v2.z), fabsf(v2.w)));
    float m3 = fmaxf(fmaxf(fabsf(v3.x), fabsf(v3.y)), fmaxf(fabsf(v3.z), fabsf(v3.w)));
    m = fmaxf(m, fmaxf(fmaxf(m0, m1), fmaxf(m2, m3)));
  }
  for (; i < n4; i += stride) {
    float4 v = p[i];
    m = fmaxf(m, fmaxf(fmaxf(fabsf(v.x), fabsf(v.y)), fmaxf(fabsf(v.z), fabsf(v.w))));
  }
#pragma unroll
  for (int k = 32; k >= 1; k >>= 1) m = fmaxf(m, __shfl_xor(m, k));
  __shared__ float wred[4];
  if ((tid & 63) == 0) wred[tid >> 6] = m;
  __syncthreads();
  if (tid == 0) {
    m = fmaxf(fmaxf(wred[0], wred[1]), fmaxf(wred[2], wred[3]));
    atomicMax(slot, __float_as_uint(m));
  }
}

// absmax of x (512 blocks)
__global__ __launch_bounds__(THREADS) void k_amax(const float4* __restrict__ p, int n4,
                                                  unsigned* __restrict__ slot) {
  amax_body(p, n4, blockIdx.x, gridDim.x, slot);
}

// Merged weight absmaxes: blocks [0,64)->w1, [64,192)->w2, [192,208)->wid.
__global__ __launch_bounds__(THREADS) void k_amaxw(const float4* __restrict__ w1,
                                                   const float4* __restrict__ w2,
                                                   const float4* __restrict__ wid,
                                                   unsigned* __restrict__ ISu) {
  int b = blockIdx.x;
  if (b < 64) amax_body(w1, 73728, b, 64, ISu + 1);
  else if (b < 192) amax_body(w2, 147456, b - 64, 128, ISu + 2);
  else amax_body(wid, 8192, b - 192, 16, ISu + 3);
}

// Quantize x (NCHW f32) -> X8 (NHWC int8) via LDS transpose.
__global__ __launch_bounds__(THREADS) void k_qx(const float* __restrict__ x, int* __restrict__ X8,
                                                const unsigned* __restrict__ ISu) {
  __shared__ signed char tile[56 * 132];
  float s = sc_from_bits(ISu[0]);
  int b = blockIdx.x;  // 32*56
  int h = b % 56, n = b / 56;
  int t = threadIdx.x;
  const float* xp = x + ((n * 128) * 56 + h) * 56;
#pragma unroll
  for (int k = 0; k < 28; ++k) {
    int i = t + k * 256;  // < 7168
    int w = i % 56, c = i / 56;
    tile[w * 132 + c] = q8(xp[c * 3136 + w], s);
  }
  __syncthreads();
  int* op = X8 + (n * 56 + h) * 56 * 32;
#pragma unroll
  for (int k = 0; k < 7; ++k) {
    int i = t + k * 256;  // < 1792
    int w = i >> 5, c4 = (i & 31) * 4;
    const signed char* tp = tile + w * 132 + c4;
    op[i] = (int)(unsigned char)tp[0] | ((int)(unsigned char)tp[1] << 8) |
            ((int)(unsigned char)tp[2] << 16) | ((int)(unsigned char)tp[3] << 24);
  }
}

// Repack 3x3 weights into MFMA B-fragment order.
__global__ __launch_bounds__(THREADS) void k_qw2m(const float* __restrict__ w, vi4* __restrict__ wm,
                                                  const unsigned* __restrict__ ISu) {
  int t = blockIdx.x * THREADS + threadIdx.x;  // < 36864
  float s = sc_from_bits(ISu[2]);
  int lane = t & 63;
  int cotile = (t >> 6) & 15;
  int ks = t >> 10;  // 0..35
  int tap = ks >> 2, kc = ks & 3;
  int kh = tap / 3, kw = tap % 3;
  int co = cotile * 16 + (lane & 15);
  int ci0 = kc * 64 + (lane >> 4) * 16;
  const float* src = w + (co * 256 + ci0) * 9 + kh * 3 + kw;
  int r[4];
#pragma unroll
  for (int q = 0; q < 4; ++q) {
    unsigned b0 = (unsigned char)q8(src[(q * 4 + 0) * 9], s);
    unsigned b1 = (unsigned char)q8(src[(q * 4 + 1) * 9], s);
    unsigned b2 = (unsigned char)q8(src[(q * 4 + 2) * 9], s);
    unsigned b3 = (unsigned char)q8(src[(q * 4 + 3) * 9], s);
    r[q] = (int)(b0 | (b1 << 8) | (b2 << 16) | (b3 << 24));
  }
  vi4 v = {r[0], r[1], r[2], r[3]};
  wm[t] = v;
}

__global__ __launch_bounds__(THREADS) void k_qw1m(const float* __restrict__ w, vi4* __restrict__ wm,
                                                  const unsigned* __restrict__ ISu) {
  int t = blockIdx.x * THREADS + threadIdx.x;  // < 18432
  float s = sc_from_bits(ISu[1]);
  int lane = t & 63;
  int cotile = (t >> 6) & 15;
  int ks = t >> 10;  // 0..17
  int tap = ks >> 1, kc = ks & 1;
  int kh = tap / 3, kw = tap % 3;
  int co = cotile * 16 + (lane & 15);
  int ci0 = kc * 64 + (lane >> 4) * 16;
  const float* src = w + (co * 128 + ci0) * 9 + kh * 3 + kw;
  int r[4];
#pragma unroll
  for (int q = 0; q < 4; ++q) {
    unsigned b0 = (unsigned char)q8(src[(q * 4 + 0) * 9], s);
    unsigned b1 = (unsigned char)q8(src[(q * 4 + 1) * 9], s);
    unsigned b2 = (unsigned char)q8(src[(q * 4 + 2) * 9], s);
    unsigned b3 = (unsigned char)q8(src[(q * 4 + 3) * 9], s);
    r[q] = (int)(b0 | (b1 << 8) | (b2 << 16) | (b3 << 24));
  }
  vi4 v = {r[0], r[1], r[2], r[3]};
  wm[t] = v;
}

__global__ __launch_bounds__(THREADS) void k_qwidm(const float* __restrict__ w,
                                                   vi4* __restrict__ wm,
                                                   const unsigned* __restrict__ ISu) {
  int t = blockIdx.x * THREADS + threadIdx.x;  // < 2048
  float s = sc_from_bits(ISu[3]);
  int lane = t & 63;
  int cotile = (t >> 6) & 15;
  int ks = t >> 10;  // 0..1
  int co = cotile * 16 + (lane & 15);
  int ci0 = ks * 64 + (lane >> 4) * 16;
  const float* src = w + co * 128 + ci0;
  int r[4];
#pragma unroll
  for (int q = 0; q < 4; ++q) {
    unsigned b0 = (unsigned char)q8(src[q * 4 + 0], s);
    unsigned b1 = (unsigned char)q8(src[q * 4 + 1], s);
    unsigned b2 = (unsigned char)q8(src[q * 4 + 2], s);
    unsigned b3 = (unsigned char)q8(src[q * 4 + 3], s);
    r[q] = (int)(b0 | (b1 << 8) | (b2 << 16) | (b3 << 24));
  }
  vi4 v = {r[0], r[1], r[2], r[3]};
  wm[t] = v;
}

#define MFMA_I8(a, b, c) __builtin_amdgcn_mfma_i32_16x16x64_i8(a, b, c, 0, 0, 0)

// conv1 3x3 s2 p1 (Cin=128) + identity 1x1 s2, MFMA implicit GEMM.
// 896 blocks (n, ho-pair, N-half). Fully-unrolled K-loop, distance-2 B prefetch.
__global__ __launch_bounds__(THREADS, 2) void k_conv1(const int* __restrict__ X8,
                                                      const vi4* __restrict__ W1m,
                                                      const vi4* __restrict__ Widm,
                                                      int* __restrict__ H1, int* __restrict__ IDI,
                                                      int* __restrict__ maxS,
                                                      int* __restrict__ minS,
                                                      int* __restrict__ maxabs_id) {
  __shared__ __align__(16) int lds[5 * 58 * 36];
  __shared__ int sMax[2][128], sMin[2][128], redA[4];
  const int tid = threadIdx.x;
  const int bx = blockIdx.x;
  const int n = bx / 28, rr = bx % 28;
  const int hp = rr >> 1, nh = rr & 1;
  const int ho0 = hp * 2;

  for (int r = 0; r < 5; ++r) {
    int h = 2 * ho0 - 1 + r;
    int* dst = lds + r * 58 * 36;
    if (h >= 0 && h < 56) {
      const int* src = X8 + (n * 56 + h) * 56 * 32;
      for (int i = tid; i < 56 * 32; i += THREADS) {
        int col = i >> 5, c = i & 31;
        dst[(col + 1) * 36 + c] = src[i];
      }
      if (tid < 32) dst[tid] = 0;
      else if (tid >= 128 && tid < 160) dst[57 * 36 + (tid - 128)] = 0;
    } else {
      for (int i = tid; i < 58 * 36; i += THREADS) dst[i] = 0;
    }
  }
  __syncthreads();

  const int lane = tid & 63, wv = tid >> 6;
  const int mw = wv & 1, nw = wv >> 1;
  const int lm = lane & 15, quad = lane >> 4;
  const int woc0 = lm, woc1 = (16 + lm) > 27 ? 27 : (16 + lm);
  const int choff = quad * 4;
  const int ho = ho0 + mw;
  const int obase = ((n * 28 + ho) * 28) * 256;
  const int ctbase = nh * 8 + nw * 4;

  vi4 zero = {0, 0, 0, 0};
  vi4 acc[2][4];
  vi4 B[3][4];
  vi4 a0c, a1c, a0n, a1n;

  // ---- identity branch first (2 K-steps), reusing acc ----
#pragma unroll
  for (int mt = 0; mt < 2; ++mt)
#pragma unroll
    for (int ct = 0; ct < 4; ++ct) acc[mt][ct] = zero;
  const vi4* wibase = Widm + ctbase * 64 + lane;
  {
    const int ro = (2 * mw + 1) * 58;
#pragma unroll
    for (int kc = 0; kc < 2; ++kc) {
      vi4 a0 = *(const vi4*)(lds + (ro + 2 * woc0 + 1) * 36 + kc * 16 + choff);
      vi4 a1 = *(const vi4*)(lds + (ro + 2 * woc1 + 1) * 36 + kc * 16 + choff);
#pragma unroll
      for (int ct = 0; ct < 4; ++ct) {
        vi4 b = wibase[kc * 1024 + ct * 64];
        acc[0][ct] = MFMA_I8(a0, b, acc[0][ct]);
        acc[1][ct] = MFMA_I8(a1, b, acc[1][ct]);
      }
    }
  }
  int am = 0;
#pragma unroll
  for (int ct = 0; ct < 4; ++ct) {
    const int co = (ctbase + ct) * 16 + lm;
#pragma unroll
    for (int mt = 0; mt < 2; ++mt)
#pragma unroll
      for (int r = 0; r < 4; ++r) {
        int wo = mt * 16 + quad * 4 + r;
        if (wo < 28) {
          int v = acc[mt][ct][r];
          IDI[obase + wo * 256 + co] = v;
          am = max(am, v < 0 ? -v : v);
        }
      }
  }
#pragma unroll
  for (int k = 32; k >= 1; k >>= 1) am = max(am, __shfl_xor(am, k));
  if (lane == 0) redA[wv] = am;

  // ---- main 3x3 conv, 18 K-steps, fully unrolled, distance-2 B prefetch ----
#pragma unroll
  for (int mt = 0; mt < 2; ++mt)
#pragma unroll
    for (int ct = 0; ct < 4; ++ct) acc[mt][ct] = zero;
  const vi4* wbase = W1m + ctbase * 64 + lane;
#pragma unroll
  for (int ct = 0; ct < 4; ++ct) B[0][ct] = wbase[ct * 64];
#pragma unroll
  for (int ct = 0; ct < 4; ++ct) B[1][ct] = wbase[1024 + ct * 64];
  {
    const int ro = (2 * mw) * 58;  // ks=0: kh=0,kw=0,kc=0
    a0c = *(const vi4*)(lds + (ro + 2 * woc0) * 36 + choff);
    a1c = *(const vi4*)(lds + (ro + 2 * woc1) * 36 + choff);
  }
#pragma unroll
  for (int ks = 0; ks < 18; ++ks) {
    const int cur = ks % 3;
    const int pf = (ks + 2) % 3;
    if (ks + 2 < 18) {
#pragma unroll
      for (int ct = 0; ct < 4; ++ct) B[pf][ct] = wbase[(ks + 2) * 1024 + ct * 64];
    }
    if (ks + 1 < 18) {
      const int ksn = ks + 1;
      const int khn = (ksn >= 6) + (ksn >= 12);
      const int t2 = ksn - khn * 6;
      const int kwn = t2 >> 1, kcn = t2 & 1;
      const int ro = (2 * mw + khn) * 58;
      a0n = *(const vi4*)(lds + (ro + 2 * woc0 + kwn) * 36 + kcn * 16 + choff);
      a1n = *(const vi4*)(lds + (ro + 2 * woc1 + kwn) * 36 + kcn * 16 + choff);
    }
#pragma unroll
    for (int ct = 0; ct < 4; ++ct) {
      acc[0][ct] = MFMA_I8(a0c, B[cur][ct], acc[0][ct]);
      acc[1][ct] = MFMA_I8(a1c, B[cur][ct], acc[1][ct]);
    }
    a0c = a0n;
    a1c = a1n;
  }

#pragma unroll
  for (int ct = 0; ct < 4; ++ct) {
    const int co = (ctbase + ct) * 16 + lm;
    int vmax = INT_MIN, vmin = INT_MAX;
#pragma unroll
    for (int mt = 0; mt < 2; ++mt)
#pragma unroll
      for (int r = 0; r < 4; ++r) {
        int wo = mt * 16 + quad * 4 + r;
        if (wo < 28) {
          int v = acc[mt][ct][r];
          H1[obase + wo * 256 + co] = v;
          vmax = max(vmax, v);
          vmin = min(vmin, v);
        }
      }
    vmax = max(vmax, __shfl_xor(vmax, 16));
    vmax = max(vmax, __shfl_xor(vmax, 32));
    vmin = min(vmin, __shfl_xor(vmin, 16));
    vmin = min(vmin, __shfl_xor(vmin, 32));
    if (lane < 16) {
      sMax[mw][nw * 64 + ct * 16 + lane] = vmax;
      sMin[mw][nw * 64 + ct * 16 + lane] = vmin;
    }
  }
  __syncthreads();
  if (tid < 128) {
    int row = n * 14 + hp;
    maxS[row * 256 + nh * 128 + tid] = max(sMax[0][tid], sMax[1][tid]);
    minS[row * 256 + nh * 128 + tid] = min(sMin[0][tid], sMin[1][tid]);
  }
  if (tid == 0) {
    int a = max(max(redA[0], redA[1]), max(redA[2], redA[3]));
    atomicMax(maxabs_id, a);
  }
}

// Reduce per-block extrema scratch (448 rows x 256 ch) into maxv/minv. 32 blocks.
__global__ __launch_bounds__(THREADS) void k_red(const int* __restrict__ maxS,
                                                 const int* __restrict__ minS,
                                                 int* __restrict__ maxv, int* __restrict__ minv) {
  int c = threadIdx.x, b = blockIdx.x;
  int vx = INT_MIN, vn = INT_MAX;
#pragma unroll
  for (int r = 0; r < 14; ++r) {
    int row = b * 14 + r;
    vx = max(vx, maxS[row * 256 + c]);
    vn = min(vn, minS[row * 256 + c]);
  }
  atomicMax(&maxv[c], vx);
  atomicMin(&minv[c], vn);
}

// Derive stage-1 scales.
__global__ __launch_bounds__(THREADS) void k_s1(int* __restrict__ IS, float* __restrict__ SC,
                                                const int* __restrict__ maxv,
                                                const int* __restrict__ minv,
                                                const float* __restrict__ wq1,
                                                const float* __restrict__ b1) {
  __shared__ int ri[THREADS];
  __shared__ float rf[THREADS];
  int c = threadIdx.x;
  int vmax = maxv[c], vmin = minv[c];
  int a1 = vmax < 0 ? -vmax : vmax;
  int a0 = vmin < 0 ? -vmin : vmin;
  ri[c] = max(a1, a0);
  __syncthreads();
  for (int s = THREADS / 2; s > 0; s >>= 1) {
    if (c < s) ri[c] = max(ri[c], ri[c + s]);
    __syncthreads();
  }
  int mh1 = ri[0];
  const unsigned* ISu = (const unsigned*)IS;
  float sx = sc_from_bits(ISu[0]);
  float sw1 = sc_from_bits(ISu[1]);
  float sxw = sx * sw1;
  float s_h1 = fmaxf(sxw * (float)mh1 / 127.0f, 1e-8f);
  float wq = wq1[c], bbc = b1[c];
  float q1 = clamp8f(rintf((float)vmax * sxw / s_h1));
  float q0 = clamp8f(rintf((float)vmin * sxw / s_h1));
  float hv1 = q1 * s_h1, hv0 = q0 * s_h1;
  float y1 = fmaxf(hv1 * wq + bbc, 0.0f);
  float y0 = fmaxf(hv0 * wq + bbc, 0.0f);
  rf[c] = fmaxf(y1, y0);
  __syncthreads();
  for (int s = THREADS / 2; s > 0; s >>= 1) {
    if (c < s) rf[c] = fmaxf(rf[c], rf[c + s]);
    __syncthreads();
  }
  if (c == 0) {
    IS[4] = mh1;
    SC[7] = rf[0];
    SC[8] = s_h1;
    SC[9] = fmaxf(rf[0] / 127.0f, 1e-8f);
    float swid = sc_from_bits(ISu[3]);
    SC[10] = fmaxf(sx * swid * (float)IS[5] / 127.0f, 1e-8f);
  }
}

// quant(h1) -> bn1 -> relu -> quant => A2 int8 (NHWC)
__device__ __forceinline__ signed char qact(int v, float sxw, float s_h1, float s_y2, float wq,
                                            float bb) {
  float hf = (float)v * sxw;
  float q = clamp8f(rintf(hf / s_h1));
  float hv = q * s_h1;
  float y = fmaxf(hv * wq + bb, 0.0f);
  float a = fminf(fmaxf(rintf(y / s_y2), -128.0f), 127.0f);
  return (signed char)(int)a;
}

__global__ __launch_bounds__(THREADS) void k_qh1(const int4* __restrict__ H1,
                                                 char4* __restrict__ A2,
                                                 const float* __restrict__ SC,
                                                 const float* __restrict__ wq1,
                                                 const float* __restrict__ b1) {
  int t = blockIdx.x * THREADS + threadIdx.x;  // < 1,605,632
  const unsigned* ISu = (const unsigned*)SC;
  float sx = sc_from_bits(ISu[0]);
  float sw1 = sc_from_bits(ISu[1]);
  float sxw = sx * sw1;
  float s_h1 = SC[8];
  float s_y2 = SC[9];
  int4 v = H1[t];
  int c0 = (t * 4) & 255;
  char4 r;
  r.x = qact(v.x, sxw, s_h1, s_y2, wq1[c0], b1[c0]);
  r.y = qact(v.y, sxw, s_h1, s_y2, wq1[c0 + 1], b1[c0 + 1]);
  r.z = qact(v.z, sxw, s_h1, s_y2, wq1[c0 + 2], b1[c0 + 2]);
  r.w = qact(v.w, sxw, s_h1, s_y2, wq1[c0 + 3], b1[c0 + 3]);
  A2[t] = r;
}

// conv2 3x3 s1 p1 (Cin=256). 896 blocks (n, ho-pair, N-half). Fully unrolled, dist-2 prefetch.
__global__ __launch_bounds__(THREADS, 2) void k_conv2(const int* __restrict__ A2,
                                                      const vi4* __restrict__ W2m,
                                                      int* __restrict__ H2,
                                                      int* __restrict__ maxabs_h2) {
  __shared__ __align__(16) int lds[4 * 30 * 68];
  __shared__ int redA[4];
  const int tid = threadIdx.x;
  const int bx = blockIdx.x;
  const int n = bx / 28, rr = bx % 28;
  const int hp = rr >> 1, nh = rr & 1;
  const int ho0 = hp * 2;

  for (int r = 0; r < 4; ++r) {
    int h = ho0 - 1 + r;
    int* dst = lds + r * 30 * 68;
    if (h >= 0 && h < 28) {
      const int* src = A2 + (n * 28 + h) * 28 * 64;
      for (int i = tid; i < 28 * 64; i += THREADS) {
        int col = i >> 6, c = i & 63;
        dst[(col + 1) * 68 + c] = src[i];
      }
      if (tid < 64) dst[tid] = 0;
      else if (tid >= 128 && tid < 192) dst[29 * 68 + (tid - 128)] = 0;
    } else {
      for (int i = tid; i < 30 * 68; i += THREADS) dst[i] = 0;
    }
  }
  __syncthreads();

  const int lane = tid & 63, wv = tid >> 6;
  const int mw = wv & 1, nw = wv >> 1;
  const int lm = lane & 15, quad = lane >> 4;
  const int woc0 = lm, woc1 = (16 + lm) > 27 ? 27 : (16 + lm);
  const int choff = quad * 4;
  const int ho = ho0 + mw;
  const int ctbase = nh * 8 + nw * 4;

  vi4 zero = {0, 0, 0, 0};
  vi4 acc[2][4];
  vi4 B[3][4];
  vi4 a0c, a1c, a0n, a1n;
#pragma unroll
  for (int mt = 0; mt < 2; ++mt)
#pragma unroll
    for (int ct = 0; ct < 4; ++ct) acc[mt][ct] = zero;

  const vi4* wbase = W2m + ctbase * 64 + lane;
#pragma unroll
  for (int ct = 0; ct < 4; ++ct) B[0][ct] = wbase[ct * 64];
#pragma unroll
  for (int ct = 0; ct < 4; ++ct) B[1][ct] = wbase[1024 + ct * 64];
  {
    const int ro = mw * 30;  // ks=0
    a0c = *(const vi4*)(lds + (ro + woc0) * 68 + choff);
    a1c = *(const vi4*)(lds + (ro + woc1) * 68 + choff);
  }
#pragma unroll
  for (int ks = 0; ks < 36; ++ks) {
    const int cur = ks % 3;
    const int pf = (ks + 2) % 3;
    if (ks + 2 < 36) {
#pragma unroll
      for (int ct = 0; ct < 4; ++ct) B[pf][ct] = wbase[(ks + 2) * 1024 + ct * 64];
    }
    if (ks + 1 < 36) {
      const int ksn = ks + 1;
      const int khn = (ksn >= 12) + (ksn >= 24);
      const int t2 = ksn - khn * 12;
      const int kwn = t2 >> 2, kcn = t2 & 3;
      const int ro = (mw + khn) * 30;
      a0n = *(const vi4*)(lds + (ro + woc0 + kwn) * 68 + kcn * 16 + choff);
      a1n = *(const vi4*)(lds + (ro + woc1 + kwn) * 68 + kcn * 16 + choff);
    }
#pragma unroll
    for (int ct = 0; ct < 4; ++ct) {
      acc[0][ct] = MFMA_I8(a0c, B[cur][ct], acc[0][ct]);
      acc[1][ct] = MFMA_I8(a1c, B[cur][ct], acc[1][ct]);
    }
    a0c = a0n;
    a1c = a1n;
  }

  const int obase = ((n * 28 + ho) * 28) * 256;
  int am = 0;
#pragma unroll
  for (int ct = 0; ct < 4; ++ct) {
    const int co = (ctbase + ct) * 16 + lm;
#pragma unroll
    for (int mt = 0; mt < 2; ++mt)
#pragma unroll
      for (int r = 0; r < 4; ++r) {
        int wo = mt * 16 + quad * 4 + r;
        if (wo < 28) {
          int v = acc[mt][ct][r];
          H2[obase + wo * 256 + co] = v;
          am = max(am, v < 0 ? -v : v);
        }
      }
  }
#pragma unroll
  for (int k = 32; k >= 1; k >>= 1) am = max(am, __shfl_xor(am, k));
  if (lane == 0) redA[wv] = am;
  __syncthreads();
  if (tid == 0) {
    int a = max(max(redA[0], redA[1]), max(redA[2], redA[3]));
    atomicMax(maxabs_h2, a);
  }
}

// ---- residual sum math shared by k_absmax2 / k_out ----
struct SumParams {
  float sxw2, s_h2, sxwid, s_idq;
};
__device__ __forceinline__ float sum_val(int v2, int vi, const SumParams& P, float wq2c, float b2c,
                                         float wqidc, float bidc) {
  float q2 = clamp8f(rintf((float)v2 * P.sxw2 / P.s_h2));
  float z = (q2 * P.s_h2) * wq2c + b2c;
  float qi = clamp8f(rintf((float)vi * P.sxwid / P.s_idq));
  float zi = (qi * P.s_idq) * wqidc + bidc;
  return z + zi;
}
__device__ __forceinline__ SumParams make_params(const float* SC, const int* IS) {
  const unsigned* ISu = (const unsigned*)IS;
  SumParams P;
  float sx = sc_from_bits(ISu[0]);
  float sw2 = sc_from_bits(ISu[2]);
  float swid = sc_from_bits(ISu[3]);
  float s_y2 = SC[9];
  P.s_idq = SC[10];
  P.sxw2 = s_y2 * sw2;
  P.s_h2 = fmaxf(P.sxw2 * (float)IS[6] / 127.0f, 1e-8f);
  P.sxwid = sx * swid;
  return P;
}

// Pass 1: global absmax of residual sum. Grid-stride, 1 atomic/block.
__global__ __launch_bounds__(THREADS) void k_absmax2(const int4* __restrict__ H2,
                                                     const int4* __restrict__ IDI,
                                                     const float* __restrict__ SC,
                                                     const int* __restrict__ IS,
                                                     const float* __restrict__ wq2,
                                                     const float* __restrict__ b2,
                                                     const float* __restrict__ wqid,
                                                     const float* __restrict__ bidp,
                                                     unsigned* __restrict__ slot) {
  __shared__ float pw2[256], pb2[256], pwi[256], pbi[256];
  int tid = threadIdx.x;
  pw2[tid] = wq2[tid];
  pb2[tid] = b2[tid];
  pwi[tid] = wqid[tid];
  pbi[tid] = bidp[tid];
  __syncthreads();
  SumParams P = make_params(SC, IS);
  const int n4 = 1605632;
  const int stride = gridDim.x * THREADS;
  float m = 0.0f;
  for (int i = blockIdx.x * THREADS + tid; i < n4; i += stride) {
    int4 v2 = H2[i];
    int4 vi = IDI[i];
    int c0 = (i * 4) & 255;
    m = fmaxf(m, fabsf(sum_val(v2.x, vi.x, P, pw2[c0], pb2[c0], pwi[c0], pbi[c0])));
    m = fmaxf(m, fabsf(sum_val(v2.y, vi.y, P, pw2[c0 + 1], pb2[c0 + 1], pwi[c0 + 1], pbi[c0 + 1])));
    m = fmaxf(m, fabsf(sum_val(v2.z, vi.z, P, pw2[c0 + 2], pb2[c0 + 2], pwi[c0 + 2], pbi[c0 + 2])));
    m = fmaxf(m, fabsf(sum_val(v2.w, vi.w, P, pw2[c0 + 3], pb2[c0 + 3], pwi[c0 + 3], pbi[c0 + 3])));
  }
#pragma unroll
  for (int k = 32; k >= 1; k >>= 1) m = fmaxf(m, __shfl_xor(m, k));
  __shared__ float wred[4];
  if ((tid & 63) == 0) wred[tid >> 6] = m;
  __syncthreads();
  if (tid == 0) {
    m = fmaxf(fmaxf(wred[0], wred[1]), fmaxf(wred[2], wred[3]));
    atomicMax(slot, __float_as_uint(m));
  }
}

// Pass 2: recompute sum, final requant + relu, write NCHW via padded LDS tile transpose.
__global__ __launch_bounds__(THREADS) void k_out(const int* __restrict__ H2,
                                                 const int* __restrict__ IDI,
                                                 const float* __restrict__ SC,
                                                 const int* __restrict__ IS,
                                                 const float* __restrict__ wq2,
                                                 const float* __restrict__ b2,
                                                 const float* __restrict__ wqid,
                                                 const float* __restrict__ bidp,
                                                 float* __restrict__ out) {
  __shared__ float tile[64 * 57];
  __shared__ float pw2[64], pb2[64], pwi[64], pbi[64];
  int tid = threadIdx.x;
  int b = blockIdx.x;
  int ct = b & 3;
  int rt = (b >> 2) % 14;
  int n = b / 56;
  int c0 = ct * 64;
  int r0 = rt * 56;
  if (tid < 64) {
    pw2[tid] = wq2[c0 + tid];
    pb2[tid] = b2[c0 + tid];
    pwi[tid] = wqid[c0 + tid];
    pbi[tid] = bidp[c0 + tid];
  }
  __syncthreads();
  SumParams P = make_params(SC, IS);
  float out_s = fmaxf(__uint_as_float(((const unsigned*)IS)[11]) / 127.0f, 1e-8f);

  const int base = (n * 784 + r0) * 256 + c0;
#pragma unroll
  for (int k = 0; k < 14; ++k) {
    int idx = tid + k * 256;  // < 3584
    int rl = idx >> 6;
    int cl = idx & 63;
    int e = base + rl * 256 + cl;
    float sv = sum_val(H2[e], IDI[e], P, pw2[cl], pb2[cl], pwi[cl], pbi[cl]);
    float q = clamp8f(rintf(sv / out_s));
    tile[cl * 57 + rl] = q > 0.0f ? q * out_s : 0.0f;
  }
  __syncthreads();
  float* ob = out + n * 200704 + c0 * 784 + r0;
#pragma unroll
  for (int k = 0; k < 14; ++k) {
    int idx = tid + k * 256;
    int cl = idx / 56;
    int rl = idx % 56;
    ob[cl * 784 + rl] = tile[cl * 57 + rl];
  }
  if (b == 0 && tid == 0) out[6422528] = out_s;
}

extern "C" void kernel_launch(void* const* d_in, const int* in_sizes, int n_in, void* d_out,
                              int out_size, void* d_ws, size_t ws_size, hipStream_t stream) {
  (void)in_sizes; (void)n_in; (void)out_size; (void)ws_size;
  const float* x = (const float*)d_in[0];
  const float* w1 = (const float*)d_in[1];
  const float* w2 = (const float*)d_in[2];
  const float* wid = (const float*)d_in[3];
  const float* bn1g = (const float*)d_in[4];
  const float* bn1b = (const float*)d_in[5];
  const float* bn1m = (const float*)d_in[6];
  const float* bn1v = (const float*)d_in[7];
  const float* bn2g = (const float*)d_in[8];
  const float* bn2b = (const float*)d_in[9];
  const float* bn2m = (const float*)d_in[10];
  const float* bn2v = (const float*)d_in[11];
  const float* idg = (const float*)d_in[12];
  const float* idb = (const float*)d_in[13];
  const float* idm = (const float*)d_in[14];
  const float* idv = (const float*)d_in[15];

  char* ws = (char*)d_ws;
  float* SC = (float*)ws;
  int* IS = (int*)ws;
  unsigned* ISu = (unsigned*)ws;
  int* maxv = (int*)(ws + 1024);
  int* minv = (int*)(ws + 2048);
  float* wq1 = (float*)(ws + 3072);
  float* b1 = (float*)(ws + 4096);
  float* wq2 = (float*)(ws + 5120);
  float* b2 = (float*)(ws + 6144);
  float* wqid = (float*)(ws + 7168);
  float* bid = (float*)(ws + 8192);
  char* X8 = ws + 16384;                 // NHWC int8; A2 overlays after conv1
  char* A2 = X8;
  char* W1m = X8 + 12845056;
  char* W2m = W1m + 294912;
  char* Widm = W2m + 589824;
  int* H1 = (int*)(Widm + 32768);
  int* H2 = H1;
  int* IDI = (int*)((char*)H1 + 25690112);
  float* out = (float*)d_out;
  int* maxS = (int*)d_out;  // extrema scratch in d_out (dead until k_out)
  int* minS = maxS + 448 * 256;

  k_boot<<<4, THREADS, 0, stream>>>(IS, maxv, minv, bn1g, bn1b, bn1m, bn1v, wq1, b1, bn2g, bn2b,
                                    bn2m, bn2v, wq2, b2, idg, idb, idm, idv, wqid, bid);
  k_amax<<<512, THREADS, 0, stream>>>((const float4*)x, 3211264, ISu + 0);
  k_amaxw<<<208, THREADS, 0, stream>>>((const float4*)w1, (const float4*)w2, (const float4*)wid,
                                       ISu);
  k_qx<<<1792, THREADS, 0, stream>>>(x, (int*)X8, ISu);
  k_qw1m<<<72, THREADS, 0, stream>>>(w1, (vi4*)W1m, ISu);
  k_qw2m<<<144, THREADS, 0, stream>>>(w2, (vi4*)W2m, ISu);
  k_qwidm<<<8, THREADS, 0, stream>>>(wid, (vi4*)Widm, ISu);
  k_conv1<<<896, THREADS, 0, stream>>>((const int*)X8, (const vi4*)W1m, (const vi4*)Widm, H1, IDI,
                                       maxS, minS, IS + 5);
  k_red<<<32, THREADS, 0, stream>>>(maxS, minS, maxv, minv);
  k_s1<<<1, THREADS, 0, stream>>>(IS, SC, maxv, minv, wq1, b1);
  k_qh1<<<6272, THREADS, 0, stream>>>((const int4*)H1, (char4*)A2, SC, wq1, b1);
  k_conv2<<<896, THREADS, 0, stream>>>((const int*)A2, (const vi4*)W2m, H2, IS + 6);
  k_absmax2<<<1024, THREADS, 0, stream>>>((const int4*)H2, (const int4*)IDI, SC, IS, wq2, b2, wqid,
                                          bid, ISu + 11);
  k_out<<<1792, THREADS, 0, stream>>>(H2, IDI, SC, IS, wq2, b2, wqid, bid, out);
}

// Round 8
// 271.229 us; speedup vs baseline: 3.3615x; 1.0564x over previous
//
#include <hip/hip_runtime.h>
#include <limits.h>

#define THREADS 256

typedef int vi4 __attribute__((ext_vector_type(4)));

__device__ __forceinline__ float clamp8f(float q) { return fminf(fmaxf(q, -128.0f), 127.0f); }
__device__ __forceinline__ float sc_from_bits(unsigned b) {
  return fmaxf(__uint_as_float(b) / 127.0f, 1e-8f);
}
__device__ __forceinline__ signed char q8(float v, float s) {
  return (signed char)(int)clamp8f(rintf(v / s));
}

// Scalar slots: [0] amax_x [1] amax_w1 [2] amax_w2 [3] amax_wid
// [4] maxabs_h1 [5] maxabs_id [6] maxabs_h2 [7] max_y2 [8] s_h1 [9] s_y2 [10] s_idq [11] amax_sum

__device__ __forceinline__ void amax_body(const float4* __restrict__ p, int n4, int bid,
                                          int nblocks, unsigned* __restrict__ slot) {
  const int tid = threadIdx.x;
  const int stride = nblocks * THREADS;
  float m = 0.0f;
  int i = bid * THREADS + tid;
  for (; i + 3 * stride < n4; i += 4 * stride) {
    float4 v0 = p[i];
    float4 v1 = p[i + stride];
    float4 v2 = p[i + 2 * stride];
    float4 v3 = p[i + 3 * stride];
    float m0 = fmaxf(fmaxf(fabsf(v0.x), fabsf(v0.y)), fmaxf(fabsf(v0.z), fabsf(v0.w)));
    float m1 = fmaxf(fmaxf(fabsf(v1.x), fabsf(v1.y)), fmaxf(fabsf(v1.z), fabsf(v1.w)));
    float m2 = fmaxf(fmaxf(fabsf(v2.x), fabsf(v2.y)), fmaxf(fabsf(v2.z), fabsf(v2.w)));
    float m3 = fmaxf(fmaxf(fabsf(v3.x), fabsf(v3.y)), fmaxf(fabsf(v3.z), fabsf(v3.w)));
    m = fmaxf(m, fmaxf(fmaxf(m0, m1), fmaxf(m2, m3)));
  }
  for (; i < n4; i += stride) {
    float4 v = p[i];
    m = fmaxf(m, fmaxf(fmaxf(fabsf(v.x), fabsf(v.y)), fmaxf(fabsf(v.z), fabsf(v.w))));
  }
#pragma unroll
  for (int k = 32; k >= 1; k >>= 1) m = fmaxf(m, __shfl_xor(m, k));
  __shared__ float wred[4];
  if ((tid & 63) == 0) wred[tid >> 6] = m;
  __syncthreads();
  if (tid == 0) {
    m = fmaxf(fmaxf(wred[0], wred[1]), fmaxf(wred[2], wred[3]));
    atomicMax(slot, __float_as_uint(m));
  }
}

// Merged: blocks 0-2 bnfold(bn1,bn2,id); 3..66 w1 amax; 67..194 w2; 195..210 wid; 211..722 x.
__global__ __launch_bounds__(THREADS) void k_pre(
    int* IS, const float* g1, const float* be1, const float* m1, const float* v1, float* wq1,
    float* b1, const float* g2, const float* be2, const float* m2, const float* v2, float* wq2,
    float* b2, const float* gi, const float* bei, const float* mi, const float* vvi, float* wqi,
    float* bi, const float4* w1, const float4* w2, const float4* wid, const float4* x) {
  unsigned* ISu = (unsigned*)IS;
  int b = blockIdx.x;
  int c = threadIdx.x;
  if (b < 3) {
    const float *gamma, *beta, *mean, *var;
    float *wq, *bb;
    if (b == 0) { gamma = g1; beta = be1; mean = m1; var = v1; wq = wq1; bb = b1; }
    else if (b == 1) { gamma = g2; beta = be2; mean = m2; var = v2; wq = wq2; bb = b2; }
    else { gamma = gi; beta = bei; mean = mi; var = vvi; wq = wqi; bb = bi; }
    __shared__ float red[THREADS];
    float ws = gamma[c] * (1.0f / sqrtf(var[c] + 1e-5f));
    red[c] = fabsf(ws);
    __syncthreads();
    for (int s = THREADS / 2; s > 0; s >>= 1) {
      if (c < s) red[c] = fmaxf(red[c], red[c + s]);
      __syncthreads();
    }
    float sws = fmaxf(red[0] / 127.0f, 1e-8f);
    float q = clamp8f(rintf(ws / sws)) * sws;
    wq[c] = q;
    bb[c] = beta[c] - mean[c] * q;
    return;
  }
  b -= 3;
  if (b < 64) { amax_body(w1, 73728, b, 64, ISu + 1); return; }
  b -= 64;
  if (b < 128) { amax_body(w2, 147456, b, 128, ISu + 2); return; }
  b -= 128;
  if (b < 16) { amax_body(wid, 8192, b, 16, ISu + 3); return; }
  b -= 16;
  amax_body(x, 3211264, b, 512, ISu + 0);
}

// Merged quantize: blocks [0,1792) qx; [1792,1864) qw1; [1864,2008) qw2; [2008,2016) qwid.
__global__ __launch_bounds__(THREADS) void k_quant(const float* __restrict__ x,
                                                   int* __restrict__ X8,
                                                   const float* __restrict__ w1f,
                                                   vi4* __restrict__ W1m,
                                                   const float* __restrict__ w2f,
                                                   vi4* __restrict__ W2m,
                                                   const float* __restrict__ widf,
                                                   vi4* __restrict__ Widm,
                                                   const unsigned* __restrict__ ISu) {
  __shared__ signed char tile[56 * 132];
  int b = blockIdx.x;
  int t = threadIdx.x;
  if (b < 1792) {
    // qx: NCHW f32 -> NHWC int8 via LDS transpose. block = (n,h).
    float s = sc_from_bits(ISu[0]);
    int h = b % 56, n = b / 56;
    const float* xp = x + ((n * 128) * 56 + h) * 56;
#pragma unroll
    for (int k = 0; k < 28; ++k) {
      int i = t + k * 256;  // < 7168
      int w = i % 56, c = i / 56;
      tile[w * 132 + c] = q8(xp[c * 3136 + w], s);
    }
    __syncthreads();
    int* op = X8 + (n * 56 + h) * 56 * 32;
#pragma unroll
    for (int k = 0; k < 7; ++k) {
      int i = t + k * 256;  // < 1792
      int w = i >> 5, c4 = (i & 31) * 4;
      const signed char* tp = tile + w * 132 + c4;
      op[i] = (int)(unsigned char)tp[0] | ((int)(unsigned char)tp[1] << 8) |
              ((int)(unsigned char)tp[2] << 16) | ((int)(unsigned char)tp[3] << 24);
    }
    return;
  }
  if (b < 1864) {
    int tt = (b - 1792) * THREADS + t;  // < 18432
    float s = sc_from_bits(ISu[1]);
    int lane = tt & 63;
    int cotile = (tt >> 6) & 15;
    int ks = tt >> 10;  // 0..17
    int tap = ks >> 1, kc = ks & 1;
    int kh = tap / 3, kw = tap % 3;
    int co = cotile * 16 + (lane & 15);
    int ci0 = kc * 64 + (lane >> 4) * 16;
    const float* src = w1f + (co * 128 + ci0) * 9 + kh * 3 + kw;
    int r[4];
#pragma unroll
    for (int q = 0; q < 4; ++q) {
      unsigned b0 = (unsigned char)q8(src[(q * 4 + 0) * 9], s);
      unsigned b1 = (unsigned char)q8(src[(q * 4 + 1) * 9], s);
      unsigned b2 = (unsigned char)q8(src[(q * 4 + 2) * 9], s);
      unsigned b3 = (unsigned char)q8(src[(q * 4 + 3) * 9], s);
      r[q] = (int)(b0 | (b1 << 8) | (b2 << 16) | (b3 << 24));
    }
    vi4 v = {r[0], r[1], r[2], r[3]};
    W1m[tt] = v;
    return;
  }
  if (b < 2008) {
    int tt = (b - 1864) * THREADS + t;  // < 36864
    float s = sc_from_bits(ISu[2]);
    int lane = tt & 63;
    int cotile = (tt >> 6) & 15;
    int ks = tt >> 10;  // 0..35
    int tap = ks >> 2, kc = ks & 3;
    int kh = tap / 3, kw = tap % 3;
    int co = cotile * 16 + (lane & 15);
    int ci0 = kc * 64 + (lane >> 4) * 16;
    const float* src = w2f + (co * 256 + ci0) * 9 + kh * 3 + kw;
    int r[4];
#pragma unroll
    for (int q = 0; q < 4; ++q) {
      unsigned b0 = (unsigned char)q8(src[(q * 4 + 0) * 9], s);
      unsigned b1 = (unsigned char)q8(src[(q * 4 + 1) * 9], s);
      unsigned b2 = (unsigned char)q8(src[(q * 4 + 2) * 9], s);
      unsigned b3 = (unsigned char)q8(src[(q * 4 + 3) * 9], s);
      r[q] = (int)(b0 | (b1 << 8) | (b2 << 16) | (b3 << 24));
    }
    vi4 v = {r[0], r[1], r[2], r[3]};
    W2m[tt] = v;
    return;
  }
  {
    int tt = (b - 2008) * THREADS + t;  // < 2048
    float s = sc_from_bits(ISu[3]);
    int lane = tt & 63;
    int cotile = (tt >> 6) & 15;
    int ks = tt >> 10;  // 0..1
    int co = cotile * 16 + (lane & 15);
    int ci0 = ks * 64 + (lane >> 4) * 16;
    const float* src = widf + co * 128 + ci0;
    int r[4];
#pragma unroll
    for (int q = 0; q < 4; ++q) {
      unsigned b0 = (unsigned char)q8(src[q * 4 + 0], s);
      unsigned b1 = (unsigned char)q8(src[q * 4 + 1], s);
      unsigned b2 = (unsigned char)q8(src[q * 4 + 2], s);
      unsigned b3 = (unsigned char)q8(src[q * 4 + 3], s);
      r[q] = (int)(b0 | (b1 << 8) | (b2 << 16) | (b3 << 24));
    }
    vi4 v = {r[0], r[1], r[2], r[3]};
    Widm[tt] = v;
  }
}

#define MFMA_I8(a, b, c) __builtin_amdgcn_mfma_i32_16x16x64_i8(a, b, c, 0, 0, 0)

// conv1 3x3 s2 p1 (Cin=128) + identity 1x1 s2, MFMA implicit GEMM.
// 896 blocks (n, ho-pair, N-half). Round-6 K-loop (dist-1 prefetch, unroll 1) + int4 staging.
__global__ __launch_bounds__(THREADS, 2) void k_conv1(const int* __restrict__ X8,
                                                      const vi4* __restrict__ W1m,
                                                      const vi4* __restrict__ Widm,
                                                      int* __restrict__ H1, int* __restrict__ IDI,
                                                      int* __restrict__ maxS,
                                                      int* __restrict__ minS,
                                                      int* __restrict__ maxabs_id) {
  __shared__ __align__(16) int lds[5 * 58 * 36];
  __shared__ int sMax[2][128], sMin[2][128], redA[4];
  const int tid = threadIdx.x;
  const int bx = blockIdx.x;
  const int n = bx / 28, rr = bx % 28;
  const int hp = rr >> 1, nh = rr & 1;
  const int ho0 = hp * 2;
  vi4 zero = {0, 0, 0, 0};

  for (int r = 0; r < 5; ++r) {
    int h = 2 * ho0 - 1 + r;
    int* dst = lds + r * 58 * 36;
    if (h >= 0 && h < 56) {
      const vi4* src = (const vi4*)(X8 + (n * 56 + h) * 56 * 32);
      for (int i4 = tid; i4 < 448; i4 += THREADS) {
        int col = i4 >> 3, c = (i4 & 7) * 4;
        *(vi4*)(dst + (col + 1) * 36 + c) = src[i4];
      }
      if (tid < 32) dst[tid] = 0;
      else if (tid >= 128 && tid < 160) dst[57 * 36 + (tid - 128)] = 0;
    } else {
      for (int i4 = tid; i4 < 522; i4 += THREADS) ((vi4*)dst)[i4] = zero;
    }
  }
  __syncthreads();

  const int lane = tid & 63, wv = tid >> 6;
  const int mw = wv & 1, nw = wv >> 1;
  const int lm = lane & 15, quad = lane >> 4;
  const int woc0 = lm, woc1 = (16 + lm) > 27 ? 27 : (16 + lm);
  const int choff = quad * 4;
  const int ho = ho0 + mw;
  const int obase = ((n * 28 + ho) * 28) * 256;
  const int ctbase = nh * 8 + nw * 4;

  vi4 acc[2][4];
  vi4 bcur[4], bnext[4];
  vi4 a0c, a1c, a0n, a1n;

  // ---- identity branch first (2 K-steps), reusing acc ----
#pragma unroll
  for (int mt = 0; mt < 2; ++mt)
#pragma unroll
    for (int ct = 0; ct < 4; ++ct) acc[mt][ct] = zero;
  const vi4* wibase = Widm + ctbase * 64 + lane;
  {
    const int ro = (2 * mw + 1) * 58;
#pragma unroll
    for (int kc = 0; kc < 2; ++kc) {
      vi4 a0 = *(const vi4*)(lds + (ro + 2 * woc0 + 1) * 36 + kc * 16 + choff);
      vi4 a1 = *(const vi4*)(lds + (ro + 2 * woc1 + 1) * 36 + kc * 16 + choff);
#pragma unroll
      for (int ct = 0; ct < 4; ++ct) {
        vi4 b = wibase[kc * 1024 + ct * 64];
        acc[0][ct] = MFMA_I8(a0, b, acc[0][ct]);
        acc[1][ct] = MFMA_I8(a1, b, acc[1][ct]);
      }
    }
  }
  int am = 0;
#pragma unroll
  for (int ct = 0; ct < 4; ++ct) {
    const int co = (ctbase + ct) * 16 + lm;
#pragma unroll
    for (int mt = 0; mt < 2; ++mt)
#pragma unroll
      for (int r = 0; r < 4; ++r) {
        int wo = mt * 16 + quad * 4 + r;
        if (wo < 28) {
          int v = acc[mt][ct][r];
          IDI[obase + wo * 256 + co] = v;
          am = max(am, v < 0 ? -v : v);
        }
      }
  }
#pragma unroll
  for (int k = 32; k >= 1; k >>= 1) am = max(am, __shfl_xor(am, k));
  if (lane == 0) redA[wv] = am;

  // ---- main 3x3 conv, 18 K-steps, software-pipelined (dist-1) ----
#pragma unroll
  for (int mt = 0; mt < 2; ++mt)
#pragma unroll
    for (int ct = 0; ct < 4; ++ct) acc[mt][ct] = zero;
  const vi4* wbase = W1m + ctbase * 64 + lane;
#pragma unroll
  for (int ct = 0; ct < 4; ++ct) bcur[ct] = wbase[ct * 64];
  {
    const int ro = (2 * mw) * 58;  // kh=0
    a0c = *(const vi4*)(lds + (ro + 2 * woc0) * 36 + choff);
    a1c = *(const vi4*)(lds + (ro + 2 * woc1) * 36 + choff);
  }
#pragma unroll 1
  for (int ks = 0; ks < 18; ++ks) {
    int ksn = ks + 1;
    if (ksn < 18) {
      int khn = (ksn >= 6) + (ksn >= 12);
      int t2 = ksn - khn * 6;
      int kwn = t2 >> 1, kcn = t2 & 1;
#pragma unroll
      for (int ct = 0; ct < 4; ++ct) bnext[ct] = wbase[ksn * 1024 + ct * 64];
      int ro = (2 * mw + khn) * 58;
      a0n = *(const vi4*)(lds + (ro + 2 * woc0 + kwn) * 36 + kcn * 16 + choff);
      a1n = *(const vi4*)(lds + (ro + 2 * woc1 + kwn) * 36 + kcn * 16 + choff);
    }
#pragma unroll
    for (int ct = 0; ct < 4; ++ct) {
      acc[0][ct] = MFMA_I8(a0c, bcur[ct], acc[0][ct]);
      acc[1][ct] = MFMA_I8(a1c, bcur[ct], acc[1][ct]);
    }
    a0c = a0n;
    a1c = a1n;
#pragma unroll
    for (int ct = 0; ct < 4; ++ct) bcur[ct] = bnext[ct];
  }

#pragma unroll
  for (int ct = 0; ct < 4; ++ct) {
    const int co = (ctbase + ct) * 16 + lm;
    int vmax = INT_MIN, vmin = INT_MAX;
#pragma unroll
    for (int mt = 0; mt < 2; ++mt)
#pragma unroll
      for (int r = 0; r < 4; ++r) {
        int wo = mt * 16 + quad * 4 + r;
        if (wo < 28) {
          int v = acc[mt][ct][r];
          H1[obase + wo * 256 + co] = v;
          vmax = max(vmax, v);
          vmin = min(vmin, v);
        }
      }
    vmax = max(vmax, __shfl_xor(vmax, 16));
    vmax = max(vmax, __shfl_xor(vmax, 32));
    vmin = min(vmin, __shfl_xor(vmin, 16));
    vmin = min(vmin, __shfl_xor(vmin, 32));
    if (lane < 16) {
      sMax[mw][nw * 64 + ct * 16 + lane] = vmax;
      sMin[mw][nw * 64 + ct * 16 + lane] = vmin;
    }
  }
  __syncthreads();
  if (tid < 128) {
    int row = n * 14 + hp;
    maxS[row * 256 + nh * 128 + tid] = max(sMax[0][tid], sMax[1][tid]);
    minS[row * 256 + nh * 128 + tid] = min(sMin[0][tid], sMin[1][tid]);
  }
  if (tid == 0) {
    int a = max(max(redA[0], redA[1]), max(redA[2], redA[3]));
    atomicMax(maxabs_id, a);
  }
}

// Merged k_red + k_s1: ONE block. Scan 448x256 extrema scratch, then derive stage-1 scales.
__global__ __launch_bounds__(THREADS) void k_rs1(int* __restrict__ IS, float* __restrict__ SC,
                                                 const int* __restrict__ maxS,
                                                 const int* __restrict__ minS,
                                                 const float* __restrict__ wq1,
                                                 const float* __restrict__ b1) {
  __shared__ int ri[THREADS];
  __shared__ float rf[THREADS];
  int c = threadIdx.x;
  int vmax = INT_MIN, vmin = INT_MAX;
#pragma unroll 4
  for (int r = 0; r < 448; ++r) {
    vmax = max(vmax, maxS[r * 256 + c]);
    vmin = min(vmin, minS[r * 256 + c]);
  }
  int a1 = vmax < 0 ? -vmax : vmax;
  int a0 = vmin < 0 ? -vmin : vmin;
  ri[c] = max(a1, a0);
  __syncthreads();
  for (int s = THREADS / 2; s > 0; s >>= 1) {
    if (c < s) ri[c] = max(ri[c], ri[c + s]);
    __syncthreads();
  }
  int mh1 = ri[0];
  const unsigned* ISu = (const unsigned*)IS;
  float sx = sc_from_bits(ISu[0]);
  float sw1 = sc_from_bits(ISu[1]);
  float sxw = sx * sw1;
  float s_h1 = fmaxf(sxw * (float)mh1 / 127.0f, 1e-8f);
  float wq = wq1[c], bbc = b1[c];
  float q1 = clamp8f(rintf((float)vmax * sxw / s_h1));
  float q0 = clamp8f(rintf((float)vmin * sxw / s_h1));
  float hv1 = q1 * s_h1, hv0 = q0 * s_h1;
  float y1 = fmaxf(hv1 * wq + bbc, 0.0f);
  float y0 = fmaxf(hv0 * wq + bbc, 0.0f);
  rf[c] = fmaxf(y1, y0);
  __syncthreads();
  for (int s = THREADS / 2; s > 0; s >>= 1) {
    if (c < s) rf[c] = fmaxf(rf[c], rf[c + s]);
    __syncthreads();
  }
  if (c == 0) {
    IS[4] = mh1;
    SC[7] = rf[0];
    SC[8] = s_h1;
    SC[9] = fmaxf(rf[0] / 127.0f, 1e-8f);
    float swid = sc_from_bits(ISu[3]);
    SC[10] = fmaxf(sx * swid * (float)IS[5] / 127.0f, 1e-8f);
  }
}

// quant(h1) -> bn1 -> relu -> quant => A2 int8 (NHWC)
__device__ __forceinline__ signed char qact(int v, float sxw, float s_h1, float s_y2, float wq,
                                            float bb) {
  float hf = (float)v * sxw;
  float q = clamp8f(rintf(hf / s_h1));
  float hv = q * s_h1;
  float y = fmaxf(hv * wq + bb, 0.0f);
  float a = fminf(fmaxf(rintf(y / s_y2), -128.0f), 127.0f);
  return (signed char)(int)a;
}

__global__ __launch_bounds__(THREADS) void k_qh1(const int4* __restrict__ H1,
                                                 char4* __restrict__ A2,
                                                 const float* __restrict__ SC,
                                                 const float* __restrict__ wq1,
                                                 const float* __restrict__ b1) {
  int t = blockIdx.x * THREADS + threadIdx.x;  // < 1,605,632
  const unsigned* ISu = (const unsigned*)SC;
  float sx = sc_from_bits(ISu[0]);
  float sw1 = sc_from_bits(ISu[1]);
  float sxw = sx * sw1;
  float s_h1 = SC[8];
  float s_y2 = SC[9];
  int4 v = H1[t];
  int c0 = (t * 4) & 255;
  char4 r;
  r.x = qact(v.x, sxw, s_h1, s_y2, wq1[c0], b1[c0]);
  r.y = qact(v.y, sxw, s_h1, s_y2, wq1[c0 + 1], b1[c0 + 1]);
  r.z = qact(v.z, sxw, s_h1, s_y2, wq1[c0 + 2], b1[c0 + 2]);
  r.w = qact(v.w, sxw, s_h1, s_y2, wq1[c0 + 3], b1[c0 + 3]);
  A2[t] = r;
}

// conv2 3x3 s1 p1 (Cin=256). 896 blocks (n, ho-pair, N-half). Round-6 K-loop + int4 staging.
__global__ __launch_bounds__(THREADS, 2) void k_conv2(const int* __restrict__ A2,
                                                      const vi4* __restrict__ W2m,
                                                      int* __restrict__ H2,
                                                      int* __restrict__ maxabs_h2) {
  __shared__ __align__(16) int lds[4 * 30 * 68];
  __shared__ int redA[4];
  const int tid = threadIdx.x;
  const int bx = blockIdx.x;
  const int n = bx / 28, rr = bx % 28;
  const int hp = rr >> 1, nh = rr & 1;
  const int ho0 = hp * 2;
  vi4 zero = {0, 0, 0, 0};

  for (int r = 0; r < 4; ++r) {
    int h = ho0 - 1 + r;
    int* dst = lds + r * 30 * 68;
    if (h >= 0 && h < 28) {
      const vi4* src = (const vi4*)(A2 + (n * 28 + h) * 28 * 64);
      for (int i4 = tid; i4 < 448; i4 += THREADS) {
        int col = i4 >> 4, c = (i4 & 15) * 4;
        *(vi4*)(dst + (col + 1) * 68 + c) = src[i4];
      }
      if (tid < 64) dst[tid] = 0;
      else if (tid >= 128 && tid < 192) dst[29 * 68 + (tid - 128)] = 0;
    } else {
      for (int i4 = tid; i4 < 510; i4 += THREADS) ((vi4*)dst)[i4] = zero;
    }
  }
  __syncthreads();

  const int lane = tid & 63, wv = tid >> 6;
  const int mw = wv & 1, nw = wv >> 1;
  const int lm = lane & 15, quad = lane >> 4;
  const int woc0 = lm, woc1 = (16 + lm) > 27 ? 27 : (16 + lm);
  const int choff = quad * 4;
  const int ho = ho0 + mw;
  const int ctbase = nh * 8 + nw * 4;

  vi4 acc[2][4];
  vi4 bcur[4], bnext[4];
  vi4 a0c, a1c, a0n, a1n;
#pragma unroll
  for (int mt = 0; mt < 2; ++mt)
#pragma unroll
    for (int ct = 0; ct < 4; ++ct) acc[mt][ct] = zero;

  const vi4* wbase = W2m + ctbase * 64 + lane;
#pragma unroll
  for (int ct = 0; ct < 4; ++ct) bcur[ct] = wbase[ct * 64];
  {
    const int ro = mw * 30;  // kh=0
    a0c = *(const vi4*)(lds + (ro + woc0) * 68 + choff);
    a1c = *(const vi4*)(lds + (ro + woc1) * 68 + choff);
  }
#pragma unroll 1
  for (int ks = 0; ks < 36; ++ks) {
    int ksn = ks + 1;
    if (ksn < 36) {
      int khn = (ksn >= 12) + (ksn >= 24);
      int t2 = ksn - khn * 12;
      int kwn = t2 >> 2, kcn = t2 & 3;
#pragma unroll
      for (int ct = 0; ct < 4; ++ct) bnext[ct] = wbase[ksn * 1024 + ct * 64];
      int ro = (mw + khn) * 30;
      a0n = *(const vi4*)(lds + (ro + woc0 + kwn) * 68 + kcn * 16 + choff);
      a1n = *(const vi4*)(lds + (ro + woc1 + kwn) * 68 + kcn * 16 + choff);
    }
#pragma unroll
    for (int ct = 0; ct < 4; ++ct) {
      acc[0][ct] = MFMA_I8(a0c, bcur[ct], acc[0][ct]);
      acc[1][ct] = MFMA_I8(a1c, bcur[ct], acc[1][ct]);
    }
    a0c = a0n;
    a1c = a1n;
#pragma unroll
    for (int ct = 0; ct < 4; ++ct) bcur[ct] = bnext[ct];
  }

  const int obase = ((n * 28 + ho) * 28) * 256;
  int am = 0;
#pragma unroll
  for (int ct = 0; ct < 4; ++ct) {
    const int co = (ctbase + ct) * 16 + lm;
#pragma unroll
    for (int mt = 0; mt < 2; ++mt)
#pragma unroll
      for (int r = 0; r < 4; ++r) {
        int wo = mt * 16 + quad * 4 + r;
        if (wo < 28) {
          int v = acc[mt][ct][r];
          H2[obase + wo * 256 + co] = v;
          am = max(am, v < 0 ? -v : v);
        }
      }
  }
#pragma unroll
  for (int k = 32; k >= 1; k >>= 1) am = max(am, __shfl_xor(am, k));
  if (lane == 0) redA[wv] = am;
  __syncthreads();
  if (tid == 0) {
    int a = max(max(redA[0], redA[1]), max(redA[2], redA[3]));
    atomicMax(maxabs_h2, a);
  }
}

// ---- residual sum math shared by k_absmax2 / k_out ----
struct SumParams {
  float sxw2, s_h2, sxwid, s_idq;
};
__device__ __forceinline__ float sum_val(int v2, int vi, const SumParams& P, float wq2c, float b2c,
                                         float wqidc, float bidc) {
  float q2 = clamp8f(rintf((float)v2 * P.sxw2 / P.s_h2));
  float z = (q2 * P.s_h2) * wq2c + b2c;
  float qi = clamp8f(rintf((float)vi * P.sxwid / P.s_idq));
  float zi = (qi * P.s_idq) * wqidc + bidc;
  return z + zi;
}
__device__ __forceinline__ SumParams make_params(const float* SC, const int* IS) {
  const unsigned* ISu = (const unsigned*)IS;
  SumParams P;
  float sx = sc_from_bits(ISu[0]);
  float sw2 = sc_from_bits(ISu[2]);
  float swid = sc_from_bits(ISu[3]);
  float s_y2 = SC[9];
  P.s_idq = SC[10];
  P.sxw2 = s_y2 * sw2;
  P.s_h2 = fmaxf(P.sxw2 * (float)IS[6] / 127.0f, 1e-8f);
  P.sxwid = sx * swid;
  return P;
}

// Pass 1: global absmax of residual sum. Grid-stride, 1 atomic/block.
__global__ __launch_bounds__(THREADS) void k_absmax2(const int4* __restrict__ H2,
                                                     const int4* __restrict__ IDI,
                                                     const float* __restrict__ SC,
                                                     const int* __restrict__ IS,
                                                     const float* __restrict__ wq2,
                                                     const float* __restrict__ b2,
                                                     const float* __restrict__ wqid,
                                                     const float* __restrict__ bidp,
                                                     unsigned* __restrict__ slot) {
  __shared__ float pw2[256], pb2[256], pwi[256], pbi[256];
  int tid = threadIdx.x;
  pw2[tid] = wq2[tid];
  pb2[tid] = b2[tid];
  pwi[tid] = wqid[tid];
  pbi[tid] = bidp[tid];
  __syncthreads();
  SumParams P = make_params(SC, IS);
  const int n4 = 1605632;
  const int stride = gridDim.x * THREADS;
  float m = 0.0f;
  for (int i = blockIdx.x * THREADS + tid; i < n4; i += stride) {
    int4 v2 = H2[i];
    int4 vi = IDI[i];
    int c0 = (i * 4) & 255;
    m = fmaxf(m, fabsf(sum_val(v2.x, vi.x, P, pw2[c0], pb2[c0], pwi[c0], pbi[c0])));
    m = fmaxf(m, fabsf(sum_val(v2.y, vi.y, P, pw2[c0 + 1], pb2[c0 + 1], pwi[c0 + 1], pbi[c0 + 1])));
    m = fmaxf(m, fabsf(sum_val(v2.z, vi.z, P, pw2[c0 + 2], pb2[c0 + 2], pwi[c0 + 2], pbi[c0 + 2])));
    m = fmaxf(m, fabsf(sum_val(v2.w, vi.w, P, pw2[c0 + 3], pb2[c0 + 3], pwi[c0 + 3], pbi[c0 + 3])));
  }
#pragma unroll
  for (int k = 32; k >= 1; k >>= 1) m = fmaxf(m, __shfl_xor(m, k));
  __shared__ float wred[4];
  if ((tid & 63) == 0) wred[tid >> 6] = m;
  __syncthreads();
  if (tid == 0) {
    m = fmaxf(fmaxf(wred[0], wred[1]), fmaxf(wred[2], wred[3]));
    atomicMax(slot, __float_as_uint(m));
  }
}

// Pass 2: recompute sum, final requant + relu, write NCHW via padded LDS tile transpose.
__global__ __launch_bounds__(THREADS) void k_out(const int* __restrict__ H2,
                                                 const int* __restrict__ IDI,
                                                 const float* __restrict__ SC,
                                                 const int* __restrict__ IS,
                                                 const float* __restrict__ wq2,
                                                 const float* __restrict__ b2,
                                                 const float* __restrict__ wqid,
                                                 const float* __restrict__ bidp,
                                                 float* __restrict__ out) {
  __shared__ float tile[64 * 57];
  __shared__ float pw2[64], pb2[64], pwi[64], pbi[64];
  int tid = threadIdx.x;
  int b = blockIdx.x;
  int ct = b & 3;
  int rt = (b >> 2) % 14;
  int n = b / 56;
  int c0 = ct * 64;
  int r0 = rt * 56;
  if (tid < 64) {
    pw2[tid] = wq2[c0 + tid];
    pb2[tid] = b2[c0 + tid];
    pwi[tid] = wqid[c0 + tid];
    pbi[tid] = bidp[c0 + tid];
  }
  __syncthreads();
  SumParams P = make_params(SC, IS);
  float out_s = fmaxf(__uint_as_float(((const unsigned*)IS)[11]) / 127.0f, 1e-8f);

  const int base = (n * 784 + r0) * 256 + c0;
#pragma unroll
  for (int k = 0; k < 14; ++k) {
    int idx = tid + k * 256;  // < 3584
    int rl = idx >> 6;
    int cl = idx & 63;
    int e = base + rl * 256 + cl;
    float sv = sum_val(H2[e], IDI[e], P, pw2[cl], pb2[cl], pwi[cl], pbi[cl]);
    float q = clamp8f(rintf(sv / out_s));
    tile[cl * 57 + rl] = q > 0.0f ? q * out_s : 0.0f;
  }
  __syncthreads();
  float* ob = out + n * 200704 + c0 * 784 + r0;
#pragma unroll
  for (int k = 0; k < 14; ++k) {
    int idx = tid + k * 256;
    int cl = idx / 56;
    int rl = idx % 56;
    ob[cl * 784 + rl] = tile[cl * 57 + rl];
  }
  if (b == 0 && tid == 0) out[6422528] = out_s;
}

extern "C" void kernel_launch(void* const* d_in, const int* in_sizes, int n_in, void* d_out,
                              int out_size, void* d_ws, size_t ws_size, hipStream_t stream) {
  (void)in_sizes; (void)n_in; (void)out_size; (void)ws_size;
  const float* x = (const float*)d_in[0];
  const float* w1 = (const float*)d_in[1];
  const float* w2 = (const float*)d_in[2];
  const float* wid = (const float*)d_in[3];
  const float* bn1g = (const float*)d_in[4];
  const float* bn1b = (const float*)d_in[5];
  const float* bn1m = (const float*)d_in[6];
  const float* bn1v = (const float*)d_in[7];
  const float* bn2g = (const float*)d_in[8];
  const float* bn2b = (const float*)d_in[9];
  const float* bn2m = (const float*)d_in[10];
  const float* bn2v = (const float*)d_in[11];
  const float* idg = (const float*)d_in[12];
  const float* idb = (const float*)d_in[13];
  const float* idm = (const float*)d_in[14];
  const float* idv = (const float*)d_in[15];

  char* ws = (char*)d_ws;
  float* SC = (float*)ws;
  int* IS = (int*)ws;
  unsigned* ISu = (unsigned*)ws;
  float* wq1 = (float*)(ws + 3072);
  float* b1 = (float*)(ws + 4096);
  float* wq2 = (float*)(ws + 5120);
  float* b2 = (float*)(ws + 6144);
  float* wqid = (float*)(ws + 7168);
  float* bid = (float*)(ws + 8192);
  char* X8 = ws + 16384;                 // NHWC int8; A2 overlays after conv1
  char* A2 = X8;
  char* W1m = X8 + 12845056;
  char* W2m = W1m + 294912;
  char* Widm = W2m + 589824;
  int* H1 = (int*)(Widm + 32768);
  int* H2 = H1;
  int* IDI = (int*)((char*)H1 + 25690112);
  float* out = (float*)d_out;
  int* maxS = (int*)d_out;  // extrema scratch in d_out (dead until k_out)
  int* minS = maxS + 448 * 256;

  hipMemsetAsync(IS, 0, 256, stream);  // zero scalar slots (atomic targets)
  k_pre<<<723, THREADS, 0, stream>>>(IS, bn1g, bn1b, bn1m, bn1v, wq1, b1, bn2g, bn2b, bn2m, bn2v,
                                     wq2, b2, idg, idb, idm, idv, wqid, bid, (const float4*)w1,
                                     (const float4*)w2, (const float4*)wid, (const float4*)x);
  k_quant<<<2016, THREADS, 0, stream>>>(x, (int*)X8, w1, (vi4*)W1m, w2, (vi4*)W2m, wid,
                                        (vi4*)Widm, ISu);
  k_conv1<<<896, THREADS, 0, stream>>>((const int*)X8, (const vi4*)W1m, (const vi4*)Widm, H1, IDI,
                                       maxS, minS, IS + 5);
  k_rs1<<<1, THREADS, 0, stream>>>(IS, SC, maxS, minS, wq1, b1);
  k_qh1<<<6272, THREADS, 0, stream>>>((const int4*)H1, (char4*)A2, SC, wq1, b1);
  k_conv2<<<896, THREADS, 0, stream>>>((const int*)A2, (const vi4*)W2m, H2, IS + 6);
  k_absmax2<<<1024, THREADS, 0, stream>>>((const int4*)H2, (const int4*)IDI, SC, IS, wq2, b2, wqid,
                                          bid, ISu + 11);
  k_out<<<1792, THREADS, 0, stream>>>(H2, IDI, SC, IS, wq2, b2, wqid, bid, out);
}

// Round 9
// 256.912 us; speedup vs baseline: 3.5488x; 1.0557x over previous
//
#include <hip/hip_runtime.h>
#include <limits.h>

#define THREADS 256

typedef int vi4 __attribute__((ext_vector_type(4)));

__device__ __forceinline__ float clamp8f(float q) { return fminf(fmaxf(q, -128.0f), 127.0f); }
__device__ __forceinline__ float sc_from_bits(unsigned b) {
  return fmaxf(__uint_as_float(b) / 127.0f, 1e-8f);
}
__device__ __forceinline__ signed char q8(float v, float s) {
  return (signed char)(int)clamp8f(rintf(v / s));
}

// Scalar slots: [0] amax_x [1] amax_w1 [2] amax_w2 [3] amax_wid
// [4] maxabs_h1 [5] maxabs_id [6] maxabs_h2 [7] max_y2 [8] s_h1 [9] s_y2 [10] s_idq [11] amax_sum

__device__ __forceinline__ void amax_body(const float4* __restrict__ p, int n4, int bid,
                                          int nblocks, unsigned* __restrict__ slot) {
  const int tid = threadIdx.x;
  const int stride = nblocks * THREADS;
  float m = 0.0f;
  int i = bid * THREADS + tid;
  for (; i + 3 * stride < n4; i += 4 * stride) {
    float4 v0 = p[i];
    float4 v1 = p[i + stride];
    float4 v2 = p[i + 2 * stride];
    float4 v3 = p[i + 3 * stride];
    float m0 = fmaxf(fmaxf(fabsf(v0.x), fabsf(v0.y)), fmaxf(fabsf(v0.z), fabsf(v0.w)));
    float m1 = fmaxf(fmaxf(fabsf(v1.x), fabsf(v1.y)), fmaxf(fabsf(v1.z), fabsf(v1.w)));
    float m2 = fmaxf(fmaxf(fabsf(v2.x), fabsf(v2.y)), fmaxf(fabsf(v2.z), fabsf(v2.w)));
    float m3 = fmaxf(fmaxf(fabsf(v3.x), fabsf(v3.y)), fmaxf(fabsf(v3.z), fabsf(v3.w)));
    m = fmaxf(m, fmaxf(fmaxf(m0, m1), fmaxf(m2, m3)));
  }
  for (; i < n4; i += stride) {
    float4 v = p[i];
    m = fmaxf(m, fmaxf(fmaxf(fabsf(v.x), fabsf(v.y)), fmaxf(fabsf(v.z), fabsf(v.w))));
  }
#pragma unroll
  for (int k = 32; k >= 1; k >>= 1) m = fmaxf(m, __shfl_xor(m, k));
  __shared__ float wred[4];
  if ((tid & 63) == 0) wred[tid >> 6] = m;
  __syncthreads();
  if (tid == 0) {
    m = fmaxf(fmaxf(wred[0], wred[1]), fmaxf(wred[2], wred[3]));
    atomicMax(slot, __float_as_uint(m));
  }
}

// Merged: blocks 0-2 bnfold(bn1,bn2,id); 3..66 w1 amax; 67..194 w2; 195..210 wid; 211..722 x.
__global__ __launch_bounds__(THREADS) void k_pre(
    int* IS, const float* g1, const float* be1, const float* m1, const float* v1, float* wq1,
    float* b1, const float* g2, const float* be2, const float* m2, const float* v2, float* wq2,
    float* b2, const float* gi, const float* bei, const float* mi, const float* vvi, float* wqi,
    float* bi, const float4* w1, const float4* w2, const float4* wid, const float4* x) {
  unsigned* ISu = (unsigned*)IS;
  int b = blockIdx.x;
  int c = threadIdx.x;
  if (b < 3) {
    const float *gamma, *beta, *mean, *var;
    float *wq, *bb;
    if (b == 0) { gamma = g1; beta = be1; mean = m1; var = v1; wq = wq1; bb = b1; }
    else if (b == 1) { gamma = g2; beta = be2; mean = m2; var = v2; wq = wq2; bb = b2; }
    else { gamma = gi; beta = bei; mean = mi; var = vvi; wq = wqi; bb = bi; }
    __shared__ float red[THREADS];
    float ws = gamma[c] * (1.0f / sqrtf(var[c] + 1e-5f));
    red[c] = fabsf(ws);
    __syncthreads();
    for (int s = THREADS / 2; s > 0; s >>= 1) {
      if (c < s) red[c] = fmaxf(red[c], red[c + s]);
      __syncthreads();
    }
    float sws = fmaxf(red[0] / 127.0f, 1e-8f);
    float q = clamp8f(rintf(ws / sws)) * sws;
    wq[c] = q;
    bb[c] = beta[c] - mean[c] * q;
    return;
  }
  b -= 3;
  if (b < 64) { amax_body(w1, 73728, b, 64, ISu + 1); return; }
  b -= 64;
  if (b < 128) { amax_body(w2, 147456, b, 128, ISu + 2); return; }
  b -= 128;
  if (b < 16) { amax_body(wid, 8192, b, 16, ISu + 3); return; }
  b -= 16;
  amax_body(x, 3211264, b, 512, ISu + 0);
}

// Merged quantize: blocks [0,1792) qx; [1792,1864) qw1; [1864,2008) qw2; [2008,2016) qwid.
__global__ __launch_bounds__(THREADS) void k_quant(const float* __restrict__ x,
                                                   int* __restrict__ X8,
                                                   const float* __restrict__ w1f,
                                                   vi4* __restrict__ W1m,
                                                   const float* __restrict__ w2f,
                                                   vi4* __restrict__ W2m,
                                                   const float* __restrict__ widf,
                                                   vi4* __restrict__ Widm,
                                                   const unsigned* __restrict__ ISu) {
  __shared__ signed char tile[56 * 132];
  int b = blockIdx.x;
  int t = threadIdx.x;
  if (b < 1792) {
    float s = sc_from_bits(ISu[0]);
    int h = b % 56, n = b / 56;
    const float* xp = x + ((n * 128) * 56 + h) * 56;
#pragma unroll
    for (int k = 0; k < 28; ++k) {
      int i = t + k * 256;  // < 7168
      int w = i % 56, c = i / 56;
      tile[w * 132 + c] = q8(xp[c * 3136 + w], s);
    }
    __syncthreads();
    int* op = X8 + (n * 56 + h) * 56 * 32;
#pragma unroll
    for (int k = 0; k < 7; ++k) {
      int i = t + k * 256;  // < 1792
      int w = i >> 5, c4 = (i & 31) * 4;
      const signed char* tp = tile + w * 132 + c4;
      op[i] = (int)(unsigned char)tp[0] | ((int)(unsigned char)tp[1] << 8) |
              ((int)(unsigned char)tp[2] << 16) | ((int)(unsigned char)tp[3] << 24);
    }
    return;
  }
  if (b < 1864) {
    int tt = (b - 1792) * THREADS + t;  // < 18432
    float s = sc_from_bits(ISu[1]);
    int lane = tt & 63;
    int cotile = (tt >> 6) & 15;
    int ks = tt >> 10;  // 0..17
    int tap = ks >> 1, kc = ks & 1;
    int kh = tap / 3, kw = tap % 3;
    int co = cotile * 16 + (lane & 15);
    int ci0 = kc * 64 + (lane >> 4) * 16;
    const float* src = w1f + (co * 128 + ci0) * 9 + kh * 3 + kw;
    int r[4];
#pragma unroll
    for (int q = 0; q < 4; ++q) {
      unsigned b0 = (unsigned char)q8(src[(q * 4 + 0) * 9], s);
      unsigned b1 = (unsigned char)q8(src[(q * 4 + 1) * 9], s);
      unsigned b2 = (unsigned char)q8(src[(q * 4 + 2) * 9], s);
      unsigned b3 = (unsigned char)q8(src[(q * 4 + 3) * 9], s);
      r[q] = (int)(b0 | (b1 << 8) | (b2 << 16) | (b3 << 24));
    }
    vi4 v = {r[0], r[1], r[2], r[3]};
    W1m[tt] = v;
    return;
  }
  if (b < 2008) {
    int tt = (b - 1864) * THREADS + t;  // < 36864
    float s = sc_from_bits(ISu[2]);
    int lane = tt & 63;
    int cotile = (tt >> 6) & 15;
    int ks = tt >> 10;  // 0..35
    int tap = ks >> 2, kc = ks & 3;
    int kh = tap / 3, kw = tap % 3;
    int co = cotile * 16 + (lane & 15);
    int ci0 = kc * 64 + (lane >> 4) * 16;
    const float* src = w2f + (co * 256 + ci0) * 9 + kh * 3 + kw;
    int r[4];
#pragma unroll
    for (int q = 0; q < 4; ++q) {
      unsigned b0 = (unsigned char)q8(src[(q * 4 + 0) * 9], s);
      unsigned b1 = (unsigned char)q8(src[(q * 4 + 1) * 9], s);
      unsigned b2 = (unsigned char)q8(src[(q * 4 + 2) * 9], s);
      unsigned b3 = (unsigned char)q8(src[(q * 4 + 3) * 9], s);
      r[q] = (int)(b0 | (b1 << 8) | (b2 << 16) | (b3 << 24));
    }
    vi4 v = {r[0], r[1], r[2], r[3]};
    W2m[tt] = v;
    return;
  }
  {
    int tt = (b - 2008) * THREADS + t;  // < 2048
    float s = sc_from_bits(ISu[3]);
    int lane = tt & 63;
    int cotile = (tt >> 6) & 15;
    int ks = tt >> 10;  // 0..1
    int co = cotile * 16 + (lane & 15);
    int ci0 = ks * 64 + (lane >> 4) * 16;
    const float* src = widf + co * 128 + ci0;
    int r[4];
#pragma unroll
    for (int q = 0; q < 4; ++q) {
      unsigned b0 = (unsigned char)q8(src[q * 4 + 0], s);
      unsigned b1 = (unsigned char)q8(src[q * 4 + 1], s);
      unsigned b2 = (unsigned char)q8(src[q * 4 + 2], s);
      unsigned b3 = (unsigned char)q8(src[q * 4 + 3], s);
      r[q] = (int)(b0 | (b1 << 8) | (b2 << 16) | (b3 << 24));
    }
    vi4 v = {r[0], r[1], r[2], r[3]};
    Widm[tt] = v;
  }
}

#define MFMA_I8(a, b, c) __builtin_amdgcn_mfma_i32_16x16x64_i8(a, b, c, 0, 0, 0)

// conv1 3x3 s2 p1 (Cin=128) + identity 1x1 s2, MFMA implicit GEMM.
// 896 blocks (n, ho-pair, N-half). 3 blocks/CU; ping-pong 2-step K-loop.
__global__ __launch_bounds__(THREADS, 3) void k_conv1(const int* __restrict__ X8,
                                                      const vi4* __restrict__ W1m,
                                                      const vi4* __restrict__ Widm,
                                                      int* __restrict__ H1, int* __restrict__ IDI,
                                                      int* __restrict__ maxS,
                                                      int* __restrict__ minS,
                                                      int* __restrict__ maxabs_id) {
  __shared__ __align__(16) int lds[5 * 58 * 36];
  __shared__ int sMax[2][128], sMin[2][128], redA[4];
  const int tid = threadIdx.x;
  const int bx = blockIdx.x;
  const int n = bx / 28, rr = bx % 28;
  const int hp = rr >> 1, nh = rr & 1;
  const int ho0 = hp * 2;
  vi4 zero = {0, 0, 0, 0};

  for (int r = 0; r < 5; ++r) {
    int h = 2 * ho0 - 1 + r;
    int* dst = lds + r * 58 * 36;
    if (h >= 0 && h < 56) {
      const vi4* src = (const vi4*)(X8 + (n * 56 + h) * 56 * 32);
      for (int i4 = tid; i4 < 448; i4 += THREADS) {
        int col = i4 >> 3, c = (i4 & 7) * 4;
        *(vi4*)(dst + (col + 1) * 36 + c) = src[i4];
      }
      if (tid < 32) dst[tid] = 0;
      else if (tid >= 128 && tid < 160) dst[57 * 36 + (tid - 128)] = 0;
    } else {
      for (int i4 = tid; i4 < 522; i4 += THREADS) ((vi4*)dst)[i4] = zero;
    }
  }
  __syncthreads();

  const int lane = tid & 63, wv = tid >> 6;
  const int mw = wv & 1, nw = wv >> 1;
  const int lm = lane & 15, quad = lane >> 4;
  const int woc0 = lm, woc1 = (16 + lm) > 27 ? 27 : (16 + lm);
  const int choff = quad * 4;
  const int ho = ho0 + mw;
  const int obase = ((n * 28 + ho) * 28) * 256;
  const int ctbase = nh * 8 + nw * 4;

  vi4 acc[2][4];
  vi4 bA[4], bB[4];
  vi4 a0A, a1A, a0B, a1B;

  // ---- identity branch first (2 K-steps), reusing acc ----
#pragma unroll
  for (int mt = 0; mt < 2; ++mt)
#pragma unroll
    for (int ct = 0; ct < 4; ++ct) acc[mt][ct] = zero;
  const vi4* wibase = Widm + ctbase * 64 + lane;
  {
    const int ro = (2 * mw + 1) * 58;
#pragma unroll
    for (int kc = 0; kc < 2; ++kc) {
      vi4 a0 = *(const vi4*)(lds + (ro + 2 * woc0 + 1) * 36 + kc * 16 + choff);
      vi4 a1 = *(const vi4*)(lds + (ro + 2 * woc1 + 1) * 36 + kc * 16 + choff);
#pragma unroll
      for (int ct = 0; ct < 4; ++ct) {
        vi4 b = wibase[kc * 1024 + ct * 64];
        acc[0][ct] = MFMA_I8(a0, b, acc[0][ct]);
        acc[1][ct] = MFMA_I8(a1, b, acc[1][ct]);
      }
    }
  }
  int am = 0;
#pragma unroll
  for (int ct = 0; ct < 4; ++ct) {
    const int co = (ctbase + ct) * 16 + lm;
#pragma unroll
    for (int mt = 0; mt < 2; ++mt)
#pragma unroll
      for (int r = 0; r < 4; ++r) {
        int wo = mt * 16 + quad * 4 + r;
        if (wo < 28) {
          int v = acc[mt][ct][r];
          IDI[obase + wo * 256 + co] = v;
          am = max(am, v < 0 ? -v : v);
        }
      }
  }
#pragma unroll
  for (int k = 32; k >= 1; k >>= 1) am = max(am, __shfl_xor(am, k));
  if (lane == 0) redA[wv] = am;

  // ---- main 3x3 conv, 18 K-steps, ping-pong (no register copies) ----
#pragma unroll
  for (int mt = 0; mt < 2; ++mt)
#pragma unroll
    for (int ct = 0; ct < 4; ++ct) acc[mt][ct] = zero;
  const vi4* wbase = W1m + ctbase * 64 + lane;
#pragma unroll
  for (int ct = 0; ct < 4; ++ct) bA[ct] = wbase[ct * 64];
  {
    const int ro = (2 * mw) * 58;  // ks=0
    a0A = *(const vi4*)(lds + (ro + 2 * woc0) * 36 + choff);
    a1A = *(const vi4*)(lds + (ro + 2 * woc1) * 36 + choff);
  }
#pragma unroll 1
  for (int ks = 0; ks < 18; ks += 2) {
    {
      const int ksn = ks + 1;
      const int khn = (ksn >= 6) + (ksn >= 12);
      const int t2 = ksn - khn * 6;
      const int kwn = t2 >> 1, kcn = t2 & 1;
#pragma unroll
      for (int ct = 0; ct < 4; ++ct) bB[ct] = wbase[ksn * 1024 + ct * 64];
      const int ro = (2 * mw + khn) * 58;
      a0B = *(const vi4*)(lds + (ro + 2 * woc0 + kwn) * 36 + kcn * 16 + choff);
      a1B = *(const vi4*)(lds + (ro + 2 * woc1 + kwn) * 36 + kcn * 16 + choff);
    }
#pragma unroll
    for (int ct = 0; ct < 4; ++ct) {
      acc[0][ct] = MFMA_I8(a0A, bA[ct], acc[0][ct]);
      acc[1][ct] = MFMA_I8(a1A, bA[ct], acc[1][ct]);
    }
    if (ks + 2 < 18) {
      const int ksn = ks + 2;
      const int khn = (ksn >= 6) + (ksn >= 12);
      const int t2 = ksn - khn * 6;
      const int kwn = t2 >> 1, kcn = t2 & 1;
#pragma unroll
      for (int ct = 0; ct < 4; ++ct) bA[ct] = wbase[ksn * 1024 + ct * 64];
      const int ro = (2 * mw + khn) * 58;
      a0A = *(const vi4*)(lds + (ro + 2 * woc0 + kwn) * 36 + kcn * 16 + choff);
      a1A = *(const vi4*)(lds + (ro + 2 * woc1 + kwn) * 36 + kcn * 16 + choff);
    }
#pragma unroll
    for (int ct = 0; ct < 4; ++ct) {
      acc[0][ct] = MFMA_I8(a0B, bB[ct], acc[0][ct]);
      acc[1][ct] = MFMA_I8(a1B, bB[ct], acc[1][ct]);
    }
  }

#pragma unroll
  for (int ct = 0; ct < 4; ++ct) {
    const int co = (ctbase + ct) * 16 + lm;
    int vmax = INT_MIN, vmin = INT_MAX;
#pragma unroll
    for (int mt = 0; mt < 2; ++mt)
#pragma unroll
      for (int r = 0; r < 4; ++r) {
        int wo = mt * 16 + quad * 4 + r;
        if (wo < 28) {
          int v = acc[mt][ct][r];
          H1[obase + wo * 256 + co] = v;
          vmax = max(vmax, v);
          vmin = min(vmin, v);
        }
      }
    vmax = max(vmax, __shfl_xor(vmax, 16));
    vmax = max(vmax, __shfl_xor(vmax, 32));
    vmin = min(vmin, __shfl_xor(vmin, 16));
    vmin = min(vmin, __shfl_xor(vmin, 32));
    if (lane < 16) {
      sMax[mw][nw * 64 + ct * 16 + lane] = vmax;
      sMin[mw][nw * 64 + ct * 16 + lane] = vmin;
    }
  }
  __syncthreads();
  if (tid < 128) {
    int row = n * 14 + hp;
    maxS[row * 256 + nh * 128 + tid] = max(sMax[0][tid], sMax[1][tid]);
    minS[row * 256 + nh * 128 + tid] = min(sMin[0][tid], sMin[1][tid]);
  }
  if (tid == 0) {
    int a = max(max(redA[0], redA[1]), max(redA[2], redA[3]));
    atomicMax(maxabs_id, a);
  }
}

// Merged k_red + k_s1, 1024 threads: 4-way row-parallel scan of 448x256 extrema + scale derivation.
__global__ __launch_bounds__(1024) void k_rs1(int* __restrict__ IS, float* __restrict__ SC,
                                              const int* __restrict__ maxS,
                                              const int* __restrict__ minS,
                                              const float* __restrict__ wq1,
                                              const float* __restrict__ b1) {
  __shared__ int pMax[4][256], pMin[4][256];
  __shared__ int ri[256];
  __shared__ float rf[256];
  int t = threadIdx.x;
  int c = t & 255, part = t >> 8;
  int vmax = INT_MIN, vmin = INT_MAX;
#pragma unroll 4
  for (int r = part; r < 448; r += 4) {
    vmax = max(vmax, maxS[r * 256 + c]);
    vmin = min(vmin, minS[r * 256 + c]);
  }
  pMax[part][c] = vmax;
  pMin[part][c] = vmin;
  __syncthreads();
  if (t < 256) {
    vmax = max(max(pMax[0][c], pMax[1][c]), max(pMax[2][c], pMax[3][c]));
    vmin = min(min(pMin[0][c], pMin[1][c]), min(pMin[2][c], pMin[3][c]));
    int a1 = vmax < 0 ? -vmax : vmax;
    int a0 = vmin < 0 ? -vmin : vmin;
    ri[c] = max(a1, a0);
  }
  __syncthreads();
  for (int s = 128; s > 0; s >>= 1) {
    if (t < s) ri[t] = max(ri[t], ri[t + s]);
    __syncthreads();
  }
  int mh1 = ri[0];
  const unsigned* ISu = (const unsigned*)IS;
  float sx = sc_from_bits(ISu[0]);
  float sw1 = sc_from_bits(ISu[1]);
  float sxw = sx * sw1;
  float s_h1 = fmaxf(sxw * (float)mh1 / 127.0f, 1e-8f);
  if (t < 256) {
    float wq = wq1[c], bbc = b1[c];
    float q1 = clamp8f(rintf((float)vmax * sxw / s_h1));
    float q0 = clamp8f(rintf((float)vmin * sxw / s_h1));
    float hv1 = q1 * s_h1, hv0 = q0 * s_h1;
    float y1 = fmaxf(hv1 * wq + bbc, 0.0f);
    float y0 = fmaxf(hv0 * wq + bbc, 0.0f);
    rf[c] = fmaxf(y1, y0);
  }
  __syncthreads();
  for (int s = 128; s > 0; s >>= 1) {
    if (t < s) rf[t] = fmaxf(rf[t], rf[t + s]);
    __syncthreads();
  }
  if (t == 0) {
    IS[4] = mh1;
    SC[7] = rf[0];
    SC[8] = s_h1;
    SC[9] = fmaxf(rf[0] / 127.0f, 1e-8f);
    float swid = sc_from_bits(ISu[3]);
    SC[10] = fmaxf(sx * swid * (float)IS[5] / 127.0f, 1e-8f);
  }
}

// quant(h1) -> bn1 -> relu -> quant => A2 int8 (NHWC)
__device__ __forceinline__ signed char qact(int v, float sxw, float s_h1, float s_y2, float wq,
                                            float bb) {
  float hf = (float)v * sxw;
  float q = clamp8f(rintf(hf / s_h1));
  float hv = q * s_h1;
  float y = fmaxf(hv * wq + bb, 0.0f);
  float a = fminf(fmaxf(rintf(y / s_y2), -128.0f), 127.0f);
  return (signed char)(int)a;
}

__global__ __launch_bounds__(THREADS) void k_qh1(const int4* __restrict__ H1,
                                                 char4* __restrict__ A2,
                                                 const float* __restrict__ SC,
                                                 const float* __restrict__ wq1,
                                                 const float* __restrict__ b1) {
  int t = blockIdx.x * THREADS + threadIdx.x;  // < 1,605,632
  const unsigned* ISu = (const unsigned*)SC;
  float sx = sc_from_bits(ISu[0]);
  float sw1 = sc_from_bits(ISu[1]);
  float sxw = sx * sw1;
  float s_h1 = SC[8];
  float s_y2 = SC[9];
  int4 v = H1[t];
  int c0 = (t * 4) & 255;
  char4 r;
  r.x = qact(v.x, sxw, s_h1, s_y2, wq1[c0], b1[c0]);
  r.y = qact(v.y, sxw, s_h1, s_y2, wq1[c0 + 1], b1[c0 + 1]);
  r.z = qact(v.z, sxw, s_h1, s_y2, wq1[c0 + 2], b1[c0 + 2]);
  r.w = qact(v.w, sxw, s_h1, s_y2, wq1[c0 + 3], b1[c0 + 3]);
  A2[t] = r;
}

// conv2 3x3 s1 p1 (Cin=256). 896 blocks (n, ho-pair, N-half). 4 blocks/CU; ping-pong K-loop.
__global__ __launch_bounds__(THREADS, 4) void k_conv2(const int* __restrict__ A2,
                                                      const vi4* __restrict__ W2m,
                                                      int* __restrict__ H2,
                                                      int* __restrict__ maxabs_h2) {
  __shared__ __align__(16) int lds[4 * 30 * 68];
  __shared__ int redA[4];
  const int tid = threadIdx.x;
  const int bx = blockIdx.x;
  const int n = bx / 28, rr = bx % 28;
  const int hp = rr >> 1, nh = rr & 1;
  const int ho0 = hp * 2;
  vi4 zero = {0, 0, 0, 0};

  for (int r = 0; r < 4; ++r) {
    int h = ho0 - 1 + r;
    int* dst = lds + r * 30 * 68;
    if (h >= 0 && h < 28) {
      const vi4* src = (const vi4*)(A2 + (n * 28 + h) * 28 * 64);
      for (int i4 = tid; i4 < 448; i4 += THREADS) {
        int col = i4 >> 4, c = (i4 & 15) * 4;
        *(vi4*)(dst + (col + 1) * 68 + c) = src[i4];
      }
      if (tid < 64) dst[tid] = 0;
      else if (tid >= 128 && tid < 192) dst[29 * 68 + (tid - 128)] = 0;
    } else {
      for (int i4 = tid; i4 < 510; i4 += THREADS) ((vi4*)dst)[i4] = zero;
    }
  }
  __syncthreads();

  const int lane = tid & 63, wv = tid >> 6;
  const int mw = wv & 1, nw = wv >> 1;
  const int lm = lane & 15, quad = lane >> 4;
  const int woc0 = lm, woc1 = (16 + lm) > 27 ? 27 : (16 + lm);
  const int choff = quad * 4;
  const int ho = ho0 + mw;
  const int ctbase = nh * 8 + nw * 4;

  vi4 acc[2][4];
  vi4 bA[4], bB[4];
  vi4 a0A, a1A, a0B, a1B;
#pragma unroll
  for (int mt = 0; mt < 2; ++mt)
#pragma unroll
    for (int ct = 0; ct < 4; ++ct) acc[mt][ct] = zero;

  const vi4* wbase = W2m + ctbase * 64 + lane;
#pragma unroll
  for (int ct = 0; ct < 4; ++ct) bA[ct] = wbase[ct * 64];
  {
    const int ro = mw * 30;  // ks=0
    a0A = *(const vi4*)(lds + (ro + woc0) * 68 + choff);
    a1A = *(const vi4*)(lds + (ro + woc1) * 68 + choff);
  }
#pragma unroll 1
  for (int ks = 0; ks < 36; ks += 2) {
    {
      const int ksn = ks + 1;
      const int khn = (ksn >= 12) + (ksn >= 24);
      const int t2 = ksn - khn * 12;
      const int kwn = t2 >> 2, kcn = t2 & 3;
#pragma unroll
      for (int ct = 0; ct < 4; ++ct) bB[ct] = wbase[ksn * 1024 + ct * 64];
      const int ro = (mw + khn) * 30;
      a0B = *(const vi4*)(lds + (ro + woc0 + kwn) * 68 + kcn * 16 + choff);
      a1B = *(const vi4*)(lds + (ro + woc1 + kwn) * 68 + kcn * 16 + choff);
    }
#pragma unroll
    for (int ct = 0; ct < 4; ++ct) {
      acc[0][ct] = MFMA_I8(a0A, bA[ct], acc[0][ct]);
      acc[1][ct] = MFMA_I8(a1A, bA[ct], acc[1][ct]);
    }
    if (ks + 2 < 36) {
      const int ksn = ks + 2;
      const int khn = (ksn >= 12) + (ksn >= 24);
      const int t2 = ksn - khn * 12;
      const int kwn = t2 >> 2, kcn = t2 & 3;
#pragma unroll
      for (int ct = 0; ct < 4; ++ct) bA[ct] = wbase[ksn * 1024 + ct * 64];
      const int ro = (mw + khn) * 30;
      a0A = *(const vi4*)(lds + (ro + woc0 + kwn) * 68 + kcn * 16 + choff);
      a1A = *(const vi4*)(lds + (ro + woc1 + kwn) * 68 + kcn * 16 + choff);
    }
#pragma unroll
    for (int ct = 0; ct < 4; ++ct) {
      acc[0][ct] = MFMA_I8(a0B, bB[ct], acc[0][ct]);
      acc[1][ct] = MFMA_I8(a1B, bB[ct], acc[1][ct]);
    }
  }

  const int obase = ((n * 28 + ho) * 28) * 256;
  int am = 0;
#pragma unroll
  for (int ct = 0; ct < 4; ++ct) {
    const int co = (ctbase + ct) * 16 + lm;
#pragma unroll
    for (int mt = 0; mt < 2; ++mt)
#pragma unroll
      for (int r = 0; r < 4; ++r) {
        int wo = mt * 16 + quad * 4 + r;
        if (wo < 28) {
          int v = acc[mt][ct][r];
          H2[obase + wo * 256 + co] = v;
          am = max(am, v < 0 ? -v : v);
        }
      }
  }
#pragma unroll
  for (int k = 32; k >= 1; k >>= 1) am = max(am, __shfl_xor(am, k));
  if (lane == 0) redA[wv] = am;
  __syncthreads();
  if (tid == 0) {
    int a = max(max(redA[0], redA[1]), max(redA[2], redA[3]));
    atomicMax(maxabs_h2, a);
  }
}

// ---- residual sum math shared by k_absmax2 / k_out ----
struct SumParams {
  float sxw2, s_h2, sxwid, s_idq;
};
__device__ __forceinline__ float sum_val(int v2, int vi, const SumParams& P, float wq2c, float b2c,
                                         float wqidc, float bidc) {
  float q2 = clamp8f(rintf((float)v2 * P.sxw2 / P.s_h2));
  float z = (q2 * P.s_h2) * wq2c + b2c;
  float qi = clamp8f(rintf((float)vi * P.sxwid / P.s_idq));
  float zi = (qi * P.s_idq) * wqidc + bidc;
  return z + zi;
}
__device__ __forceinline__ SumParams make_params(const float* SC, const int* IS) {
  const unsigned* ISu = (const unsigned*)IS;
  SumParams P;
  float sx = sc_from_bits(ISu[0]);
  float sw2 = sc_from_bits(ISu[2]);
  float swid = sc_from_bits(ISu[3]);
  float s_y2 = SC[9];
  P.s_idq = SC[10];
  P.sxw2 = s_y2 * sw2;
  P.s_h2 = fmaxf(P.sxw2 * (float)IS[6] / 127.0f, 1e-8f);
  P.sxwid = sx * swid;
  return P;
}

// Pass 1: global absmax of residual sum. Grid-stride, 1 atomic/block.
__global__ __launch_bounds__(THREADS) void k_absmax2(const int4* __restrict__ H2,
                                                     const int4* __restrict__ IDI,
                                                     const float* __restrict__ SC,
                                                     const int* __restrict__ IS,
                                                     const float* __restrict__ wq2,
                                                     const float* __restrict__ b2,
                                                     const float* __restrict__ wqid,
                                                     const float* __restrict__ bidp,
                                                     unsigned* __restrict__ slot) {
  __shared__ float pw2[256], pb2[256], pwi[256], pbi[256];
  int tid = threadIdx.x;
  pw2[tid] = wq2[tid];
  pb2[tid] = b2[tid];
  pwi[tid] = wqid[tid];
  pbi[tid] = bidp[tid];
  __syncthreads();
  SumParams P = make_params(SC, IS);
  const int n4 = 1605632;
  const int stride = gridDim.x * THREADS;
  float m = 0.0f;
  for (int i = blockIdx.x * THREADS + tid; i < n4; i += stride) {
    int4 v2 = H2[i];
    int4 vi = IDI[i];
    int c0 = (i * 4) & 255;
    m = fmaxf(m, fabsf(sum_val(v2.x, vi.x, P, pw2[c0], pb2[c0], pwi[c0], pbi[c0])));
    m = fmaxf(m, fabsf(sum_val(v2.y, vi.y, P, pw2[c0 + 1], pb2[c0 + 1], pwi[c0 + 1], pbi[c0 + 1])));
    m = fmaxf(m, fabsf(sum_val(v2.z, vi.z, P, pw2[c0 + 2], pb2[c0 + 2], pwi[c0 + 2], pbi[c0 + 2])));
    m = fmaxf(m, fabsf(sum_val(v2.w, vi.w, P, pw2[c0 + 3], pb2[c0 + 3], pwi[c0 + 3], pbi[c0 + 3])));
  }
#pragma unroll
  for (int k = 32; k >= 1; k >>= 1) m = fmaxf(m, __shfl_xor(m, k));
  __shared__ float wred[4];
  if ((tid & 63) == 0) wred[tid >> 6] = m;
  __syncthreads();
  if (tid == 0) {
    m = fmaxf(fmaxf(wred[0], wred[1]), fmaxf(wred[2], wred[3]));
    atomicMax(slot, __float_as_uint(m));
  }
}

// Pass 2: recompute sum, final requant + relu, write NCHW via padded LDS tile transpose.
__global__ __launch_bounds__(THREADS) void k_out(const int* __restrict__ H2,
                                                 const int* __restrict__ IDI,
                                                 const float* __restrict__ SC,
                                                 const int* __restrict__ IS,
                                                 const float* __restrict__ wq2,
                                                 const float* __restrict__ b2,
                                                 const float* __restrict__ wqid,
                                                 const float* __restrict__ bidp,
                                                 float* __restrict__ out) {
  __shared__ float tile[64 * 57];
  __shared__ float pw2[64], pb2[64], pwi[64], pbi[64];
  int tid = threadIdx.x;
  int b = blockIdx.x;
  int ct = b & 3;
  int rt = (b >> 2) % 14;
  int n = b / 56;
  int c0 = ct * 64;
  int r0 = rt * 56;
  if (tid < 64) {
    pw2[tid] = wq2[c0 + tid];
    pb2[tid] = b2[c0 + tid];
    pwi[tid] = wqid[c0 + tid];
    pbi[tid] = bidp[c0 + tid];
  }
  __syncthreads();
  SumParams P = make_params(SC, IS);
  float out_s = fmaxf(__uint_as_float(((const unsigned*)IS)[11]) / 127.0f, 1e-8f);

  const int base = (n * 784 + r0) * 256 + c0;
#pragma unroll
  for (int k = 0; k < 14; ++k) {
    int idx = tid + k * 256;  // < 3584
    int rl = idx >> 6;
    int cl = idx & 63;
    int e = base + rl * 256 + cl;
    float sv = sum_val(H2[e], IDI[e], P, pw2[cl], pb2[cl], pwi[cl], pbi[cl]);
    float q = clamp8f(rintf(sv / out_s));
    tile[cl * 57 + rl] = q > 0.0f ? q * out_s : 0.0f;
  }
  __syncthreads();
  float* ob = out + n * 200704 + c0 * 784 + r0;
#pragma unroll
  for (int k = 0; k < 14; ++k) {
    int idx = tid + k * 256;
    int cl = idx / 56;
    int rl = idx % 56;
    ob[cl * 784 + rl] = tile[cl * 57 + rl];
  }
  if (b == 0 && tid == 0) out[6422528] = out_s;
}

extern "C" void kernel_launch(void* const* d_in, const int* in_sizes, int n_in, void* d_out,
                              int out_size, void* d_ws, size_t ws_size, hipStream_t stream) {
  (void)in_sizes; (void)n_in; (void)out_size; (void)ws_size;
  const float* x = (const float*)d_in[0];
  const float* w1 = (const float*)d_in[1];
  const float* w2 = (const float*)d_in[2];
  const float* wid = (const float*)d_in[3];
  const float* bn1g = (const float*)d_in[4];
  const float* bn1b = (const float*)d_in[5];
  const float* bn1m = (const float*)d_in[6];
  const float* bn1v = (const float*)d_in[7];
  const float* bn2g = (const float*)d_in[8];
  const float* bn2b = (const float*)d_in[9];
  const float* bn2m = (const float*)d_in[10];
  const float* bn2v = (const float*)d_in[11];
  const float* idg = (const float*)d_in[12];
  const float* idb = (const float*)d_in[13];
  const float* idm = (const float*)d_in[14];
  const float* idv = (const float*)d_in[15];

  char* ws = (char*)d_ws;
  float* SC = (float*)ws;
  int* IS = (int*)ws;
  unsigned* ISu = (unsigned*)ws;
  float* wq1 = (float*)(ws + 3072);
  float* b1 = (float*)(ws + 4096);
  float* wq2 = (float*)(ws + 5120);
  float* b2 = (float*)(ws + 6144);
  float* wqid = (float*)(ws + 7168);
  float* bid = (float*)(ws + 8192);
  char* X8 = ws + 16384;                 // NHWC int8; A2 overlays after conv1
  char* A2 = X8;
  char* W1m = X8 + 12845056;
  char* W2m = W1m + 294912;
  char* Widm = W2m + 589824;
  int* H1 = (int*)(Widm + 32768);
  int* H2 = H1;
  int* IDI = (int*)((char*)H1 + 25690112);
  float* out = (float*)d_out;
  int* maxS = (int*)d_out;  // extrema scratch in d_out (dead until k_out)
  int* minS = maxS + 448 * 256;

  hipMemsetAsync(IS, 0, 256, stream);  // zero scalar slots (atomic targets)
  k_pre<<<723, THREADS, 0, stream>>>(IS, bn1g, bn1b, bn1m, bn1v, wq1, b1, bn2g, bn2b, bn2m, bn2v,
                                     wq2, b2, idg, idb, idm, idv, wqid, bid, (const float4*)w1,
                                     (const float4*)w2, (const float4*)wid, (const float4*)x);
  k_quant<<<2016, THREADS, 0, stream>>>(x, (int*)X8, w1, (vi4*)W1m, w2, (vi4*)W2m, wid,
                                        (vi4*)Widm, ISu);
  k_conv1<<<896, THREADS, 0, stream>>>((const int*)X8, (const vi4*)W1m, (const vi4*)Widm, H1, IDI,
                                       maxS, minS, IS + 5);
  k_rs1<<<1, 1024, 0, stream>>>(IS, SC, maxS, minS, wq1, b1);
  k_qh1<<<6272, THREADS, 0, stream>>>((const int4*)H1, (char4*)A2, SC, wq1, b1);
  k_conv2<<<896, THREADS, 0, stream>>>((const int*)A2, (const vi4*)W2m, H2, IS + 6);
  k_absmax2<<<1024, THREADS, 0, stream>>>((const int4*)H2, (const int4*)IDI, SC, IS, wq2, b2, wqid,
                                          bid, ISu + 11);
  k_out<<<1792, THREADS, 0, stream>>>(H2, IDI, SC, IS, wq2, b2, wqid, bid, out);
}